// Round 2
// baseline (21038.049 us; speedup 1.0000x reference)
//
#include <hip/hip_runtime.h>
#include <cstddef>
#include <cstdint>

// ============================================================================
// DevignModel: GGNN(8 steps) -> conv/bn/relu/pool x2 -> MLP -> mean -> sigmoid
// Round 1: fp32, workspace-slim (~253 MB): in-place GRU, per-etype aggregation
// into one reused buffer, chunked GRU GEMMs, no cmat materialization.
// ============================================================================

__global__ void fail_k(float* out, float code) { out[0] = code; out[1] = code; }

__global__ void init_h0_k(const float* __restrict__ feat, float* __restrict__ h, int N) {
  int total = N * 200;
  for (int i = blockIdx.x * blockDim.x + threadIdx.x; i < total; i += blockDim.x * gridDim.x) {
    int n = i / 200, c = i - n * 200;
    h[i] = (c < 100) ? feat[n * 100 + c] : 0.f;
  }
}

__global__ void count_deg_k(const int* __restrict__ dst, const int* __restrict__ et,
                            int* __restrict__ deg_et, int N, int E) {
  for (int e = blockIdx.x * blockDim.x + threadIdx.x; e < E; e += blockDim.x * gridDim.x)
    atomicAdd(&deg_et[et[e] * N + dst[e]], 1);
}

// single-block chunked exclusive scan over L entries
__global__ void scan4_k(const int* __restrict__ cnt, int* __restrict__ off, int L) {
  __shared__ int buf[1024];
  __shared__ int carry;
  if (threadIdx.x == 0) carry = 0;
  __syncthreads();
  for (int base = 0; base < L; base += 1024) {
    int i = base + threadIdx.x;
    int v = (i < L) ? cnt[i] : 0;
    buf[threadIdx.x] = v;
    __syncthreads();
    for (int o = 1; o < 1024; o <<= 1) {
      int t = (threadIdx.x >= o) ? buf[threadIdx.x - o] : 0;
      __syncthreads();
      buf[threadIdx.x] += t;
      __syncthreads();
    }
    if (i < L) off[i] = buf[threadIdx.x] - v + carry;  // exclusive
    int tot = buf[1023];
    __syncthreads();
    if (threadIdx.x == 0) carry += tot;
    __syncthreads();
  }
}

__global__ void copy_int_k(const int* __restrict__ a, int* __restrict__ b, int n) {
  for (int i = blockIdx.x * blockDim.x + threadIdx.x; i < n; i += blockDim.x * gridDim.x) b[i] = a[i];
}

// bucket edges by (etype, dst); store the SOURCE node id directly
__global__ void fill_src_k(const int* __restrict__ src, const int* __restrict__ dst,
                           const int* __restrict__ et, int* __restrict__ cursor,
                           int* __restrict__ esrc, int N, int E) {
  for (int e = blockIdx.x * blockDim.x + threadIdx.x; e < E; e += blockDim.x * gridDim.x) {
    int p = atomicAdd(&cursor[et[e] * N + dst[e]], 1);
    esrc[p] = src[e];
  }
}

// wt[t][co][ci] = w[co][ci][kw] slice t   (conv1: O=I=200, kw=3)
__global__ void pack_conv3_k(const float* __restrict__ w, float* __restrict__ wt, int O, int I) {
  int total = 3 * O * I;
  for (int i = blockIdx.x * blockDim.x + threadIdx.x; i < total; i += blockDim.x * gridDim.x) {
    int t = i / (O * I), r = i - t * (O * I);
    int co = r / I, ci = r - co * I;
    wt[i] = w[(co * I + ci) * 3 + t];
  }
}

// convc1 (300 x 300 x 3) split into h-part (ci<200) and feat-part (ci>=200)
__global__ void pack_convc1_k(const float* __restrict__ w, float* __restrict__ wh,
                              float* __restrict__ wf) {
  int total = 3 * 300 * 300;
  for (int i = blockIdx.x * blockDim.x + threadIdx.x; i < total; i += blockDim.x * gridDim.x) {
    int co = i / 900, r = i - co * 900;
    int ci = r / 3, t = r - ci * 3;
    float v = w[i];
    if (ci < 200) wh[(t * 300 + co) * 200 + ci] = v;
    else          wf[(t * 300 + co) * 100 + (ci - 200)] = v;
  }
}

// abuf[n][o] = sum_k deg_et[k][n] * ggnn_b[k][o]   (per-step init of 'a')
__global__ void abias_k(const int* __restrict__ deg_et, const float* __restrict__ gb,
                        float* __restrict__ abuf, int N) {
  int total = N * 200;
  for (int i = blockIdx.x * blockDim.x + threadIdx.x; i < total; i += blockDim.x * gridDim.x) {
    int n = i / 200, o = i - n * 200;
    float v = 0.f;
#pragma unroll
    for (int k = 0; k < 4; ++k) v += (float)deg_et[k * N + n] * gb[k * 200 + o];
    abuf[i] = v;
  }
}

// one etype pass: s[n][0:200] = sum over type-k in-edges of h[src]
__global__ void aggregate_et_k(const int* __restrict__ off, const int* __restrict__ deg,
                               const int* __restrict__ esrc, const float* __restrict__ h,
                               float* __restrict__ s, int N) {
  int gtid = blockIdx.x * blockDim.x + threadIdx.x;
  int wid = gtid >> 6, lane = threadIdx.x & 63;
  int nw = (blockDim.x * gridDim.x) >> 6;
  for (int n = wid; n < N; n += nw) {
    float a0 = 0.f, a1 = 0.f, a2 = 0.f, a3 = 0.f;
    int rs = off[n], re = rs + deg[n];
    for (int idx = rs; idx < re; ++idx) {
      const float* hr = h + (size_t)esrc[idx] * 200;
      a0 += hr[lane];
      a1 += hr[lane + 64];
      a2 += hr[lane + 128];
      if (lane < 8) a3 += hr[lane + 192];
    }
    float* sr = s + (size_t)n * 200;
    sr[lane] = a0; sr[lane + 64] = a1; sr[lane + 128] = a2;
    if (lane < 8) sr[lane + 192] = a3;
  }
}

// ---------------- generic tiled fp32 GEMM: C[M,Nn] (+)= A[M,K] @ B[Nn,K]^T + bias
__global__ __launch_bounds__(256) void gemm_nt(
    const float* __restrict__ A, int lda,
    const float* __restrict__ B, int ldb,
    float* __restrict__ C, int ldc,
    int M, int Nn, int K,
    const float* __restrict__ bias,
    int accumulate) {
  __shared__ float As[16][64];
  __shared__ float Bs[16][64];
  const int tid = threadIdx.x;
  const int bm = blockIdx.y * 64;
  const int bn = blockIdx.x * 64;
  const int tx = tid & 15;   // n-dir
  const int ty = tid >> 4;   // m-dir
  const int lrow = tid >> 2; // 0..63
  const int lk = (tid & 3) << 2;

  float acc[4][4];
#pragma unroll
  for (int i = 0; i < 4; ++i)
#pragma unroll
    for (int j = 0; j < 4; ++j) acc[i][j] = 0.f;

  for (int k0 = 0; k0 < K; k0 += 16) {
    int gk = k0 + lk;
    float4 va = make_float4(0.f, 0.f, 0.f, 0.f);
    float4 vb = make_float4(0.f, 0.f, 0.f, 0.f);
    {
      int ra = bm + lrow;
      if (ra < M) {
        const float* p = A + (size_t)ra * lda + gk;
        if (gk + 4 <= K) va = *reinterpret_cast<const float4*>(p);
        else {
          float t0 = (gk + 0 < K) ? p[0] : 0.f;
          float t1 = (gk + 1 < K) ? p[1] : 0.f;
          float t2 = (gk + 2 < K) ? p[2] : 0.f;
          va = make_float4(t0, t1, t2, 0.f);
        }
      }
    }
    {
      int rb = bn + lrow;
      if (rb < Nn) {
        const float* p = B + (size_t)rb * ldb + gk;
        if (gk + 4 <= K) vb = *reinterpret_cast<const float4*>(p);
        else {
          float t0 = (gk + 0 < K) ? p[0] : 0.f;
          float t1 = (gk + 1 < K) ? p[1] : 0.f;
          float t2 = (gk + 2 < K) ? p[2] : 0.f;
          vb = make_float4(t0, t1, t2, 0.f);
        }
      }
    }
    __syncthreads();
    As[lk + 0][lrow] = va.x; As[lk + 1][lrow] = va.y; As[lk + 2][lrow] = va.z; As[lk + 3][lrow] = va.w;
    Bs[lk + 0][lrow] = vb.x; Bs[lk + 1][lrow] = vb.y; Bs[lk + 2][lrow] = vb.z; Bs[lk + 3][lrow] = vb.w;
    __syncthreads();
#pragma unroll
    for (int kk = 0; kk < 16; ++kk) {
      const float4 a4 = *reinterpret_cast<const float4*>(&As[kk][ty << 2]);
      const float4 b4 = *reinterpret_cast<const float4*>(&Bs[kk][tx << 2]);
      float aa[4] = {a4.x, a4.y, a4.z, a4.w};
      float bb[4] = {b4.x, b4.y, b4.z, b4.w};
#pragma unroll
      for (int i = 0; i < 4; ++i)
#pragma unroll
        for (int j = 0; j < 4; ++j) acc[i][j] = fmaf(aa[i], bb[j], acc[i][j]);
    }
  }

#pragma unroll
  for (int i = 0; i < 4; ++i) {
    int m = bm + (ty << 2) + i;
    if (m >= M) continue;
#pragma unroll
    for (int j = 0; j < 4; ++j) {
      int n = bn + (tx << 2) + j;
      if (n >= Nn) continue;
      float v = acc[i][j];
      if (bias) v += bias[n];
      if (accumulate) v += C[(size_t)m * ldc + n];
      C[(size_t)m * ldc + n] = v;
    }
  }
}

// GRU pointwise update, in place on h chunk
__global__ void gru_k(const float* __restrict__ grz, const float* __restrict__ inn,
                      const float* __restrict__ hn, float* __restrict__ h, int Nc) {
  int total = Nc * 200;
  for (int i = blockIdx.x * blockDim.x + threadIdx.x; i < total; i += blockDim.x * gridDim.x) {
    int n = i / 200, o = i - n * 200;
    size_t base = (size_t)n * 400;
    float r = 1.f / (1.f + expf(-grz[base + o]));
    float z = 1.f / (1.f + expf(-grz[base + 200 + o]));
    float nn = tanhf(inn[i] + r * hn[i]);
    h[i] = (1.f - z) * nn + z * h[i];
  }
}

// per-channel sum & sumsq of X [L, C], accumulated into stats[2C] (pre-zeroed)
__global__ __launch_bounds__(256) void bn_stats_k(const float* __restrict__ X, int total, int C,
                                                  float* __restrict__ stats) {
  __shared__ float sb[300], qb[300];
  for (int c = threadIdx.x; c < C; c += blockDim.x) { sb[c] = 0.f; qb[c] = 0.f; }
  __syncthreads();
  for (int i = blockIdx.x * blockDim.x + threadIdx.x; i < total; i += blockDim.x * gridDim.x) {
    float v = X[i];
    int c = i % C;
    atomicAdd(&sb[c], v);
    atomicAdd(&qb[c], v * v);
  }
  __syncthreads();
  for (int c = threadIdx.x; c < C; c += blockDim.x) {
    atomicAdd(&stats[c], sb[c]);
    atomicAdd(&stats[C + c], qb[c]);
  }
}

__global__ void bn_fin_k(const float* __restrict__ stats, const float* __restrict__ g,
                         const float* __restrict__ b, int C, float Linv,
                         float* __restrict__ scsh) {
  int c = blockIdx.x * blockDim.x + threadIdx.x;
  if (c < C) {
    float mean = stats[c] * Linv;
    float var = stats[C + c] * Linv - mean * mean;
    float sc = g[c] * rsqrtf(var + 1e-5f);
    scsh[c] = sc;
    scsh[C + c] = b[c] - mean * sc;
  }
}

// fused bn + relu + maxpool
__global__ void pool_k(const float* __restrict__ X, int C, const float* __restrict__ scsh,
                       int kw, int stride, float* __restrict__ Y, int Lout) {
  int total = Lout * C;
  for (int i = blockIdx.x * blockDim.x + threadIdx.x; i < total; i += blockDim.x * gridDim.x) {
    int lp = i / C, c = i - lp * C;
    float sc = scsh[c], sh = scsh[C + c];
    int l0 = lp * stride;
    float m = 0.f;  // relu lower bound
    for (int w = 0; w < kw; ++w) {
      float x = X[(size_t)(l0 + w) * C + c];
      m = fmaxf(m, fmaf(x, sc, sh));
    }
    Y[i] = m;
  }
}

__global__ __launch_bounds__(256) void final_dot_k(
    const float* __restrict__ Y2, const float* __restrict__ Z2,
    const float* __restrict__ wy, const float* __restrict__ by,
    const float* __restrict__ wz, const float* __restrict__ bz,
    float* __restrict__ acc, int L) {
  float s0 = 0.f, s1 = 0.f;
  for (int lp = blockIdx.x * blockDim.x + threadIdx.x; lp < L; lp += blockDim.x * gridDim.x) {
    const float* y = Y2 + (size_t)lp * 200;
    const float* z = Z2 + (size_t)lp * 300;
    float d0 = 0.f, d1 = 0.f;
    for (int k = 0; k < 200; ++k) { float v = y[k]; d0 += v * wy[k]; d1 += v * wy[200 + k]; }
    float e0 = 0.f, e1 = 0.f;
    for (int k = 0; k < 300; ++k) { float v = z[k]; e0 += v * wz[k]; e1 += v * wz[300 + k]; }
    s0 += (d0 + by[0]) * (e0 + bz[0]);
    s1 += (d1 + by[1]) * (e1 + bz[1]);
  }
  __shared__ float r0[256], r1[256];
  r0[threadIdx.x] = s0; r1[threadIdx.x] = s1;
  __syncthreads();
  for (int off = 128; off > 0; off >>= 1) {
    if (threadIdx.x < off) { r0[threadIdx.x] += r0[threadIdx.x + off]; r1[threadIdx.x] += r1[threadIdx.x + off]; }
    __syncthreads();
  }
  if (threadIdx.x == 0) { atomicAdd(&acc[0], r0[0]); atomicAdd(&acc[1], r1[0]); }
}

__global__ void final_out_k(const float* __restrict__ acc, float invL, float* __restrict__ out) {
  int j = threadIdx.x;
  if (j < 2) out[j] = 1.f / (1.f + expf(-acc[j] * invL));
}

// ---------------- host ----------------

static inline void launch_gemm(hipStream_t s, const float* A, int lda, const float* B, int ldb,
                               float* C, int ldc, int M, int Nn, int K,
                               const float* bias, int accumulate) {
  dim3 grid((Nn + 63) / 64, (M + 63) / 64);
  gemm_nt<<<grid, 256, 0, s>>>(A, lda, B, ldb, C, ldc, M, Nn, K, bias, accumulate);
}

extern "C" void kernel_launch(void* const* d_in, const int* in_sizes, int n_in,
                              void* d_out, int out_size, void* d_ws, size_t ws_size,
                              hipStream_t stream) {
  (void)n_in; (void)out_size;
  const float* feat    = (const float*)d_in[0];
  const int*   eix     = (const int*)d_in[1];
  const int*   etyp    = (const int*)d_in[2];
  const float* ggnnW   = (const float*)d_in[3];
  const float* ggnnB   = (const float*)d_in[4];
  const float* Wih     = (const float*)d_in[5];
  const float* Whh     = (const float*)d_in[6];
  const float* bih     = (const float*)d_in[7];
  const float* bhh     = (const float*)d_in[8];
  const float* conv1w  = (const float*)d_in[9];
  const float* conv2w  = (const float*)d_in[11];
  const float* convc1w = (const float*)d_in[13];
  const float* convc2w = (const float*)d_in[15];
  const float* bnyg    = (const float*)d_in[17];
  const float* bnyb    = (const float*)d_in[18];
  const float* bncg    = (const float*)d_in[19];
  const float* bncb    = (const float*)d_in[20];
  const float* mlpyw   = (const float*)d_in[21];
  const float* mlpyb   = (const float*)d_in[22];
  const float* mlpzw   = (const float*)d_in[23];
  const float* mlpzb   = (const float*)d_in[24];

  const int N = in_sizes[0] / 100;
  const int E = in_sizes[2];
  const int* src = eix;
  const int* dst = eix + E;

  const size_t U = (size_t)N * 200;  // one node-buffer, floats
  float* P = (float*)d_ws;

  // arena: 3 node-buffers
  float* h    = P;          // [0, U)
  float* abuf = P + U;      // [U, 2U)
  float* sbuf = P + 2 * U;  // [2U, 3U)

  // small float region
  float* smallf = P + 3 * U;
  float* w1t   = smallf;             // 3*200*200 = 120000
  float* wc1h  = smallf + 120000;    // 3*300*200 = 180000
  float* wc1f  = smallf + 300000;    // 3*300*100 =  90000
  float* stats = smallf + 390000;    // 600
  float* scsh  = smallf + 391000;    // 600
  float* acc2  = smallf + 392000;    // 2
  // int region
  int* ipart  = (int*)(smallf + 393000);
  int* deg_et = ipart;                       // 4N
  int* off_et = ipart + 4 * (size_t)N;       // 4N
  int* cursor = off_et + 4 * (size_t)N;      // 4N
  int* esrc   = cursor + 4 * (size_t)N;      // E

  size_t need_bytes = (3 * U + 393000) * 4 + (12 * (size_t)N + (size_t)E) * 4;
  if (ws_size < need_bytes) {
    // report the actual budget (in MB, negated) so we can re-plan
    fail_k<<<1, 64, 0, stream>>>((float*)d_out, -(float)(ws_size >> 20));
    return;
  }

  // ---- CSR build (bucketed by etype,dst) + weight packs ----
  hipMemsetAsync(deg_et, 0, sizeof(int) * 4 * (size_t)N, stream);
  init_h0_k<<<2048, 256, 0, stream>>>(feat, h, N);
  count_deg_k<<<2048, 256, 0, stream>>>(dst, etyp, deg_et, N, E);
  scan4_k<<<1, 1024, 0, stream>>>(deg_et, off_et, 4 * N);
  copy_int_k<<<512, 256, 0, stream>>>(off_et, cursor, 4 * N);
  fill_src_k<<<2048, 256, 0, stream>>>(src, dst, etyp, cursor, esrc, N, E);
  pack_conv3_k<<<256, 256, 0, stream>>>(conv1w, w1t, 200, 200);
  pack_convc1_k<<<256, 256, 0, stream>>>(convc1w, wc1h, wc1f);

  // ---- GGNN 8 steps (h updated in place) ----
  const int chunk = N / 4;  // GRU scratch (chunk*800 floats) fits in sbuf (N*200)
  for (int step = 0; step < 8; ++step) {
    // a := bias term, then += s_k @ W_k^T for each etype
    abias_k<<<2048, 256, 0, stream>>>(deg_et, ggnnB, abuf, N);
    for (int k = 0; k < 4; ++k) {
      aggregate_et_k<<<2048, 256, 0, stream>>>(off_et + (size_t)k * N, deg_et + (size_t)k * N,
                                               esrc, h, sbuf, N);
      launch_gemm(stream, sbuf, 200, ggnnW + (size_t)k * 40000, 200,
                  abuf, 200, N, 200, 200, nullptr, 1);
    }
    // GRU in node chunks; scratch aliases sbuf
    for (int c0 = 0; c0 < N; c0 += chunk) {
      int Nc = (c0 + chunk <= N) ? chunk : (N - c0);
      float* grz = sbuf;                         // Nc*400
      float* hnb = sbuf + (size_t)chunk * 400;   // Nc*200
      float* inn = sbuf + (size_t)chunk * 600;   // Nc*200
      const float* a_c = abuf + (size_t)c0 * 200;
      float* h_c = h + (size_t)c0 * 200;
      launch_gemm(stream, a_c, 200, Wih, 200, grz, 400, Nc, 400, 200, bih, 0);
      launch_gemm(stream, h_c, 200, Whh, 200, grz, 400, Nc, 400, 200, bhh, 1);
      launch_gemm(stream, h_c, 200, Whh + 400 * 200, 200, hnb, 200, Nc, 200, 200, bhh + 400, 0);
      launch_gemm(stream, a_c, 200, Wih + 400 * 200, 200, inn, 200, Nc, 200, 200, bih + 400, 0);
      gru_k<<<2048, 256, 0, stream>>>(grz, inn, hnb, h_c, Nc);
    }
  }

  // ---- conv paths ----
  const int L1 = N - 2;
  const int L2 = (L1 - 3) / 2 + 1;
  const int L3 = (L2 - 2) / 2 + 1;

  // placement in the 3U arena (live ranges verified):
  float* out1  = abuf;                          // L1*200  <= U
  float* y1    = sbuf;                          // L2*200
  float* out2  = sbuf + (size_t)L2 * 200;       // L2*200  (both halves fit in U)
  float* Y2b   = abuf;                          // L3*200  (out1 dead)
  float* outc1 = abuf + (size_t)L3 * 200;       // L1*300  (after Y2; h still live)
  float* z1    = h;                             // L2*300  (h dead after outc1)
  float* outc2 = abuf + (size_t)L3 * 200;       // L2*300  (outc1 dead after z1)
  float* Z2b   = sbuf;                          // L3*300  (y1/out2 dead)

  // Y path: conv1 (k=3) = 3 accumulated GEMMs vs shifted h rows; conv bias cancels in BN
  for (int t = 0; t < 3; ++t)
    launch_gemm(stream, h + (size_t)t * 200, 200, w1t + (size_t)t * 40000, 200,
                out1, 200, L1, 200, 200, nullptr, t > 0);
  hipMemsetAsync(stats, 0, sizeof(float) * 400, stream);
  bn_stats_k<<<1024, 256, 0, stream>>>(out1, L1 * 200, 200, stats);
  bn_fin_k<<<2, 256, 0, stream>>>(stats, bnyg, bnyb, 200, 1.f / (float)L1, scsh);
  pool_k<<<2048, 256, 0, stream>>>(out1, 200, scsh, 3, 2, y1, L2);

  launch_gemm(stream, y1, 200, conv2w, 200, out2, 200, L2, 200, 200, nullptr, 0);
  hipMemsetAsync(stats, 0, sizeof(float) * 400, stream);
  bn_stats_k<<<1024, 256, 0, stream>>>(out2, L2 * 200, 200, stats);
  bn_fin_k<<<2, 256, 0, stream>>>(stats, bnyg, bnyb, 200, 1.f / (float)L2, scsh);
  pool_k<<<2048, 256, 0, stream>>>(out2, 200, scsh, 2, 2, Y2b, L3);

  // Z path: convc1 (k=3, Cin=300) = 6 accumulated GEMMs vs shifted h (K=200) and feat (K=100)
  for (int t = 0; t < 3; ++t) {
    launch_gemm(stream, h + (size_t)t * 200, 200, wc1h + (size_t)t * 60000, 200,
                outc1, 300, L1, 300, 200, nullptr, t > 0);
    launch_gemm(stream, feat + (size_t)t * 100, 100, wc1f + (size_t)t * 30000, 100,
                outc1, 300, L1, 300, 100, nullptr, 1);
  }
  hipMemsetAsync(stats, 0, sizeof(float) * 600, stream);
  bn_stats_k<<<1024, 256, 0, stream>>>(outc1, L1 * 300, 300, stats);
  bn_fin_k<<<2, 256, 0, stream>>>(stats, bncg, bncb, 300, 1.f / (float)L1, scsh);
  pool_k<<<2048, 256, 0, stream>>>(outc1, 300, scsh, 3, 2, z1, L2);

  launch_gemm(stream, z1, 300, convc2w, 300, outc2, 300, L2, 300, 300, nullptr, 0);
  hipMemsetAsync(stats, 0, sizeof(float) * 600, stream);
  bn_stats_k<<<1024, 256, 0, stream>>>(outc2, L2 * 300, 300, stats);
  bn_fin_k<<<2, 256, 0, stream>>>(stats, bncg, bncb, 300, 1.f / (float)L2, scsh);
  pool_k<<<2048, 256, 0, stream>>>(outc2, 300, scsh, 2, 2, Z2b, L3);

  // ---- final MLP product + mean + sigmoid ----
  hipMemsetAsync(acc2, 0, sizeof(float) * 2, stream);
  final_dot_k<<<256, 256, 0, stream>>>(Y2b, Z2b, mlpyw, mlpyb, mlpzw, mlpzb, acc2, L3);
  final_out_k<<<1, 64, 0, stream>>>(acc2, 1.f / (float)L3, (float*)d_out);
}

// Round 3
// 12634.059 us; speedup vs baseline: 1.6652x; 1.6652x over previous
//
#include <hip/hip_runtime.h>
#include <cstddef>
#include <cstdint>

// ============================================================================
// DevignModel round 3: bf16 MFMA everywhere.
//  - all GEMMs via one 16x16x32-bf16 MFMA kernel (128x64 tile, 4 waves)
//  - k=3 convs folded into single GEMMs (row-stride shift trick, no im2col)
//  - activations bf16 (K padded to x32, zero pads), fp32 only where sums
//    span multiple GEMM calls (abuf, gates)
//  - workspace ~228 MB
// ============================================================================

typedef unsigned short u16;
typedef __attribute__((ext_vector_type(8))) short bf16x8;
typedef __attribute__((ext_vector_type(4))) float f32x4;
typedef __attribute__((ext_vector_type(8))) unsigned short u16x8;
typedef __attribute__((ext_vector_type(4))) unsigned short u16x4;

static __device__ __forceinline__ float bf2f(u16 u) {
  union { unsigned int i; float f; } v; v.i = ((unsigned int)u) << 16; return v.f;
}
static __device__ __forceinline__ u16 f2bf(float f) {
  union { float f; unsigned int i; } v; v.f = f;
  unsigned int r = v.i + 0x7FFFu + ((v.i >> 16) & 1u);
  return (u16)(r >> 16);
}

__global__ void fail_k(float* out, float code) { out[0] = code; out[1] = code; }

// h_b[n][c<100]=feat, else 0 (pads included) ; stride 224
__global__ void init_h0_b(const float* __restrict__ feat, u16* __restrict__ h, int N) {
  int total = N * 224;
  for (int i = blockIdx.x * blockDim.x + threadIdx.x; i < total; i += blockDim.x * gridDim.x) {
    int n = i / 224, c = i - n * 224;
    h[i] = (c < 100) ? f2bf(feat[n * 100 + c]) : (u16)0;
  }
}

__global__ void count_deg_k(const int* __restrict__ dst, const int* __restrict__ et,
                            int* __restrict__ deg_et, int N, int E) {
  for (int e = blockIdx.x * blockDim.x + threadIdx.x; e < E; e += blockDim.x * gridDim.x)
    atomicAdd(&deg_et[et[e] * N + dst[e]], 1);
}

// single-block chunked exclusive scan over L entries
__global__ void scan4_k(const int* __restrict__ cnt, int* __restrict__ off, int L) {
  __shared__ int buf[1024];
  __shared__ int carry;
  if (threadIdx.x == 0) carry = 0;
  __syncthreads();
  for (int base = 0; base < L; base += 1024) {
    int i = base + threadIdx.x;
    int v = (i < L) ? cnt[i] : 0;
    buf[threadIdx.x] = v;
    __syncthreads();
    for (int o = 1; o < 1024; o <<= 1) {
      int t = (threadIdx.x >= o) ? buf[threadIdx.x - o] : 0;
      __syncthreads();
      buf[threadIdx.x] += t;
      __syncthreads();
    }
    if (i < L) off[i] = buf[threadIdx.x] - v + carry;
    int tot = buf[1023];
    __syncthreads();
    if (threadIdx.x == 0) carry += tot;
    __syncthreads();
  }
}

__global__ void copy_int_k(const int* __restrict__ a, int* __restrict__ b, int n) {
  for (int i = blockIdx.x * blockDim.x + threadIdx.x; i < n; i += blockDim.x * gridDim.x) b[i] = a[i];
}

__global__ void fill_src_k(const int* __restrict__ src, const int* __restrict__ dst,
                           const int* __restrict__ et, int* __restrict__ cursor,
                           int* __restrict__ esrc, int N, int E) {
  for (int e = blockIdx.x * blockDim.x + threadIdx.x; e < E; e += blockDim.x * gridDim.x) {
    int p = atomicAdd(&cursor[et[e] * N + dst[e]], 1);
    esrc[p] = src[e];
  }
}

// ---- weight packs (fp32 -> bf16, K zero-padded) ----

// generic linear: src [Nn][K] -> dst [Nn][Kp]
__global__ void pack_lin_b(const float* __restrict__ src, u16* __restrict__ dst,
                           int Nn, int K, int Kp) {
  int total = Nn * Kp;
  for (int i = blockIdx.x * blockDim.x + threadIdx.x; i < total; i += blockDim.x * gridDim.x) {
    int o = i / Kp, kp = i - o * Kp;
    dst[i] = (kp < K) ? f2bf(src[(size_t)o * K + kp]) : (u16)0;
  }
}

// ggnn_W [4][200][200] -> [4][200][224]
__global__ void pack_ggnnW_b(const float* __restrict__ W, u16* __restrict__ dst) {
  int total = 4 * 200 * 224;
  for (int i = blockIdx.x * blockDim.x + threadIdx.x; i < total; i += blockDim.x * gridDim.x) {
    int k = i / 44800, r = i - k * 44800;
    int o = r / 224, kp = r - o * 224;
    dst[i] = (kp < 200) ? f2bf(W[((size_t)k * 200 + o) * 200 + kp]) : (u16)0;
  }
}

// conv k=3: src [O][I][3] -> dst [O][3*Ip] with dst[o][t*Ip+kp] = src[o][kp][t]
__global__ void pack_conv3_b(const float* __restrict__ src, u16* __restrict__ dst,
                             int O, int I, int Ip) {
  int total = O * 3 * Ip;
  for (int i = blockIdx.x * blockDim.x + threadIdx.x; i < total; i += blockDim.x * gridDim.x) {
    int o = i / (3 * Ip), r = i - o * (3 * Ip);
    int t = r / Ip, kp = r - t * Ip;
    dst[i] = (kp < I) ? f2bf(src[((size_t)o * I + kp) * 3 + t]) : (u16)0;
  }
}

// convc1 [300][300][3] -> [300][1056] matching cmat layout [h(224 pad)|feat(128 pad)] per t
__global__ void pack_wc1_b(const float* __restrict__ src, u16* __restrict__ dst) {
  int total = 300 * 1056;
  for (int i = blockIdx.x * blockDim.x + threadIdx.x; i < total; i += blockDim.x * gridDim.x) {
    int o = i / 1056, r = i - o * 1056;
    int t = r / 352, kp = r - t * 352;
    int ci = (kp < 224) ? (kp < 200 ? kp : -1) : ((kp - 224) < 100 ? 200 + (kp - 224) : -1);
    dst[i] = (ci >= 0) ? f2bf(src[((size_t)o * 300 + ci) * 3 + t]) : (u16)0;
  }
}

// abuf[n][o] = sum_k deg_et[k][n] * ggnn_b[k][o]   (fp32 init of 'a')
__global__ void abias_k(const int* __restrict__ deg_et, const float* __restrict__ gb,
                        float* __restrict__ abuf, int N) {
  int total = N * 200;
  for (int i = blockIdx.x * blockDim.x + threadIdx.x; i < total; i += blockDim.x * gridDim.x) {
    int n = i / 200, o = i - n * 200;
    float v = 0.f;
#pragma unroll
    for (int k = 0; k < 4; ++k) v += (float)deg_et[k * N + n] * gb[k * 200 + o];
    abuf[i] = v;
  }
}

// per-etype aggregation: s[n][0:224] = sum over type-k in-edges of h_b[src] (bf16 in/out, fp32 acc)
__global__ void aggregate_b_k(const int* __restrict__ off, const int* __restrict__ deg,
                              const int* __restrict__ esrc, const u16* __restrict__ h,
                              u16* __restrict__ s, int N) {
  int gtid = blockIdx.x * blockDim.x + threadIdx.x;
  int wid = gtid >> 6, lane = threadIdx.x & 63;
  int nw = (blockDim.x * gridDim.x) >> 6;
  for (int n = wid; n < N; n += nw) {
    int rs = off[n], re = rs + deg[n];
    if (lane < 56) {
      float a0 = 0.f, a1 = 0.f, a2 = 0.f, a3 = 0.f;
      for (int i = rs; i < re; ++i) {
        const u16* hr = h + (size_t)esrc[i] * 224 + lane * 4;
        u16x4 v = *reinterpret_cast<const u16x4*>(hr);
        a0 += bf2f(v[0]); a1 += bf2f(v[1]); a2 += bf2f(v[2]); a3 += bf2f(v[3]);
      }
      u16x4 r;
      r[0] = f2bf(a0); r[1] = f2bf(a1); r[2] = f2bf(a2); r[3] = f2bf(a3);
      *reinterpret_cast<u16x4*>(s + (size_t)n * 224 + lane * 4) = r;
    }
  }
}

// ---------------- bf16 MFMA GEMM: C[M,Nn] (+)= A[M,K]@B[Nn,K]^T (+bias) ----------------
// A,B bf16 row-major (lda/ldb >= K, K multiple of 32). Cf fp32 out (optional),
// Cb bf16 out (optional, padded to ldcb with zeros).
__global__ __launch_bounds__(256) void gemm_mfma(
    const u16* __restrict__ A, int lda,
    const u16* __restrict__ B, int ldb,
    float* __restrict__ Cf, int ldc,
    u16* __restrict__ Cb, int ldcb,
    int M, int Nn, int K,
    const float* __restrict__ bias, int accumulate) {
  __shared__ u16 As[128 * 40];  // 32 k + 8 pad per row
  __shared__ u16 Bs[64 * 40];
  const int tid = threadIdx.x;
  const int lane = tid & 63;
  const int w = tid >> 6;
  const int wr = w >> 1, wc = w & 1;
  const int m0 = blockIdx.y * 128;
  const int n0 = blockIdx.x * 64;

  const int srow = tid >> 2;       // 0..63
  const int skg = (tid & 3) * 8;   // 0,8,16,24

  const int fr = lane & 15;
  const int fk = (lane >> 4) * 8;

  f32x4 acc[4][2] = {};

  for (int k0 = 0; k0 < K; k0 += 32) {
    u16x8 va0 = 0, va1 = 0, vb = 0;
    int ra0 = m0 + srow, ra1 = m0 + srow + 64, rb = n0 + srow;
    if (ra0 < M) va0 = *reinterpret_cast<const u16x8*>(A + (size_t)ra0 * lda + k0 + skg);
    if (ra1 < M) va1 = *reinterpret_cast<const u16x8*>(A + (size_t)ra1 * lda + k0 + skg);
    if (rb < Nn) vb = *reinterpret_cast<const u16x8*>(B + (size_t)rb * ldb + k0 + skg);
    __syncthreads();
    *reinterpret_cast<u16x8*>(&As[srow * 40 + skg]) = va0;
    *reinterpret_cast<u16x8*>(&As[(srow + 64) * 40 + skg]) = va1;
    *reinterpret_cast<u16x8*>(&Bs[srow * 40 + skg]) = vb;
    __syncthreads();

    bf16x8 af[4], bfr[2];
#pragma unroll
    for (int i = 0; i < 4; ++i)
      af[i] = *reinterpret_cast<const bf16x8*>(&As[(wr * 64 + i * 16 + fr) * 40 + fk]);
#pragma unroll
    for (int j = 0; j < 2; ++j)
      bfr[j] = *reinterpret_cast<const bf16x8*>(&Bs[(wc * 32 + j * 16 + fr) * 40 + fk]);
#pragma unroll
    for (int i = 0; i < 4; ++i)
#pragma unroll
      for (int j = 0; j < 2; ++j)
        acc[i][j] = __builtin_amdgcn_mfma_f32_16x16x32_bf16(af[i], bfr[j], acc[i][j], 0, 0, 0);
  }

  const int er = (lane >> 4) * 4;
  const int ec = lane & 15;
#pragma unroll
  for (int i = 0; i < 4; ++i) {
#pragma unroll
    for (int j = 0; j < 2; ++j) {
      int n = n0 + wc * 32 + j * 16 + ec;
#pragma unroll
      for (int r = 0; r < 4; ++r) {
        int m = m0 + wr * 64 + i * 16 + er + r;
        if (m >= M) continue;
        if (n < Nn) {
          float v = acc[i][j][r];
          if (bias) v += bias[n];
          if (accumulate) v += Cf[(size_t)m * ldc + n];
          if (Cf) Cf[(size_t)m * ldc + n] = v;
          if (Cb) Cb[(size_t)m * ldcb + n] = f2bf(v);
        } else if (Cb && n < ldcb) {
          Cb[(size_t)m * ldcb + n] = (u16)0;
        }
      }
    }
  }
}

// GRU pointwise, in place on bf16 h chunk (stride 224)
__global__ void gru_b_k(const float* __restrict__ grz, const float* __restrict__ inn,
                        const float* __restrict__ hn, u16* __restrict__ h, int Nc) {
  int total = Nc * 200;
  for (int i = blockIdx.x * blockDim.x + threadIdx.x; i < total; i += blockDim.x * gridDim.x) {
    int n = i / 200, o = i - n * 200;
    size_t gb = (size_t)n * 400;
    float r = 1.f / (1.f + expf(-grz[gb + o]));
    float z = 1.f / (1.f + expf(-grz[gb + 200 + o]));
    float nn = tanhf(inn[i] + r * hn[i]);
    size_t hi = (size_t)n * 224 + o;
    float hold = bf2f(h[hi]);
    h[hi] = f2bf((1.f - z) * nn + z * hold);
  }
}

// cmat[n][0:224]=h_b row (incl pads), [224:352]= feat|0
__global__ void cmat_k(const u16* __restrict__ h, const float* __restrict__ feat,
                       u16* __restrict__ c, int N) {
  int total = N * 352;
  for (int i = blockIdx.x * blockDim.x + threadIdx.x; i < total; i += blockDim.x * gridDim.x) {
    int n = i / 352, j = i - n * 352;
    u16 v;
    if (j < 224) v = h[(size_t)n * 224 + j];
    else { int f = j - 224; v = (f < 100) ? f2bf(feat[(size_t)n * 100 + f]) : (u16)0; }
    c[i] = v;
  }
}

// per-channel sum & sumsq of bf16 X [L,C], accumulated into stats[2C] (pre-zeroed)
__global__ __launch_bounds__(256) void bn_stats_b_k(const u16* __restrict__ X, int total, int C,
                                                    float* __restrict__ stats) {
  __shared__ float sb[300], qb[300];
  for (int c = threadIdx.x; c < C; c += blockDim.x) { sb[c] = 0.f; qb[c] = 0.f; }
  __syncthreads();
  for (int i = blockIdx.x * blockDim.x + threadIdx.x; i < total; i += blockDim.x * gridDim.x) {
    float v = bf2f(X[i]);
    int c = i % C;
    atomicAdd(&sb[c], v);
    atomicAdd(&qb[c], v * v);
  }
  __syncthreads();
  for (int c = threadIdx.x; c < C; c += blockDim.x) {
    atomicAdd(&stats[c], sb[c]);
    atomicAdd(&stats[C + c], qb[c]);
  }
}

__global__ void bn_fin_k(const float* __restrict__ stats, const float* __restrict__ g,
                         const float* __restrict__ b, int C, float Linv,
                         float* __restrict__ scsh) {
  int c = blockIdx.x * blockDim.x + threadIdx.x;
  if (c < C) {
    float mean = stats[c] * Linv;
    float var = stats[C + c] * Linv - mean * mean;
    float sc = g[c] * rsqrtf(var + 1e-5f);
    scsh[c] = sc;
    scsh[C + c] = b[c] - mean * sc;
  }
}

// fused bn+relu+maxpool, bf16 in -> bf16 out padded to Cpad
__global__ void pool_bf_k(const u16* __restrict__ X, int C, const float* __restrict__ scsh,
                          int kw, int stride, u16* __restrict__ Y, int Cpad, int Lout) {
  int total = Lout * Cpad;
  for (int i = blockIdx.x * blockDim.x + threadIdx.x; i < total; i += blockDim.x * gridDim.x) {
    int lp = i / Cpad, c = i - lp * Cpad;
    if (c >= C) { Y[i] = (u16)0; continue; }
    float sc = scsh[c], sh = scsh[C + c];
    int l0 = lp * stride;
    float m = 0.f;
    for (int wq = 0; wq < kw; ++wq)
      m = fmaxf(m, fmaf(bf2f(X[(size_t)(l0 + wq) * C + c]), sc, sh));
    Y[i] = f2bf(m);
  }
}

// fused bn+relu+maxpool, bf16 in -> fp32 out (no pad)
__global__ void pool_f32_k(const u16* __restrict__ X, int C, const float* __restrict__ scsh,
                           int kw, int stride, float* __restrict__ Y, int Lout) {
  int total = Lout * C;
  for (int i = blockIdx.x * blockDim.x + threadIdx.x; i < total; i += blockDim.x * gridDim.x) {
    int lp = i / C, c = i - lp * C;
    float sc = scsh[c], sh = scsh[C + c];
    int l0 = lp * stride;
    float m = 0.f;
    for (int wq = 0; wq < kw; ++wq)
      m = fmaxf(m, fmaf(bf2f(X[(size_t)(l0 + wq) * C + c]), sc, sh));
    Y[i] = m;
  }
}

__global__ __launch_bounds__(256) void final_dot_k(
    const float* __restrict__ Y2, const float* __restrict__ Z2,
    const float* __restrict__ wy, const float* __restrict__ by,
    const float* __restrict__ wz, const float* __restrict__ bz,
    float* __restrict__ acc, int L) {
  float s0 = 0.f, s1 = 0.f;
  for (int lp = blockIdx.x * blockDim.x + threadIdx.x; lp < L; lp += blockDim.x * gridDim.x) {
    const float* y = Y2 + (size_t)lp * 200;
    const float* z = Z2 + (size_t)lp * 300;
    float d0 = 0.f, d1 = 0.f;
    for (int k = 0; k < 200; ++k) { float v = y[k]; d0 += v * wy[k]; d1 += v * wy[200 + k]; }
    float e0 = 0.f, e1 = 0.f;
    for (int k = 0; k < 300; ++k) { float v = z[k]; e0 += v * wz[k]; e1 += v * wz[300 + k]; }
    s0 += (d0 + by[0]) * (e0 + bz[0]);
    s1 += (d1 + by[1]) * (e1 + bz[1]);
  }
  __shared__ float r0[256], r1[256];
  r0[threadIdx.x] = s0; r1[threadIdx.x] = s1;
  __syncthreads();
  for (int off = 128; off > 0; off >>= 1) {
    if (threadIdx.x < off) { r0[threadIdx.x] += r0[threadIdx.x + off]; r1[threadIdx.x] += r1[threadIdx.x + off]; }
    __syncthreads();
  }
  if (threadIdx.x == 0) { atomicAdd(&acc[0], r0[0]); atomicAdd(&acc[1], r1[0]); }
}

__global__ void final_out_k(const float* __restrict__ acc, float invL, float* __restrict__ out) {
  int j = threadIdx.x;
  if (j < 2) out[j] = 1.f / (1.f + expf(-acc[j] * invL));
}

// ---------------- host ----------------

static inline void gemmL(hipStream_t st, const u16* A, int lda, const u16* B, int ldb,
                         float* Cf, int ldc, u16* Cb, int ldcb,
                         int M, int Nn, int K, const float* bias, int acc) {
  dim3 g((Nn + 63) / 64, (M + 127) / 128);
  gemm_mfma<<<g, 256, 0, st>>>(A, lda, B, ldb, Cf, ldc, Cb, ldcb, M, Nn, K, bias, acc);
}

extern "C" void kernel_launch(void* const* d_in, const int* in_sizes, int n_in,
                              void* d_out, int out_size, void* d_ws, size_t ws_size,
                              hipStream_t stream) {
  (void)n_in; (void)out_size;
  const float* feat    = (const float*)d_in[0];
  const int*   eix     = (const int*)d_in[1];
  const int*   etyp    = (const int*)d_in[2];
  const float* ggnnW   = (const float*)d_in[3];
  const float* ggnnB   = (const float*)d_in[4];
  const float* Wih     = (const float*)d_in[5];
  const float* Whh     = (const float*)d_in[6];
  const float* bih     = (const float*)d_in[7];
  const float* bhh     = (const float*)d_in[8];
  const float* conv1w  = (const float*)d_in[9];
  const float* conv2w  = (const float*)d_in[11];
  const float* convc1w = (const float*)d_in[13];
  const float* convc2w = (const float*)d_in[15];
  const float* bnyg    = (const float*)d_in[17];
  const float* bnyb    = (const float*)d_in[18];
  const float* bncg    = (const float*)d_in[19];
  const float* bncb    = (const float*)d_in[20];
  const float* mlpyw   = (const float*)d_in[21];
  const float* mlpyb   = (const float*)d_in[22];
  const float* mlpzw   = (const float*)d_in[23];
  const float* mlpzb   = (const float*)d_in[24];

  const int N = in_sizes[0] / 100;
  const int E = in_sizes[2];
  const int* src = eix;
  const int* dst = eix + E;

  char* base = (char*)d_ws;
  const size_t RA = (size_t)N * 200 * 4;   // fp32 node buffer region
  const size_t RU = (size_t)N * 224 * 2;   // bf16 node buffer region

  float* abuf = (float*)base;              // RegA
  u16* h_b = (u16*)(base + RA);            // RegB
  u16* s_b = (u16*)(base + RA + RU);       // RegC
  u16* a_b = (u16*)(base + RA + 2 * RU);   // RegD

  // weights (bf16, padded)
  size_t WOFF = RA + 3 * RU;
  u16* Wgb  = (u16*)(base + WOFF);     // 4*200*224
  u16* Wihb = Wgb + 4 * 200 * 224;     // 600*224
  u16* Whhb = Wihb + 600 * 224;        // 600*224
  u16* w1b  = Whhb + 600 * 224;        // 200*672
  u16* c2b  = w1b + 200 * 672;         // 200*224
  u16* wc1b = c2b + 200 * 224;         // 300*1056
  u16* wc2b = wc1b + 300 * 1056;       // 300*320
  float* stats = (float*)(wc2b + 300 * 320);
  float* scsh  = stats + 600;
  float* acc2  = scsh + 600;
  int* deg_et = (int*)(acc2 + 8);
  int* off_et = deg_et + 4 * (size_t)N;
  int* cursor = off_et + 4 * (size_t)N;
  int* esrc   = cursor + 4 * (size_t)N;
  size_t need = (size_t)((char*)(esrc + E) - base);

  if (ws_size < need) {
    fail_k<<<1, 64, 0, stream>>>((float*)d_out, -(float)(ws_size >> 20));
    return;
  }

  // ---- CSR build + packs ----
  hipMemsetAsync(deg_et, 0, sizeof(int) * 4 * (size_t)N, stream);
  init_h0_b<<<2048, 256, 0, stream>>>(feat, h_b, N);
  count_deg_k<<<2048, 256, 0, stream>>>(dst, etyp, deg_et, N, E);
  scan4_k<<<1, 1024, 0, stream>>>(deg_et, off_et, 4 * N);
  copy_int_k<<<512, 256, 0, stream>>>(off_et, cursor, 4 * N);
  fill_src_k<<<2048, 256, 0, stream>>>(src, dst, etyp, cursor, esrc, N, E);
  pack_ggnnW_b<<<700, 256, 0, stream>>>(ggnnW, Wgb);
  pack_lin_b<<<525, 256, 0, stream>>>(Wih, Wihb, 600, 200, 224);
  pack_lin_b<<<525, 256, 0, stream>>>(Whh, Whhb, 600, 200, 224);
  pack_conv3_b<<<525, 256, 0, stream>>>(conv1w, w1b, 200, 200, 224);
  pack_lin_b<<<175, 256, 0, stream>>>(conv2w, c2b, 200, 200, 224);
  pack_wc1_b<<<1238, 256, 0, stream>>>(convc1w, wc1b);
  pack_lin_b<<<375, 256, 0, stream>>>(convc2w, wc2b, 300, 300, 320);

  // ---- GGNN 8 steps ----
  const int CH = (N + 7) / 8;     // gate-chunk rows; CH*800*4 bytes <= RU
  float* gch = (float*)s_b;       // gates alias RegC when s dead
  for (int step = 0; step < 8; ++step) {
    abias_k<<<2048, 256, 0, stream>>>(deg_et, ggnnB, abuf, N);
    for (int k = 0; k < 4; ++k) {
      aggregate_b_k<<<2048, 256, 0, stream>>>(off_et + (size_t)k * N, deg_et + (size_t)k * N,
                                              esrc, h_b, s_b, N);
      gemmL(stream, s_b, 224, Wgb + (size_t)k * 44800, 224,
            abuf, 200, (k == 3) ? a_b : nullptr, 224, N, 200, 224, nullptr, 1);
    }
    for (int c0 = 0; c0 < N; c0 += CH) {
      int Nc = (c0 + CH <= N) ? CH : (N - c0);
      float* grz = gch;                       // Nc*400
      float* inn = gch + (size_t)CH * 400;    // Nc*200
      float* hnb = gch + (size_t)CH * 600;    // Nc*200
      const u16* a_c = a_b + (size_t)c0 * 224;
      u16* h_c = h_b + (size_t)c0 * 224;
      gemmL(stream, a_c, 224, Wihb, 224, grz, 400, nullptr, 0, Nc, 400, 224, bih, 0);
      gemmL(stream, h_c, 224, Whhb, 224, grz, 400, nullptr, 0, Nc, 400, 224, bhh, 1);
      gemmL(stream, a_c, 224, Wihb + 400 * 224, 224, inn, 200, nullptr, 0, Nc, 200, 224, bih + 400, 0);
      gemmL(stream, h_c, 224, Whhb + 400 * 224, 224, hnb, 200, nullptr, 0, Nc, 200, 224, bhh + 400, 0);
      gru_b_k<<<2048, 256, 0, stream>>>(grz, inn, hnb, h_c, Nc);
    }
  }

  // ---- conv paths ----
  const int L1 = N - 2;
  const int L2 = (L1 - 3) / 2 + 1;
  const int L3 = (L2 - 2) / 2 + 1;

  u16*   out1_b  = (u16*)base;                          // L1*200 bf16 (RegA)
  float* Y2b     = (float*)base;                        // L3*200 fp32 (RegA, after out1 dead)
  u16*   outc1_b = (u16*)(base + (size_t)L3 * 200 * 4); // L1*300 bf16
  float* Z2b     = (float*)(base + (size_t)L3 * 200 * 4);
  u16*   y1_b    = s_b;                                 // L2*224
  u16*   out2_b  = a_b;                                 // L2*200
  u16*   cmat    = s_b;                                 // N*352 (spans RegC+RegD)
  u16*   z1_b    = s_b;                                 // L2*320
  u16*   outc2_b = a_b;                                 // L2*300

  // Y path: conv1 (k=3) as ONE GEMM with K=3*224 via row-shift trick
  gemmL(stream, h_b, 224, w1b, 672, nullptr, 0, out1_b, 200, L1, 200, 672, nullptr, 0);
  hipMemsetAsync(stats, 0, sizeof(float) * 400, stream);
  bn_stats_b_k<<<1024, 256, 0, stream>>>(out1_b, L1 * 200, 200, stats);
  bn_fin_k<<<2, 256, 0, stream>>>(stats, bnyg, bnyb, 200, 1.f / (float)L1, scsh);
  pool_bf_k<<<2048, 256, 0, stream>>>(out1_b, 200, scsh, 3, 2, y1_b, 224, L2);

  gemmL(stream, y1_b, 224, c2b, 224, nullptr, 0, out2_b, 200, L2, 200, 224, nullptr, 0);
  hipMemsetAsync(stats, 0, sizeof(float) * 400, stream);
  bn_stats_b_k<<<1024, 256, 0, stream>>>(out2_b, L2 * 200, 200, stats);
  bn_fin_k<<<2, 256, 0, stream>>>(stats, bnyg, bnyb, 200, 1.f / (float)L2, scsh);
  pool_f32_k<<<2048, 256, 0, stream>>>(out2_b, 200, scsh, 2, 2, Y2b, L3);

  // Z path: cmat = [h|feat] (bf16), convc1 as ONE GEMM with K=3*352
  cmat_k<<<2048, 256, 0, stream>>>(h_b, feat, cmat, N);
  gemmL(stream, cmat, 352, wc1b, 1056, nullptr, 0, outc1_b, 300, L1, 300, 1056, nullptr, 0);
  hipMemsetAsync(stats, 0, sizeof(float) * 600, stream);
  bn_stats_b_k<<<1024, 256, 0, stream>>>(outc1_b, L1 * 300, 300, stats);
  bn_fin_k<<<2, 256, 0, stream>>>(stats, bncg, bncb, 300, 1.f / (float)L1, scsh);
  pool_bf_k<<<2048, 256, 0, stream>>>(outc1_b, 300, scsh, 3, 2, z1_b, 320, L2);

  gemmL(stream, z1_b, 320, wc2b, 320, nullptr, 0, outc2_b, 300, L2, 300, 320, nullptr, 0);
  hipMemsetAsync(stats, 0, sizeof(float) * 600, stream);
  bn_stats_b_k<<<1024, 256, 0, stream>>>(outc2_b, L2 * 300, 300, stats);
  bn_fin_k<<<2, 256, 0, stream>>>(stats, bncg, bncb, 300, 1.f / (float)L2, scsh);
  pool_f32_k<<<2048, 256, 0, stream>>>(outc2_b, 300, scsh, 2, 2, Z2b, L3);

  // ---- final MLP product + mean + sigmoid ----
  hipMemsetAsync(acc2, 0, sizeof(float) * 2, stream);
  final_dot_k<<<256, 256, 0, stream>>>(Y2b, Z2b, mlpyw, mlpyb, mlpzw, mlpzb, acc2, L3);
  final_out_k<<<1, 64, 0, stream>>>(acc2, 1.f / (float)L3, (float*)d_out);
}

// Round 4
// 7794.560 us; speedup vs baseline: 2.6991x; 1.6209x over previous
//
#include <hip/hip_runtime.h>
#include <cstddef>
#include <cstdint>

// ============================================================================
// DevignModel round 4: restructured GGNN.
//  - a = s_cat@Wcat^T in ONE GEMM per chunk (K=832, deg-cols fold the bias)
//  - rz  = [a|h]@Wrz^T in ONE GEMM (K=448) -> gi+gh summed in MFMA accumulator
//  - all activations & gates bf16; 2 node-chunks of ~50k; ~188 MB workspace
// ============================================================================

typedef unsigned short u16;
typedef __attribute__((ext_vector_type(8))) short bf16x8;
typedef __attribute__((ext_vector_type(4))) float f32x4;
typedef __attribute__((ext_vector_type(8))) unsigned short u16x8;
typedef __attribute__((ext_vector_type(4))) unsigned short u16x4;

static __device__ __forceinline__ float bf2f(u16 u) {
  union { unsigned int i; float f; } v; v.i = ((unsigned int)u) << 16; return v.f;
}
static __device__ __forceinline__ u16 f2bf(float f) {
  union { float f; unsigned int i; } v; v.f = f;
  unsigned int r = v.i + 0x7FFFu + ((v.i >> 16) & 1u);
  return (u16)(r >> 16);
}
static __device__ __forceinline__ float sigm(float x) { return 1.f / (1.f + __expf(-x)); }

__global__ void fail_k(float* out, float code) { out[0] = code; out[1] = code; }

// ah[n][448]: [a(200)+pad24 | h(200)+pad24]; h0 = [feat | 0]
__global__ void init_ah_k(const float* __restrict__ feat, u16* __restrict__ ah, int N) {
  int total = N * 448;
  for (int i = blockIdx.x * blockDim.x + threadIdx.x; i < total; i += blockDim.x * gridDim.x) {
    int n = i / 448, j = i - n * 448;
    u16 v = 0;
    if (j >= 224 && j < 324) v = f2bf(feat[(size_t)n * 100 + (j - 224)]);
    ah[i] = v;
  }
}

__global__ void count_deg_k(const int* __restrict__ dst, const int* __restrict__ et,
                            int* __restrict__ deg_et, int N, int E) {
  for (int e = blockIdx.x * blockDim.x + threadIdx.x; e < E; e += blockDim.x * gridDim.x)
    atomicAdd(&deg_et[et[e] * N + dst[e]], 1);
}

__global__ void scan4_k(const int* __restrict__ cnt, int* __restrict__ off, int L) {
  __shared__ int buf[1024];
  __shared__ int carry;
  if (threadIdx.x == 0) carry = 0;
  __syncthreads();
  for (int base = 0; base < L; base += 1024) {
    int i = base + threadIdx.x;
    int v = (i < L) ? cnt[i] : 0;
    buf[threadIdx.x] = v;
    __syncthreads();
    for (int o = 1; o < 1024; o <<= 1) {
      int t = (threadIdx.x >= o) ? buf[threadIdx.x - o] : 0;
      __syncthreads();
      buf[threadIdx.x] += t;
      __syncthreads();
    }
    if (i < L) off[i] = buf[threadIdx.x] - v + carry;
    int tot = buf[1023];
    __syncthreads();
    if (threadIdx.x == 0) carry += tot;
    __syncthreads();
  }
}

__global__ void copy_int_k(const int* __restrict__ a, int* __restrict__ b, int n) {
  for (int i = blockIdx.x * blockDim.x + threadIdx.x; i < n; i += blockDim.x * gridDim.x) b[i] = a[i];
}

__global__ void fill_src_k(const int* __restrict__ src, const int* __restrict__ dst,
                           const int* __restrict__ et, int* __restrict__ cursor,
                           int* __restrict__ esrc, int N, int E) {
  for (int e = blockIdx.x * blockDim.x + threadIdx.x; e < E; e += blockDim.x * gridDim.x) {
    int p = atomicAdd(&cursor[et[e] * N + dst[e]], 1);
    esrc[p] = src[e];
  }
}

// ---- weight packs ----

// Wcat[200][832]: [o][k*200+kk]=W[k][o][kk]; [o][800+k]=b[k][o]; else 0
__global__ void pack_wcat_k(const float* __restrict__ W, const float* __restrict__ gb,
                            u16* __restrict__ dst) {
  int total = 200 * 832;
  for (int i = blockIdx.x * blockDim.x + threadIdx.x; i < total; i += blockDim.x * gridDim.x) {
    int o = i / 832, kp = i - o * 832;
    float v = 0.f;
    if (kp < 800) { int k = kp / 200, kk = kp - k * 200; v = W[((size_t)k * 200 + o) * 200 + kk]; }
    else if (kp < 804) v = gb[(kp - 800) * 200 + o];
    dst[i] = f2bf(v);
  }
}

// Wrz[400][448]: [j][kk<200]=Wih[j][kk]; [j][224+kk]=Whh[j][kk]; else 0
__global__ void pack_wrz_k(const float* __restrict__ Wih, const float* __restrict__ Whh,
                           u16* __restrict__ dst) {
  int total = 400 * 448;
  for (int i = blockIdx.x * blockDim.x + threadIdx.x; i < total; i += blockDim.x * gridDim.x) {
    int j = i / 448, kp = i - j * 448;
    float v = 0.f;
    if (kp < 200) v = Wih[(size_t)j * 200 + kp];
    else if (kp >= 224 && kp < 424) v = Whh[(size_t)j * 200 + (kp - 224)];
    dst[i] = f2bf(v);
  }
}

__global__ void brz_k(const float* __restrict__ bih, const float* __restrict__ bhh,
                      float* __restrict__ brz) {
  int j = blockIdx.x * blockDim.x + threadIdx.x;
  if (j < 400) brz[j] = bih[j] + bhh[j];
}

// generic linear pack: src [Nn][K] -> dst [Nn][Kp] (zero pad)
__global__ void pack_lin_b(const float* __restrict__ src, u16* __restrict__ dst,
                           int Nn, int K, int Kp) {
  int total = Nn * Kp;
  for (int i = blockIdx.x * blockDim.x + threadIdx.x; i < total; i += blockDim.x * gridDim.x) {
    int o = i / Kp, kp = i - o * Kp;
    dst[i] = (kp < K) ? f2bf(src[(size_t)o * K + kp]) : (u16)0;
  }
}

// conv1 over cmat layout: w1c[200][1056], [o][t*352+kp] = conv1w[o][kp][t] (kp<200)
__global__ void pack_w1c_k(const float* __restrict__ src, u16* __restrict__ dst) {
  int total = 200 * 1056;
  for (int i = blockIdx.x * blockDim.x + threadIdx.x; i < total; i += blockDim.x * gridDim.x) {
    int o = i / 1056, r = i - o * 1056;
    int t = r / 352, kp = r - t * 352;
    dst[i] = (kp < 200) ? f2bf(src[((size_t)o * 200 + kp) * 3 + t]) : (u16)0;
  }
}

// convc1 [300][300][3] -> [300][1056] matching cmat layout [h(224)|feat(128)]
__global__ void pack_wc1_b(const float* __restrict__ src, u16* __restrict__ dst) {
  int total = 300 * 1056;
  for (int i = blockIdx.x * blockDim.x + threadIdx.x; i < total; i += blockDim.x * gridDim.x) {
    int o = i / 1056, r = i - o * 1056;
    int t = r / 352, kp = r - t * 352;
    int ci = (kp < 224) ? (kp < 200 ? kp : -1) : ((kp - 224) < 100 ? 200 + (kp - 224) : -1);
    dst[i] = (ci >= 0) ? f2bf(src[((size_t)o * 300 + ci) * 3 + t]) : (u16)0;
  }
}

// aggregation: wave per (node, etype); scat[n-n0][832] = [s0|s1|s2|s3|deg0..3|0...]
__global__ void agg_k(const int* __restrict__ off_et, const int* __restrict__ deg_et,
                      const int* __restrict__ esrc, const u16* __restrict__ ah,
                      u16* __restrict__ scat, int n0, int Nc, int N) {
  int gtid = blockIdx.x * blockDim.x + threadIdx.x;
  int wid = gtid >> 6, lane = threadIdx.x & 63;
  int nw = (blockDim.x * gridDim.x) >> 6;
  int total = Nc * 4;
  for (int u = wid; u < total; u += nw) {
    int n = n0 + (u >> 2), k = u & 3;
    u16* srow = scat + (size_t)(u >> 2) * 832;
    if (lane < 50) {
      int rs = off_et[(size_t)k * N + n], d = deg_et[(size_t)k * N + n];
      float a0 = 0.f, a1 = 0.f, a2 = 0.f, a3 = 0.f;
      for (int i = 0; i < d; ++i) {
        const u16* hr = ah + (size_t)esrc[rs + i] * 448 + 224 + lane * 4;
        u16x4 v = *reinterpret_cast<const u16x4*>(hr);
        a0 += bf2f(v[0]); a1 += bf2f(v[1]); a2 += bf2f(v[2]); a3 += bf2f(v[3]);
      }
      u16x4 r;
      r[0] = f2bf(a0); r[1] = f2bf(a1); r[2] = f2bf(a2); r[3] = f2bf(a3);
      *reinterpret_cast<u16x4*>(srow + k * 200 + lane * 4) = r;
    } else if (k == 0 && lane == 50) {
      u16x4 r;
#pragma unroll
      for (int kk = 0; kk < 4; ++kk) r[kk] = f2bf((float)deg_et[(size_t)kk * N + n]);
      *reinterpret_cast<u16x4*>(srow + 800) = r;
    } else if (k == 1 && lane >= 51 && lane <= 57) {
      u16x4 z; z[0] = z[1] = z[2] = z[3] = 0;
      *reinterpret_cast<u16x4*>(srow + 804 + (lane - 51) * 4) = z;
    }
  }
}

// ---------------- bf16 MFMA GEMM: Cb[M, 0:Nn] = A[M,K]@B[Nn,K]^T (+bias); cols [Nn,npad) zeroed
__global__ __launch_bounds__(256) void gemm_mfma(
    const u16* __restrict__ A, int lda,
    const u16* __restrict__ B, int ldb,
    u16* __restrict__ Cb, int ldcb, int npad,
    int M, int Nn, int K, const float* __restrict__ bias) {
  __shared__ u16 As[128 * 40];  // 32 k + 8 pad
  __shared__ u16 Bs[64 * 40];
  const int tid = threadIdx.x;
  const int lane = tid & 63;
  const int w = tid >> 6;
  const int wr = w >> 1, wc = w & 1;
  const int m0 = blockIdx.y * 128;
  const int n0 = blockIdx.x * 64;
  const int srow = tid >> 2;
  const int skg = (tid & 3) * 8;
  const int fr = lane & 15;
  const int fk = (lane >> 4) * 8;

  f32x4 acc[4][2] = {};

  for (int k0 = 0; k0 < K; k0 += 32) {
    u16x8 va0 = 0, va1 = 0, vb = 0;
    int ra0 = m0 + srow, ra1 = m0 + srow + 64, rb = n0 + srow;
    if (ra0 < M) va0 = *reinterpret_cast<const u16x8*>(A + (size_t)ra0 * lda + k0 + skg);
    if (ra1 < M) va1 = *reinterpret_cast<const u16x8*>(A + (size_t)ra1 * lda + k0 + skg);
    if (rb < Nn) vb = *reinterpret_cast<const u16x8*>(B + (size_t)rb * ldb + k0 + skg);
    __syncthreads();
    *reinterpret_cast<u16x8*>(&As[srow * 40 + skg]) = va0;
    *reinterpret_cast<u16x8*>(&As[(srow + 64) * 40 + skg]) = va1;
    *reinterpret_cast<u16x8*>(&Bs[srow * 40 + skg]) = vb;
    __syncthreads();

    bf16x8 af[4], bfr[2];
#pragma unroll
    for (int i = 0; i < 4; ++i)
      af[i] = *reinterpret_cast<const bf16x8*>(&As[(wr * 64 + i * 16 + fr) * 40 + fk]);
#pragma unroll
    for (int j = 0; j < 2; ++j)
      bfr[j] = *reinterpret_cast<const bf16x8*>(&Bs[(wc * 32 + j * 16 + fr) * 40 + fk]);
#pragma unroll
    for (int i = 0; i < 4; ++i)
#pragma unroll
      for (int j = 0; j < 2; ++j)
        acc[i][j] = __builtin_amdgcn_mfma_f32_16x16x32_bf16(af[i], bfr[j], acc[i][j], 0, 0, 0);
  }

  const int er = (lane >> 4) * 4;
  const int ec = lane & 15;
#pragma unroll
  for (int i = 0; i < 4; ++i) {
#pragma unroll
    for (int j = 0; j < 2; ++j) {
      int n = n0 + wc * 32 + j * 16 + ec;
#pragma unroll
      for (int r = 0; r < 4; ++r) {
        int m = m0 + wr * 64 + i * 16 + er + r;
        if (m >= M) continue;
        if (n < Nn) {
          float v = acc[i][j][r];
          if (bias) v += bias[n];
          Cb[(size_t)m * ldcb + n] = f2bf(v);
        } else if (n < npad) {
          Cb[(size_t)m * ldcb + n] = (u16)0;
        }
      }
    }
  }
}

// GRU pointwise: h := (1-z)*tanh(inn + r*hn) + z*h   (bf16 gates, h in ah)
__global__ void gru_b_k(const u16* __restrict__ rz, const u16* __restrict__ inn,
                        const u16* __restrict__ hn, u16* __restrict__ ah, int c0, int Nc) {
  int total = Nc * 200;
  for (int i = blockIdx.x * blockDim.x + threadIdx.x; i < total; i += blockDim.x * gridDim.x) {
    int n = i / 200, o = i - n * 200;
    float r = sigm(bf2f(rz[(size_t)n * 400 + o]));
    float z = sigm(bf2f(rz[(size_t)n * 400 + 200 + o]));
    float x = bf2f(inn[(size_t)n * 224 + o]) + r * bf2f(hn[(size_t)n * 224 + o]);
    float e2 = __expf(2.f * x);
    float nn = (e2 - 1.f) / (e2 + 1.f);
    size_t hi = (size_t)(c0 + n) * 448 + 224 + o;
    float hold = bf2f(ah[hi]);
    ah[hi] = f2bf((1.f - z) * nn + z * hold);
  }
}

// cmat[n][352] = [h(224 incl zero pads) | feat(100) | 0(28)]
__global__ void cmat_k(const u16* __restrict__ ah, const float* __restrict__ feat,
                       u16* __restrict__ c, int N) {
  int total = N * 352;
  for (int i = blockIdx.x * blockDim.x + threadIdx.x; i < total; i += blockDim.x * gridDim.x) {
    int n = i / 352, j = i - n * 352;
    u16 v;
    if (j < 224) v = ah[(size_t)n * 448 + 224 + j];
    else { int f = j - 224; v = (f < 100) ? f2bf(feat[(size_t)n * 100 + f]) : (u16)0; }
    c[i] = v;
  }
}

__global__ __launch_bounds__(256) void bn_stats_b_k(const u16* __restrict__ X, int total, int C,
                                                    float* __restrict__ stats) {
  __shared__ float sb[300], qb[300];
  for (int c = threadIdx.x; c < C; c += blockDim.x) { sb[c] = 0.f; qb[c] = 0.f; }
  __syncthreads();
  for (int i = blockIdx.x * blockDim.x + threadIdx.x; i < total; i += blockDim.x * gridDim.x) {
    float v = bf2f(X[i]);
    int c = i % C;
    atomicAdd(&sb[c], v);
    atomicAdd(&qb[c], v * v);
  }
  __syncthreads();
  for (int c = threadIdx.x; c < C; c += blockDim.x) {
    atomicAdd(&stats[c], sb[c]);
    atomicAdd(&stats[C + c], qb[c]);
  }
}

__global__ void bn_fin_k(const float* __restrict__ stats, const float* __restrict__ g,
                         const float* __restrict__ b, int C, float Linv,
                         float* __restrict__ scsh) {
  int c = blockIdx.x * blockDim.x + threadIdx.x;
  if (c < C) {
    float mean = stats[c] * Linv;
    float var = stats[C + c] * Linv - mean * mean;
    float sc = g[c] * rsqrtf(var + 1e-5f);
    scsh[c] = sc;
    scsh[C + c] = b[c] - mean * sc;
  }
}

__global__ void pool_bf_k(const u16* __restrict__ X, int C, const float* __restrict__ scsh,
                          int kw, int stride, u16* __restrict__ Y, int Cpad, int Lout) {
  int total = Lout * Cpad;
  for (int i = blockIdx.x * blockDim.x + threadIdx.x; i < total; i += blockDim.x * gridDim.x) {
    int lp = i / Cpad, c = i - lp * Cpad;
    if (c >= C) { Y[i] = (u16)0; continue; }
    float sc = scsh[c], sh = scsh[C + c];
    int l0 = lp * stride;
    float m = 0.f;
    for (int wq = 0; wq < kw; ++wq)
      m = fmaxf(m, fmaf(bf2f(X[(size_t)(l0 + wq) * C + c]), sc, sh));
    Y[i] = f2bf(m);
  }
}

__global__ void pool_f32_k(const u16* __restrict__ X, int C, const float* __restrict__ scsh,
                           int kw, int stride, float* __restrict__ Y, int Lout) {
  int total = Lout * C;
  for (int i = blockIdx.x * blockDim.x + threadIdx.x; i < total; i += blockDim.x * gridDim.x) {
    int lp = i / C, c = i - lp * C;
    float sc = scsh[c], sh = scsh[C + c];
    int l0 = lp * stride;
    float m = 0.f;
    for (int wq = 0; wq < kw; ++wq)
      m = fmaxf(m, fmaf(bf2f(X[(size_t)(l0 + wq) * C + c]), sc, sh));
    Y[i] = m;
  }
}

__global__ __launch_bounds__(256) void final_dot_k(
    const float* __restrict__ Y2, const float* __restrict__ Z2,
    const float* __restrict__ wy, const float* __restrict__ by,
    const float* __restrict__ wz, const float* __restrict__ bz,
    float* __restrict__ acc, int L) {
  float s0 = 0.f, s1 = 0.f;
  for (int lp = blockIdx.x * blockDim.x + threadIdx.x; lp < L; lp += blockDim.x * gridDim.x) {
    const float* y = Y2 + (size_t)lp * 200;
    const float* z = Z2 + (size_t)lp * 300;
    float d0 = 0.f, d1 = 0.f;
    for (int k = 0; k < 200; ++k) { float v = y[k]; d0 += v * wy[k]; d1 += v * wy[200 + k]; }
    float e0 = 0.f, e1 = 0.f;
    for (int k = 0; k < 300; ++k) { float v = z[k]; e0 += v * wz[k]; e1 += v * wz[300 + k]; }
    s0 += (d0 + by[0]) * (e0 + bz[0]);
    s1 += (d1 + by[1]) * (e1 + bz[1]);
  }
  __shared__ float r0[256], r1[256];
  r0[threadIdx.x] = s0; r1[threadIdx.x] = s1;
  __syncthreads();
  for (int off = 128; off > 0; off >>= 1) {
    if (threadIdx.x < off) { r0[threadIdx.x] += r0[threadIdx.x + off]; r1[threadIdx.x] += r1[threadIdx.x + off]; }
    __syncthreads();
  }
  if (threadIdx.x == 0) { atomicAdd(&acc[0], r0[0]); atomicAdd(&acc[1], r1[0]); }
}

__global__ void final_out_k(const float* __restrict__ acc, float invL, float* __restrict__ out) {
  int j = threadIdx.x;
  if (j < 2) out[j] = 1.f / (1.f + expf(-acc[j] * invL));
}

// ---------------- host ----------------

static inline void gemmL(hipStream_t st, const u16* A, int lda, const u16* B, int ldb,
                         u16* Cb, int ldcb, int npad, int M, int Nn, int K, const float* bias) {
  int ncols = (npad > Nn) ? npad : Nn;
  dim3 g((ncols + 63) / 64, (M + 127) / 128);
  gemm_mfma<<<g, 256, 0, st>>>(A, lda, B, ldb, Cb, ldcb, npad, M, Nn, K, bias);
}

extern "C" void kernel_launch(void* const* d_in, const int* in_sizes, int n_in,
                              void* d_out, int out_size, void* d_ws, size_t ws_size,
                              hipStream_t stream) {
  (void)n_in; (void)out_size;
  const float* feat    = (const float*)d_in[0];
  const int*   eix     = (const int*)d_in[1];
  const int*   etyp    = (const int*)d_in[2];
  const float* ggnnW   = (const float*)d_in[3];
  const float* ggnnB   = (const float*)d_in[4];
  const float* Wih     = (const float*)d_in[5];
  const float* Whh     = (const float*)d_in[6];
  const float* bih     = (const float*)d_in[7];
  const float* bhh     = (const float*)d_in[8];
  const float* conv1w  = (const float*)d_in[9];
  const float* conv2w  = (const float*)d_in[11];
  const float* convc1w = (const float*)d_in[13];
  const float* convc2w = (const float*)d_in[15];
  const float* bnyg    = (const float*)d_in[17];
  const float* bnyb    = (const float*)d_in[18];
  const float* bncg    = (const float*)d_in[19];
  const float* bncb    = (const float*)d_in[20];
  const float* mlpyw   = (const float*)d_in[21];
  const float* mlpyb   = (const float*)d_in[22];
  const float* mlpzw   = (const float*)d_in[23];
  const float* mlpzb   = (const float*)d_in[24];

  const int N = in_sizes[0] / 100;
  const int E = in_sizes[2];
  const int* src = eix;
  const int* dst = eix + E;

  char* base = (char*)d_ws;
  const size_t AH_B = (size_t)N * 448 * 2;     // region R0
  const int CH = (N + 1) / 2;
  const size_t SCR_B = (size_t)CH * 1696;      // region R1 (scat 1664 B/row, gates 1696 B/row)

  u16* ah = (u16*)base;
  char* R1 = base + AH_B;
  char* WREG = R1 + SCR_B;

  u16* Wcat = (u16*)WREG;          // 200*832
  u16* Wrz  = Wcat + 166400;       // 400*448
  u16* Winn = Wrz + 179200;        // 200*224
  u16* Whn  = Winn + 44800;        // 200*224
  u16* w1c  = Whn + 44800;         // 200*1056
  u16* c2b  = w1c + 211200;        // 200*224
  u16* wc1  = c2b + 44800;         // 300*1056
  u16* wc2  = wc1 + 316800;        // 300*320
  float* brz   = (float*)(wc2 + 96000);  // 400
  float* stats = brz + 400;              // 600
  float* scsh  = stats + 600;            // 600
  float* acc2  = scsh + 600;             // 2 (+pad)
  int* deg_et = (int*)(acc2 + 4);
  int* off_et = deg_et + 4 * (size_t)N;
  int* cursor = off_et + 4 * (size_t)N;
  int* esrc   = cursor + 4 * (size_t)N;
  size_t need = (size_t)((char*)(esrc + E) - base);

  if (ws_size < need) {
    fail_k<<<1, 64, 0, stream>>>((float*)d_out, -(float)(ws_size >> 20));
    return;
  }

  // ---- CSR build + packs ----
  hipMemsetAsync(deg_et, 0, sizeof(int) * 4 * (size_t)N, stream);
  init_ah_k<<<4096, 256, 0, stream>>>(feat, ah, N);
  count_deg_k<<<2048, 256, 0, stream>>>(dst, etyp, deg_et, N, E);
  scan4_k<<<1, 1024, 0, stream>>>(deg_et, off_et, 4 * N);
  copy_int_k<<<512, 256, 0, stream>>>(off_et, cursor, 4 * N);
  fill_src_k<<<2048, 256, 0, stream>>>(src, dst, etyp, cursor, esrc, N, E);
  pack_wcat_k<<<651, 256, 0, stream>>>(ggnnW, ggnnB, Wcat);
  pack_wrz_k<<<700, 256, 0, stream>>>(Wih, Whh, Wrz);
  brz_k<<<2, 256, 0, stream>>>(bih, bhh, brz);
  pack_lin_b<<<175, 256, 0, stream>>>(Wih + 400 * 200, Winn, 200, 200, 224);
  pack_lin_b<<<175, 256, 0, stream>>>(Whh + 400 * 200, Whn, 200, 200, 224);
  pack_w1c_k<<<825, 256, 0, stream>>>(conv1w, w1c);
  pack_lin_b<<<175, 256, 0, stream>>>(conv2w, c2b, 200, 200, 224);
  pack_wc1_b<<<1238, 256, 0, stream>>>(convc1w, wc1);
  pack_lin_b<<<375, 256, 0, stream>>>(convc2w, wc2, 300, 300, 320);

  // ---- GGNN 8 steps ----
  u16* scat  = (u16*)R1;                      // CH x 832
  u16* rz_c  = (u16*)R1;                      // CH x 400
  u16* inn_c = rz_c + (size_t)CH * 400;       // CH x 224
  u16* hn_c  = inn_c + (size_t)CH * 224;      // CH x 224

  for (int step = 0; step < 8; ++step) {
    // phase A: a = s_cat @ Wcat^T (bias folded via deg cols), per chunk
    for (int c0 = 0; c0 < N; c0 += CH) {
      int Nc = (c0 + CH <= N) ? CH : (N - c0);
      agg_k<<<4096, 256, 0, stream>>>(off_et, deg_et, esrc, ah, scat, c0, Nc, N);
      gemmL(stream, scat, 832, Wcat, 832, ah + (size_t)c0 * 448, 448, 224,
            Nc, 200, 832, nullptr);
    }
    // phase B: gates + GRU update, per chunk
    for (int c0 = 0; c0 < N; c0 += CH) {
      int Nc = (c0 + CH <= N) ? CH : (N - c0);
      const u16* ahc = ah + (size_t)c0 * 448;
      gemmL(stream, ahc, 448, Wrz, 448, rz_c, 400, 400, Nc, 400, 448, brz);
      gemmL(stream, ahc, 448, Winn, 224, inn_c, 224, 224, Nc, 200, 224, bih + 400);
      gemmL(stream, ahc + 224, 448, Whn, 224, hn_c, 224, 224, Nc, 200, 224, bhh + 400);
      gru_b_k<<<2048, 256, 0, stream>>>(rz_c, inn_c, hn_c, ah, c0, Nc);
    }
  }

  // ---- conv paths ----
  const int L1 = N - 2;
  const int L2 = (L1 - 3) / 2 + 1;
  const int L3 = (L2 - 2) / 2 + 1;

  u16* cmat = (u16*)R1;                                              // N*352
  u16* out1 = (u16*)base;                                            // L1*200
  size_t y1_off = (((size_t)L1 * 400) + 255) & ~(size_t)255;
  u16* y1 = (u16*)(base + y1_off);                                   // L2*224
  size_t o2_off = y1_off + ((((size_t)L2 * 448) + 255) & ~(size_t)255);
  u16* out2 = (u16*)(base + o2_off);                                 // L2*200
  float* Y2f = (float*)base;                                         // L3*200 f32
  size_t oc1_off = (((size_t)L3 * 800) + 255) & ~(size_t)255;
  u16* outc1 = (u16*)(base + oc1_off);                               // L1*300
  u16* z1 = (u16*)R1;                                                // L2*320
  size_t oc2_off = (((size_t)L2 * 640) + 255) & ~(size_t)255;
  u16* outc2 = (u16*)(R1 + oc2_off);                                 // L2*300
  float* Z2f = (float*)(base + oc1_off);                             // L3*300 f32

  cmat_k<<<4096, 256, 0, stream>>>(ah, feat, cmat, N);

  // Y path
  gemmL(stream, cmat, 352, w1c, 1056, out1, 200, 200, L1, 200, 1056, nullptr);
  hipMemsetAsync(stats, 0, sizeof(float) * 400, stream);
  bn_stats_b_k<<<1024, 256, 0, stream>>>(out1, L1 * 200, 200, stats);
  bn_fin_k<<<2, 256, 0, stream>>>(stats, bnyg, bnyb, 200, 1.f / (float)L1, scsh);
  pool_bf_k<<<2048, 256, 0, stream>>>(out1, 200, scsh, 3, 2, y1, 224, L2);

  gemmL(stream, y1, 224, c2b, 224, out2, 200, 200, L2, 200, 224, nullptr);
  hipMemsetAsync(stats, 0, sizeof(float) * 400, stream);
  bn_stats_b_k<<<1024, 256, 0, stream>>>(out2, L2 * 200, 200, stats);
  bn_fin_k<<<2, 256, 0, stream>>>(stats, bnyg, bnyb, 200, 1.f / (float)L2, scsh);
  pool_f32_k<<<2048, 256, 0, stream>>>(out2, 200, scsh, 2, 2, Y2f, L3);

  // Z path
  gemmL(stream, cmat, 352, wc1, 1056, outc1, 300, 300, L1, 300, 1056, nullptr);
  hipMemsetAsync(stats, 0, sizeof(float) * 600, stream);
  bn_stats_b_k<<<1024, 256, 0, stream>>>(outc1, L1 * 300, 300, stats);
  bn_fin_k<<<2, 256, 0, stream>>>(stats, bncg, bncb, 300, 1.f / (float)L1, scsh);
  pool_bf_k<<<2048, 256, 0, stream>>>(outc1, 300, scsh, 3, 2, z1, 320, L2);

  gemmL(stream, z1, 320, wc2, 320, outc2, 300, 300, L2, 300, 320, nullptr);
  hipMemsetAsync(stats, 0, sizeof(float) * 600, stream);
  bn_stats_b_k<<<1024, 256, 0, stream>>>(outc2, L2 * 300, 300, stats);
  bn_fin_k<<<2, 256, 0, stream>>>(stats, bncg, bncb, 300, 1.f / (float)L2, scsh);
  pool_f32_k<<<2048, 256, 0, stream>>>(outc2, 300, scsh, 2, 2, Z2f, L3);

  // ---- final MLP product + mean + sigmoid ----
  hipMemsetAsync(acc2, 0, sizeof(float) * 2, stream);
  final_dot_k<<<256, 256, 0, stream>>>(Y2f, Z2f, mlpyw, mlpyb, mlpzw, mlpzb, acc2, L3);
  final_out_k<<<1, 64, 0, stream>>>(acc2, 1.f / (float)L3, (float*)d_out);
}

// Round 5
// 6341.156 us; speedup vs baseline: 3.3177x; 1.2292x over previous
//
#include <hip/hip_runtime.h>
#include <cstddef>
#include <cstdint>

// ============================================================================
// DevignModel round 5:
//  - parallel 3-kernel scan (was: 720us single-block scan = top hotspot)
//  - GRU fused into hn-GEMM epilogue (no gru pass, no hn buffer)
//  - bn_stats: fixed-channel coalesced accumulation (no per-element atomics)
// ============================================================================

typedef unsigned short u16;
typedef __attribute__((ext_vector_type(8))) short bf16x8;
typedef __attribute__((ext_vector_type(4))) float f32x4;
typedef __attribute__((ext_vector_type(8))) unsigned short u16x8;
typedef __attribute__((ext_vector_type(4))) unsigned short u16x4;

static __device__ __forceinline__ float bf2f(u16 u) {
  union { unsigned int i; float f; } v; v.i = ((unsigned int)u) << 16; return v.f;
}
static __device__ __forceinline__ u16 f2bf(float f) {
  union { float f; unsigned int i; } v; v.f = f;
  unsigned int r = v.i + 0x7FFFu + ((v.i >> 16) & 1u);
  return (u16)(r >> 16);
}
static __device__ __forceinline__ float sigm(float x) { return 1.f / (1.f + __expf(-x)); }

__global__ void fail_k(float* out, float code) { out[0] = code; out[1] = code; }

// ah[n][448]: [a(200)+pad24 | h(200)+pad24]; h0 = [feat | 0]
__global__ void init_ah_k(const float* __restrict__ feat, u16* __restrict__ ah, int N) {
  int total = N * 448;
  for (int i = blockIdx.x * blockDim.x + threadIdx.x; i < total; i += blockDim.x * gridDim.x) {
    int n = i / 448, j = i - n * 448;
    u16 v = 0;
    if (j >= 224 && j < 324) v = f2bf(feat[(size_t)n * 100 + (j - 224)]);
    ah[i] = v;
  }
}

__global__ void count_deg_k(const int* __restrict__ dst, const int* __restrict__ et,
                            int* __restrict__ deg_et, int N, int E) {
  for (int e = blockIdx.x * blockDim.x + threadIdx.x; e < E; e += blockDim.x * gridDim.x)
    atomicAdd(&deg_et[et[e] * N + dst[e]], 1);
}

// ---- parallel exclusive scan over L ints (3 kernels) ----
__global__ __launch_bounds__(1024) void bsum_k(const int* __restrict__ cnt,
                                               int* __restrict__ bsum, int L) {
  __shared__ int buf[1024];
  int i = blockIdx.x * 1024 + threadIdx.x;
  buf[threadIdx.x] = (i < L) ? cnt[i] : 0;
  __syncthreads();
  for (int o = 512; o > 0; o >>= 1) {
    if (threadIdx.x < o) buf[threadIdx.x] += buf[threadIdx.x + o];
    __syncthreads();
  }
  if (threadIdx.x == 0) bsum[blockIdx.x] = buf[0];
}

__global__ __launch_bounds__(1024) void scanb_k(int* __restrict__ bsum, int nb) {
  __shared__ int buf[1024];
  int v = (threadIdx.x < nb) ? bsum[threadIdx.x] : 0;
  buf[threadIdx.x] = v;
  __syncthreads();
  for (int o = 1; o < 1024; o <<= 1) {
    int t = (threadIdx.x >= o) ? buf[threadIdx.x - o] : 0;
    __syncthreads();
    buf[threadIdx.x] += t;
    __syncthreads();
  }
  if (threadIdx.x < nb) bsum[threadIdx.x] = buf[threadIdx.x] - v;  // exclusive
}

__global__ __launch_bounds__(1024) void scan_fin_k(const int* __restrict__ cnt,
                                                   const int* __restrict__ bsum,
                                                   int* __restrict__ off, int L) {
  __shared__ int buf[1024];
  int i = blockIdx.x * 1024 + threadIdx.x;
  int v = (i < L) ? cnt[i] : 0;
  buf[threadIdx.x] = v;
  __syncthreads();
  for (int o = 1; o < 1024; o <<= 1) {
    int t = (threadIdx.x >= o) ? buf[threadIdx.x - o] : 0;
    __syncthreads();
    buf[threadIdx.x] += t;
    __syncthreads();
  }
  if (i < L) off[i] = buf[threadIdx.x] - v + bsum[blockIdx.x];
}

__global__ void copy_int_k(const int* __restrict__ a, int* __restrict__ b, int n) {
  for (int i = blockIdx.x * blockDim.x + threadIdx.x; i < n; i += blockDim.x * gridDim.x) b[i] = a[i];
}

__global__ void fill_src_k(const int* __restrict__ src, const int* __restrict__ dst,
                           const int* __restrict__ et, int* __restrict__ cursor,
                           int* __restrict__ esrc, int N, int E) {
  for (int e = blockIdx.x * blockDim.x + threadIdx.x; e < E; e += blockDim.x * gridDim.x) {
    int p = atomicAdd(&cursor[et[e] * N + dst[e]], 1);
    esrc[p] = src[e];
  }
}

// ---- weight packs ----

__global__ void pack_wcat_k(const float* __restrict__ W, const float* __restrict__ gb,
                            u16* __restrict__ dst) {
  int total = 200 * 832;
  for (int i = blockIdx.x * blockDim.x + threadIdx.x; i < total; i += blockDim.x * gridDim.x) {
    int o = i / 832, kp = i - o * 832;
    float v = 0.f;
    if (kp < 800) { int k = kp / 200, kk = kp - k * 200; v = W[((size_t)k * 200 + o) * 200 + kk]; }
    else if (kp < 804) v = gb[(kp - 800) * 200 + o];
    dst[i] = f2bf(v);
  }
}

__global__ void pack_wrz_k(const float* __restrict__ Wih, const float* __restrict__ Whh,
                           u16* __restrict__ dst) {
  int total = 400 * 448;
  for (int i = blockIdx.x * blockDim.x + threadIdx.x; i < total; i += blockDim.x * gridDim.x) {
    int j = i / 448, kp = i - j * 448;
    float v = 0.f;
    if (kp < 200) v = Wih[(size_t)j * 200 + kp];
    else if (kp >= 224 && kp < 424) v = Whh[(size_t)j * 200 + (kp - 224)];
    dst[i] = f2bf(v);
  }
}

__global__ void brz_k(const float* __restrict__ bih, const float* __restrict__ bhh,
                      float* __restrict__ brz) {
  int j = blockIdx.x * blockDim.x + threadIdx.x;
  if (j < 400) brz[j] = bih[j] + bhh[j];
}

__global__ void pack_lin_b(const float* __restrict__ src, u16* __restrict__ dst,
                           int Nn, int K, int Kp) {
  int total = Nn * Kp;
  for (int i = blockIdx.x * blockDim.x + threadIdx.x; i < total; i += blockDim.x * gridDim.x) {
    int o = i / Kp, kp = i - o * Kp;
    dst[i] = (kp < K) ? f2bf(src[(size_t)o * K + kp]) : (u16)0;
  }
}

__global__ void pack_w1c_k(const float* __restrict__ src, u16* __restrict__ dst) {
  int total = 200 * 1056;
  for (int i = blockIdx.x * blockDim.x + threadIdx.x; i < total; i += blockDim.x * gridDim.x) {
    int o = i / 1056, r = i - o * 1056;
    int t = r / 352, kp = r - t * 352;
    dst[i] = (kp < 200) ? f2bf(src[((size_t)o * 200 + kp) * 3 + t]) : (u16)0;
  }
}

__global__ void pack_wc1_b(const float* __restrict__ src, u16* __restrict__ dst) {
  int total = 300 * 1056;
  for (int i = blockIdx.x * blockDim.x + threadIdx.x; i < total; i += blockDim.x * gridDim.x) {
    int o = i / 1056, r = i - o * 1056;
    int t = r / 352, kp = r - t * 352;
    int ci = (kp < 224) ? (kp < 200 ? kp : -1) : ((kp - 224) < 100 ? 200 + (kp - 224) : -1);
    dst[i] = (ci >= 0) ? f2bf(src[((size_t)o * 300 + ci) * 3 + t]) : (u16)0;
  }
}

// aggregation: wave per (node, etype); scat[n-n0][832] = [s0|s1|s2|s3|deg0..3|0...]
__global__ void agg_k(const int* __restrict__ off_et, const int* __restrict__ deg_et,
                      const int* __restrict__ esrc, const u16* __restrict__ ah,
                      u16* __restrict__ scat, int n0, int Nc, int N) {
  int gtid = blockIdx.x * blockDim.x + threadIdx.x;
  int wid = gtid >> 6, lane = threadIdx.x & 63;
  int nw = (blockDim.x * gridDim.x) >> 6;
  int total = Nc * 4;
  for (int u = wid; u < total; u += nw) {
    int n = n0 + (u >> 2), k = u & 3;
    u16* srow = scat + (size_t)(u >> 2) * 832;
    if (lane < 50) {
      int rs = off_et[(size_t)k * N + n], d = deg_et[(size_t)k * N + n];
      float a0 = 0.f, a1 = 0.f, a2 = 0.f, a3 = 0.f;
      for (int i = 0; i < d; ++i) {
        const u16* hr = ah + (size_t)esrc[rs + i] * 448 + 224 + lane * 4;
        u16x4 v = *reinterpret_cast<const u16x4*>(hr);
        a0 += bf2f(v[0]); a1 += bf2f(v[1]); a2 += bf2f(v[2]); a3 += bf2f(v[3]);
      }
      u16x4 r;
      r[0] = f2bf(a0); r[1] = f2bf(a1); r[2] = f2bf(a2); r[3] = f2bf(a3);
      *reinterpret_cast<u16x4*>(srow + k * 200 + lane * 4) = r;
    } else if (k == 0 && lane == 50) {
      u16x4 r;
#pragma unroll
      for (int kk = 0; kk < 4; ++kk) r[kk] = f2bf((float)deg_et[(size_t)kk * N + n]);
      *reinterpret_cast<u16x4*>(srow + 800) = r;
    } else if (k == 1 && lane >= 51 && lane <= 57) {
      u16x4 z; z[0] = z[1] = z[2] = z[3] = 0;
      *reinterpret_cast<u16x4*>(srow + 804 + (lane - 51) * 4) = z;
    }
  }
}

// ---------------- bf16 MFMA GEMM ----------------
// mode 0: Cb[M,0:Nn] = A@B^T (+bias); cols [Nn,npad) zeroed.
// mode 1: GRU-final: v = acc+bias = hn; reads rz/inn, updates ah h-slice in place.
__global__ __launch_bounds__(256) void gemm_mfma(
    const u16* __restrict__ A, int lda,
    const u16* __restrict__ B, int ldb,
    u16* __restrict__ Cb, int ldcb, int npad,
    int M, int Nn, int K, const float* __restrict__ bias,
    int mode, const u16* __restrict__ rz, const u16* __restrict__ inn,
    u16* __restrict__ ahout, int c0) {
  __shared__ u16 As[128 * 40];
  __shared__ u16 Bs[64 * 40];
  const int tid = threadIdx.x;
  const int lane = tid & 63;
  const int w = tid >> 6;
  const int wr = w >> 1, wc = w & 1;
  const int m0 = blockIdx.y * 128;
  const int n0 = blockIdx.x * 64;
  const int srow = tid >> 2;
  const int skg = (tid & 3) * 8;
  const int fr = lane & 15;
  const int fk = (lane >> 4) * 8;

  f32x4 acc[4][2] = {};

  for (int k0 = 0; k0 < K; k0 += 32) {
    u16x8 va0 = 0, va1 = 0, vb = 0;
    int ra0 = m0 + srow, ra1 = m0 + srow + 64, rb = n0 + srow;
    if (ra0 < M) va0 = *reinterpret_cast<const u16x8*>(A + (size_t)ra0 * lda + k0 + skg);
    if (ra1 < M) va1 = *reinterpret_cast<const u16x8*>(A + (size_t)ra1 * lda + k0 + skg);
    if (rb < Nn) vb = *reinterpret_cast<const u16x8*>(B + (size_t)rb * ldb + k0 + skg);
    __syncthreads();
    *reinterpret_cast<u16x8*>(&As[srow * 40 + skg]) = va0;
    *reinterpret_cast<u16x8*>(&As[(srow + 64) * 40 + skg]) = va1;
    *reinterpret_cast<u16x8*>(&Bs[srow * 40 + skg]) = vb;
    __syncthreads();

    bf16x8 af[4], bfr[2];
#pragma unroll
    for (int i = 0; i < 4; ++i)
      af[i] = *reinterpret_cast<const bf16x8*>(&As[(wr * 64 + i * 16 + fr) * 40 + fk]);
#pragma unroll
    for (int j = 0; j < 2; ++j)
      bfr[j] = *reinterpret_cast<const bf16x8*>(&Bs[(wc * 32 + j * 16 + fr) * 40 + fk]);
#pragma unroll
    for (int i = 0; i < 4; ++i)
#pragma unroll
      for (int j = 0; j < 2; ++j)
        acc[i][j] = __builtin_amdgcn_mfma_f32_16x16x32_bf16(af[i], bfr[j], acc[i][j], 0, 0, 0);
  }

  const int er = (lane >> 4) * 4;
  const int ec = lane & 15;
#pragma unroll
  for (int i = 0; i < 4; ++i) {
#pragma unroll
    for (int j = 0; j < 2; ++j) {
      int n = n0 + wc * 32 + j * 16 + ec;
#pragma unroll
      for (int r = 0; r < 4; ++r) {
        int m = m0 + wr * 64 + i * 16 + er + r;
        if (m >= M) continue;
        if (mode == 0) {
          if (n < Nn) {
            float v = acc[i][j][r];
            if (bias) v += bias[n];
            Cb[(size_t)m * ldcb + n] = f2bf(v);
          } else if (n < npad) {
            Cb[(size_t)m * ldcb + n] = (u16)0;
          }
        } else {
          if (n < Nn) {
            float hnv = acc[i][j][r] + bias[n];
            float rg = sigm(bf2f(rz[(size_t)m * 400 + n]));
            float zg = sigm(bf2f(rz[(size_t)m * 400 + 200 + n]));
            float x = bf2f(inn[(size_t)m * 224 + n]) + rg * hnv;
            float e2 = __expf(2.f * x);
            float nn = (e2 - 1.f) / (e2 + 1.f);
            size_t hi = (size_t)(c0 + m) * 448 + 224 + n;
            float hold = bf2f(ahout[hi]);
            ahout[hi] = f2bf((1.f - zg) * nn + zg * hold);
          }
        }
      }
    }
  }
}

// cmat[n][352] = [h(224 incl zero pads) | feat(100) | 0(28)]
__global__ void cmat_k(const u16* __restrict__ ah, const float* __restrict__ feat,
                       u16* __restrict__ c, int N) {
  int total = N * 352;
  for (int i = blockIdx.x * blockDim.x + threadIdx.x; i < total; i += blockDim.x * gridDim.x) {
    int n = i / 352, j = i - n * 352;
    u16 v;
    if (j < 224) v = ah[(size_t)n * 448 + 224 + j];
    else { int f = j - 224; v = (f < 100) ? f2bf(feat[(size_t)n * 100 + f]) : (u16)0; }
    c[i] = v;
  }
}

// per-channel stats: fixed channel per thread, coalesced, no hot-loop atomics.
__global__ __launch_bounds__(1024) void bn_stats2_k(const u16* __restrict__ X, int L, int C,
                                                    float* __restrict__ stats) {
  const int Q = 1024 / C;       // rows per sweep-group (5 for C=200, 3 for C=300)
  const int T = Q * C;
  const int tid = threadIdx.x;
  float s = 0.f, q = 0.f;
  int c = 0;
  if (tid < T) {
    int qi = tid / C; c = tid - qi * C;
    for (size_t r = (size_t)blockIdx.x * Q + qi; r < (size_t)L; r += (size_t)gridDim.x * Q) {
      float v = bf2f(X[r * C + c]);
      s += v; q += v * v;
    }
  }
  __shared__ float sb[304], qb[304];
  for (int cc = tid; cc < C; cc += 1024) { sb[cc] = 0.f; qb[cc] = 0.f; }
  __syncthreads();
  if (tid < T) { atomicAdd(&sb[c], s); atomicAdd(&qb[c], q); }
  __syncthreads();
  for (int cc = tid; cc < C; cc += 1024) {
    atomicAdd(&stats[cc], sb[cc]);
    atomicAdd(&stats[C + cc], qb[cc]);
  }
}

__global__ void bn_fin_k(const float* __restrict__ stats, const float* __restrict__ g,
                         const float* __restrict__ b, int C, float Linv,
                         float* __restrict__ scsh) {
  int c = blockIdx.x * blockDim.x + threadIdx.x;
  if (c < C) {
    float mean = stats[c] * Linv;
    float var = stats[C + c] * Linv - mean * mean;
    float sc = g[c] * rsqrtf(var + 1e-5f);
    scsh[c] = sc;
    scsh[C + c] = b[c] - mean * sc;
  }
}

__global__ void pool_bf_k(const u16* __restrict__ X, int C, const float* __restrict__ scsh,
                          int kw, int stride, u16* __restrict__ Y, int Cpad, int Lout) {
  int total = Lout * Cpad;
  for (int i = blockIdx.x * blockDim.x + threadIdx.x; i < total; i += blockDim.x * gridDim.x) {
    int lp = i / Cpad, c = i - lp * Cpad;
    if (c >= C) { Y[i] = (u16)0; continue; }
    float sc = scsh[c], sh = scsh[C + c];
    int l0 = lp * stride;
    float m = 0.f;
    for (int wq = 0; wq < kw; ++wq)
      m = fmaxf(m, fmaf(bf2f(X[(size_t)(l0 + wq) * C + c]), sc, sh));
    Y[i] = f2bf(m);
  }
}

__global__ void pool_f32_k(const u16* __restrict__ X, int C, const float* __restrict__ scsh,
                           int kw, int stride, float* __restrict__ Y, int Lout) {
  int total = Lout * C;
  for (int i = blockIdx.x * blockDim.x + threadIdx.x; i < total; i += blockDim.x * gridDim.x) {
    int lp = i / C, c = i - lp * C;
    float sc = scsh[c], sh = scsh[C + c];
    int l0 = lp * stride;
    float m = 0.f;
    for (int wq = 0; wq < kw; ++wq)
      m = fmaxf(m, fmaf(bf2f(X[(size_t)(l0 + wq) * C + c]), sc, sh));
    Y[i] = m;
  }
}

__global__ __launch_bounds__(256) void final_dot_k(
    const float* __restrict__ Y2, const float* __restrict__ Z2,
    const float* __restrict__ wy, const float* __restrict__ by,
    const float* __restrict__ wz, const float* __restrict__ bz,
    float* __restrict__ acc, int L) {
  float s0 = 0.f, s1 = 0.f;
  for (int lp = blockIdx.x * blockDim.x + threadIdx.x; lp < L; lp += blockDim.x * gridDim.x) {
    const float* y = Y2 + (size_t)lp * 200;
    const float* z = Z2 + (size_t)lp * 300;
    float d0 = 0.f, d1 = 0.f;
    for (int k = 0; k < 200; ++k) { float v = y[k]; d0 += v * wy[k]; d1 += v * wy[200 + k]; }
    float e0 = 0.f, e1 = 0.f;
    for (int k = 0; k < 300; ++k) { float v = z[k]; e0 += v * wz[k]; e1 += v * wz[300 + k]; }
    s0 += (d0 + by[0]) * (e0 + bz[0]);
    s1 += (d1 + by[1]) * (e1 + bz[1]);
  }
  __shared__ float r0[256], r1[256];
  r0[threadIdx.x] = s0; r1[threadIdx.x] = s1;
  __syncthreads();
  for (int off = 128; off > 0; off >>= 1) {
    if (threadIdx.x < off) { r0[threadIdx.x] += r0[threadIdx.x + off]; r1[threadIdx.x] += r1[threadIdx.x + off]; }
    __syncthreads();
  }
  if (threadIdx.x == 0) { atomicAdd(&acc[0], r0[0]); atomicAdd(&acc[1], r1[0]); }
}

__global__ void final_out_k(const float* __restrict__ acc, float invL, float* __restrict__ out) {
  int j = threadIdx.x;
  if (j < 2) out[j] = 1.f / (1.f + expf(-acc[j] * invL));
}

// ---------------- host ----------------

static inline void gemmL(hipStream_t st, const u16* A, int lda, const u16* B, int ldb,
                         u16* Cb, int ldcb, int npad, int M, int Nn, int K, const float* bias) {
  int ncols = (npad > Nn) ? npad : Nn;
  dim3 g((ncols + 63) / 64, (M + 127) / 128);
  gemm_mfma<<<g, 256, 0, st>>>(A, lda, B, ldb, Cb, ldcb, npad, M, Nn, K, bias,
                               0, nullptr, nullptr, nullptr, 0);
}

static inline void gemmGRU(hipStream_t st, const u16* A, int lda, const u16* B, int ldb,
                           int M, int K, const float* bias,
                           const u16* rz, const u16* inn, u16* ah, int c0) {
  dim3 g((200 + 63) / 64, (M + 127) / 128);
  gemm_mfma<<<g, 256, 0, st>>>(A, lda, B, ldb, nullptr, 0, 0, M, 200, K, bias,
                               1, rz, inn, ah, c0);
}

extern "C" void kernel_launch(void* const* d_in, const int* in_sizes, int n_in,
                              void* d_out, int out_size, void* d_ws, size_t ws_size,
                              hipStream_t stream) {
  (void)n_in; (void)out_size;
  const float* feat    = (const float*)d_in[0];
  const int*   eix     = (const int*)d_in[1];
  const int*   etyp    = (const int*)d_in[2];
  const float* ggnnW   = (const float*)d_in[3];
  const float* ggnnB   = (const float*)d_in[4];
  const float* Wih     = (const float*)d_in[5];
  const float* Whh     = (const float*)d_in[6];
  const float* bih     = (const float*)d_in[7];
  const float* bhh     = (const float*)d_in[8];
  const float* conv1w  = (const float*)d_in[9];
  const float* conv2w  = (const float*)d_in[11];
  const float* convc1w = (const float*)d_in[13];
  const float* convc2w = (const float*)d_in[15];
  const float* bnyg    = (const float*)d_in[17];
  const float* bnyb    = (const float*)d_in[18];
  const float* bncg    = (const float*)d_in[19];
  const float* bncb    = (const float*)d_in[20];
  const float* mlpyw   = (const float*)d_in[21];
  const float* mlpyb   = (const float*)d_in[22];
  const float* mlpzw   = (const float*)d_in[23];
  const float* mlpzb   = (const float*)d_in[24];

  const int N = in_sizes[0] / 100;
  const int E = in_sizes[2];
  const int* src = eix;
  const int* dst = eix + E;

  char* base = (char*)d_ws;
  const size_t AH_B = (size_t)N * 448 * 2;
  const int CH = (N + 1) / 2;
  const size_t SCR_B = (size_t)CH * 1696;

  u16* ah = (u16*)base;
  char* R1 = base + AH_B;
  char* WREG = R1 + SCR_B;

  u16* Wcat = (u16*)WREG;          // 200*832
  u16* Wrz  = Wcat + 166400;       // 400*448
  u16* Winn = Wrz + 179200;        // 200*224
  u16* Whn  = Winn + 44800;        // 200*224
  u16* w1c  = Whn + 44800;         // 200*1056
  u16* c2b  = w1c + 211200;        // 200*224
  u16* wc1  = c2b + 44800;         // 300*1056
  u16* wc2  = wc1 + 316800;        // 300*320
  float* brz   = (float*)(wc2 + 96000);  // 400
  float* stats = brz + 400;              // 600
  float* scsh  = stats + 600;            // 600
  float* acc2  = scsh + 600;             // 2 (+pad)
  int* deg_et = (int*)(acc2 + 4);
  int* off_et = deg_et + 4 * (size_t)N;
  int* cursor = off_et + 4 * (size_t)N;
  int* esrc   = cursor + 4 * (size_t)N;
  int* bsum   = esrc + E;                 // ceil(4N/1024) block sums
  const int L4 = 4 * N;
  const int NB = (L4 + 1023) / 1024;
  size_t need = (size_t)((char*)(bsum + NB) - base);

  if (ws_size < need) {
    fail_k<<<1, 64, 0, stream>>>((float*)d_out, -(float)(ws_size >> 20));
    return;
  }

  // ---- CSR build + packs ----
  hipMemsetAsync(deg_et, 0, sizeof(int) * 4 * (size_t)N, stream);
  init_ah_k<<<4096, 256, 0, stream>>>(feat, ah, N);
  count_deg_k<<<2048, 256, 0, stream>>>(dst, etyp, deg_et, N, E);
  bsum_k<<<NB, 1024, 0, stream>>>(deg_et, bsum, L4);
  scanb_k<<<1, 1024, 0, stream>>>(bsum, NB);
  scan_fin_k<<<NB, 1024, 0, stream>>>(deg_et, bsum, off_et, L4);
  copy_int_k<<<512, 256, 0, stream>>>(off_et, cursor, L4);
  fill_src_k<<<2048, 256, 0, stream>>>(src, dst, etyp, cursor, esrc, N, E);
  pack_wcat_k<<<651, 256, 0, stream>>>(ggnnW, ggnnB, Wcat);
  pack_wrz_k<<<700, 256, 0, stream>>>(Wih, Whh, Wrz);
  brz_k<<<2, 256, 0, stream>>>(bih, bhh, brz);
  pack_lin_b<<<175, 256, 0, stream>>>(Wih + 400 * 200, Winn, 200, 200, 224);
  pack_lin_b<<<175, 256, 0, stream>>>(Whh + 400 * 200, Whn, 200, 200, 224);
  pack_w1c_k<<<825, 256, 0, stream>>>(conv1w, w1c);
  pack_lin_b<<<175, 256, 0, stream>>>(conv2w, c2b, 200, 200, 224);
  pack_wc1_b<<<1238, 256, 0, stream>>>(convc1w, wc1);
  pack_lin_b<<<375, 256, 0, stream>>>(convc2w, wc2, 300, 300, 320);

  // ---- GGNN 8 steps ----
  u16* scat  = (u16*)R1;                      // CH x 832
  u16* rz_c  = (u16*)R1;                      // CH x 400
  u16* inn_c = rz_c + (size_t)CH * 400;       // CH x 224

  for (int step = 0; step < 8; ++step) {
    for (int c0 = 0; c0 < N; c0 += CH) {
      int Nc = (c0 + CH <= N) ? CH : (N - c0);
      agg_k<<<4096, 256, 0, stream>>>(off_et, deg_et, esrc, ah, scat, c0, Nc, N);
      gemmL(stream, scat, 832, Wcat, 832, ah + (size_t)c0 * 448, 448, 224,
            Nc, 200, 832, nullptr);
    }
    for (int c0 = 0; c0 < N; c0 += CH) {
      int Nc = (c0 + CH <= N) ? CH : (N - c0);
      const u16* ahc = ah + (size_t)c0 * 448;
      gemmL(stream, ahc, 448, Wrz, 448, rz_c, 400, 400, Nc, 400, 448, brz);
      gemmL(stream, ahc, 448, Winn, 224, inn_c, 224, 224, Nc, 200, 224, bih + 400);
      gemmGRU(stream, ahc + 224, 448, Whn, 224, Nc, 224, bhh + 400, rz_c, inn_c, ah, c0);
    }
  }

  // ---- conv paths ----
  const int L1 = N - 2;
  const int L2 = (L1 - 3) / 2 + 1;
  const int L3 = (L2 - 2) / 2 + 1;

  u16* cmat = (u16*)R1;                                              // N*352
  u16* out1 = (u16*)base;                                            // L1*200
  size_t y1_off = (((size_t)L1 * 400) + 255) & ~(size_t)255;
  u16* y1 = (u16*)(base + y1_off);                                   // L2*224
  u16* out2;                                                         // set below
  float* Y2f = (float*)base;                                         // L3*200 f32
  size_t o2_off = y1_off + ((((size_t)L2 * 448) + 255) & ~(size_t)255);
  out2 = (u16*)(base + o2_off);                                      // L2*200
  size_t oc1_off = (((size_t)L3 * 800) + 255) & ~(size_t)255;
  u16* outc1 = (u16*)(base + oc1_off);                               // L1*300
  u16* z1 = (u16*)R1;                                                // L2*320
  size_t oc2_off = (((size_t)L2 * 640) + 255) & ~(size_t)255;
  u16* outc2 = (u16*)(R1 + oc2_off);                                 // L2*300
  float* Z2f = (float*)(base + oc1_off);                             // L3*300 f32

  cmat_k<<<4096, 256, 0, stream>>>(ah, feat, cmat, N);

  // Y path
  gemmL(stream, cmat, 352, w1c, 1056, out1, 200, 200, L1, 200, 1056, nullptr);
  hipMemsetAsync(stats, 0, sizeof(float) * 400, stream);
  bn_stats2_k<<<512, 1024, 0, stream>>>(out1, L1, 200, stats);
  bn_fin_k<<<2, 256, 0, stream>>>(stats, bnyg, bnyb, 200, 1.f / (float)L1, scsh);
  pool_bf_k<<<2048, 256, 0, stream>>>(out1, 200, scsh, 3, 2, y1, 224, L2);

  gemmL(stream, y1, 224, c2b, 224, out2, 200, 200, L2, 200, 224, nullptr);
  hipMemsetAsync(stats, 0, sizeof(float) * 400, stream);
  bn_stats2_k<<<512, 1024, 0, stream>>>(out2, L2, 200, stats);
  bn_fin_k<<<2, 256, 0, stream>>>(stats, bnyg, bnyb, 200, 1.f / (float)L2, scsh);
  pool_f32_k<<<2048, 256, 0, stream>>>(out2, 200, scsh, 2, 2, Y2f, L3);

  // Z path
  gemmL(stream, cmat, 352, wc1, 1056, outc1, 300, 300, L1, 300, 1056, nullptr);
  hipMemsetAsync(stats, 0, sizeof(float) * 600, stream);
  bn_stats2_k<<<512, 1024, 0, stream>>>(outc1, L1, 300, stats);
  bn_fin_k<<<2, 256, 0, stream>>>(stats, bncg, bncb, 300, 1.f / (float)L1, scsh);
  pool_bf_k<<<2048, 256, 0, stream>>>(outc1, 300, scsh, 3, 2, z1, 320, L2);

  gemmL(stream, z1, 320, wc2, 320, outc2, 300, 300, L2, 300, 320, nullptr);
  hipMemsetAsync(stats, 0, sizeof(float) * 600, stream);
  bn_stats2_k<<<512, 1024, 0, stream>>>(outc2, L2, 300, stats);
  bn_fin_k<<<2, 256, 0, stream>>>(stats, bncg, bncb, 300, 1.f / (float)L2, scsh);
  pool_f32_k<<<2048, 256, 0, stream>>>(outc2, 300, scsh, 2, 2, Z2f, L3);

  // ---- final MLP product + mean + sigmoid ----
  hipMemsetAsync(acc2, 0, sizeof(float) * 2, stream);
  final_dot_k<<<256, 256, 0, stream>>>(Y2f, Z2f, mlpyw, mlpyb, mlpzw, mlpzb, acc2, L3);
  final_out_k<<<1, 64, 0, stream>>>(acc2, 1.f / (float)L3, (float*)d_out);
}

// Round 6
// 5606.516 us; speedup vs baseline: 3.7524x; 1.1310x over previous
//
#include <hip/hip_runtime.h>
#include <cstddef>
#include <cstdint>

// ============================================================================
// DevignModel round 6:
//  - 128x128 GEMM tile (4 waves, 64x64/wave) -> fewer col-blocks, less A re-fetch
//  - XCD row-band block swizzle: col-blocks of a row-block share one XCD's L2
//  - single "gates" GEMM (rz|inn|hn, Nn=800, K=448) + elementwise GRU finisher
// ============================================================================

typedef unsigned short u16;
typedef __attribute__((ext_vector_type(8))) short bf16x8;
typedef __attribute__((ext_vector_type(4))) float f32x4;
typedef __attribute__((ext_vector_type(8))) unsigned short u16x8;
typedef __attribute__((ext_vector_type(4))) unsigned short u16x4;

static __device__ __forceinline__ float bf2f(u16 u) {
  union { unsigned int i; float f; } v; v.i = ((unsigned int)u) << 16; return v.f;
}
static __device__ __forceinline__ u16 f2bf(float f) {
  union { float f; unsigned int i; } v; v.f = f;
  unsigned int r = v.i + 0x7FFFu + ((v.i >> 16) & 1u);
  return (u16)(r >> 16);
}
static __device__ __forceinline__ float sigm(float x) { return 1.f / (1.f + __expf(-x)); }

__global__ void fail_k(float* out, float code) { out[0] = code; out[1] = code; }

// ah[n][448]: [a(200)+pad24 | h(200)+pad24]; h0 = [feat | 0]
__global__ void init_ah_k(const float* __restrict__ feat, u16* __restrict__ ah, int N) {
  int total = N * 448;
  for (int i = blockIdx.x * blockDim.x + threadIdx.x; i < total; i += blockDim.x * gridDim.x) {
    int n = i / 448, j = i - n * 448;
    u16 v = 0;
    if (j >= 224 && j < 324) v = f2bf(feat[(size_t)n * 100 + (j - 224)]);
    ah[i] = v;
  }
}

__global__ void count_deg_k(const int* __restrict__ dst, const int* __restrict__ et,
                            int* __restrict__ deg_et, int N, int E) {
  for (int e = blockIdx.x * blockDim.x + threadIdx.x; e < E; e += blockDim.x * gridDim.x)
    atomicAdd(&deg_et[et[e] * N + dst[e]], 1);
}

// ---- parallel exclusive scan (3 kernels) ----
__global__ __launch_bounds__(1024) void bsum_k(const int* __restrict__ cnt,
                                               int* __restrict__ bsum, int L) {
  __shared__ int buf[1024];
  int i = blockIdx.x * 1024 + threadIdx.x;
  buf[threadIdx.x] = (i < L) ? cnt[i] : 0;
  __syncthreads();
  for (int o = 512; o > 0; o >>= 1) {
    if (threadIdx.x < o) buf[threadIdx.x] += buf[threadIdx.x + o];
    __syncthreads();
  }
  if (threadIdx.x == 0) bsum[blockIdx.x] = buf[0];
}

__global__ __launch_bounds__(1024) void scanb_k(int* __restrict__ bsum, int nb) {
  __shared__ int buf[1024];
  int v = (threadIdx.x < nb) ? bsum[threadIdx.x] : 0;
  buf[threadIdx.x] = v;
  __syncthreads();
  for (int o = 1; o < 1024; o <<= 1) {
    int t = (threadIdx.x >= o) ? buf[threadIdx.x - o] : 0;
    __syncthreads();
    buf[threadIdx.x] += t;
    __syncthreads();
  }
  if (threadIdx.x < nb) bsum[threadIdx.x] = buf[threadIdx.x] - v;
}

__global__ __launch_bounds__(1024) void scan_fin_k(const int* __restrict__ cnt,
                                                   const int* __restrict__ bsum,
                                                   int* __restrict__ off, int L) {
  __shared__ int buf[1024];
  int i = blockIdx.x * 1024 + threadIdx.x;
  int v = (i < L) ? cnt[i] : 0;
  buf[threadIdx.x] = v;
  __syncthreads();
  for (int o = 1; o < 1024; o <<= 1) {
    int t = (threadIdx.x >= o) ? buf[threadIdx.x - o] : 0;
    __syncthreads();
    buf[threadIdx.x] += t;
    __syncthreads();
  }
  if (i < L) off[i] = buf[threadIdx.x] - v + bsum[blockIdx.x];
}

__global__ void copy_int_k(const int* __restrict__ a, int* __restrict__ b, int n) {
  for (int i = blockIdx.x * blockDim.x + threadIdx.x; i < n; i += blockDim.x * gridDim.x) b[i] = a[i];
}

__global__ void fill_src_k(const int* __restrict__ src, const int* __restrict__ dst,
                           const int* __restrict__ et, int* __restrict__ cursor,
                           int* __restrict__ esrc, int N, int E) {
  for (int e = blockIdx.x * blockDim.x + threadIdx.x; e < E; e += blockDim.x * gridDim.x) {
    int p = atomicAdd(&cursor[et[e] * N + dst[e]], 1);
    esrc[p] = src[e];
  }
}

// ---- weight packs ----

__global__ void pack_wcat_k(const float* __restrict__ W, const float* __restrict__ gb,
                            u16* __restrict__ dst) {
  int total = 200 * 832;
  for (int i = blockIdx.x * blockDim.x + threadIdx.x; i < total; i += blockDim.x * gridDim.x) {
    int o = i / 832, kp = i - o * 832;
    float v = 0.f;
    if (kp < 800) { int k = kp / 200, kk = kp - k * 200; v = W[((size_t)k * 200 + o) * 200 + kk]; }
    else if (kp < 804) v = gb[(kp - 800) * 200 + o];
    dst[i] = f2bf(v);
  }
}

// Wall[800][448]: rows 0-399 = [Wih_rz | 0pad | Whh_rz | 0pad];
// rows 400-599 = [Wih_n | 0]; rows 600-799 = [0 | Whh_n]
__global__ void pack_wall_k(const float* __restrict__ Wih, const float* __restrict__ Whh,
                            u16* __restrict__ dst) {
  int total = 800 * 448;
  for (int i = blockIdx.x * blockDim.x + threadIdx.x; i < total; i += blockDim.x * gridDim.x) {
    int j = i / 448, kp = i - j * 448;
    float v = 0.f;
    if (j < 400) {
      if (kp < 200) v = Wih[(size_t)j * 200 + kp];
      else if (kp >= 224 && kp < 424) v = Whh[(size_t)j * 200 + (kp - 224)];
    } else if (j < 600) {
      if (kp < 200) v = Wih[(size_t)j * 200 + kp];
    } else {
      if (kp >= 224 && kp < 424) v = Whh[(size_t)(j - 200) * 200 + (kp - 224)];
    }
    dst[i] = f2bf(v);
  }
}

__global__ void ball_k(const float* __restrict__ bih, const float* __restrict__ bhh,
                       float* __restrict__ ball) {
  int j = blockIdx.x * blockDim.x + threadIdx.x;
  if (j < 800) ball[j] = (j < 400) ? bih[j] + bhh[j] : (j < 600 ? bih[j] : bhh[j - 200]);
}

__global__ void pack_lin_b(const float* __restrict__ src, u16* __restrict__ dst,
                           int Nn, int K, int Kp) {
  int total = Nn * Kp;
  for (int i = blockIdx.x * blockDim.x + threadIdx.x; i < total; i += blockDim.x * gridDim.x) {
    int o = i / Kp, kp = i - o * Kp;
    dst[i] = (kp < K) ? f2bf(src[(size_t)o * K + kp]) : (u16)0;
  }
}

__global__ void pack_w1c_k(const float* __restrict__ src, u16* __restrict__ dst) {
  int total = 200 * 1056;
  for (int i = blockIdx.x * blockDim.x + threadIdx.x; i < total; i += blockDim.x * gridDim.x) {
    int o = i / 1056, r = i - o * 1056;
    int t = r / 352, kp = r - t * 352;
    dst[i] = (kp < 200) ? f2bf(src[((size_t)o * 200 + kp) * 3 + t]) : (u16)0;
  }
}

__global__ void pack_wc1_b(const float* __restrict__ src, u16* __restrict__ dst) {
  int total = 300 * 1056;
  for (int i = blockIdx.x * blockDim.x + threadIdx.x; i < total; i += blockDim.x * gridDim.x) {
    int o = i / 1056, r = i - o * 1056;
    int t = r / 352, kp = r - t * 352;
    int ci = (kp < 224) ? (kp < 200 ? kp : -1) : ((kp - 224) < 100 ? 200 + (kp - 224) : -1);
    dst[i] = (ci >= 0) ? f2bf(src[((size_t)o * 300 + ci) * 3 + t]) : (u16)0;
  }
}

// aggregation: wave per (node, etype); scat[n-n0][832] = [s0|s1|s2|s3|deg0..3|0...]
__global__ void agg_k(const int* __restrict__ off_et, const int* __restrict__ deg_et,
                      const int* __restrict__ esrc, const u16* __restrict__ ah,
                      u16* __restrict__ scat, int n0, int Nc, int N) {
  int gtid = blockIdx.x * blockDim.x + threadIdx.x;
  int wid = gtid >> 6, lane = threadIdx.x & 63;
  int nw = (blockDim.x * gridDim.x) >> 6;
  int total = Nc * 4;
  for (int u = wid; u < total; u += nw) {
    int n = n0 + (u >> 2), k = u & 3;
    u16* srow = scat + (size_t)(u >> 2) * 832;
    if (lane < 50) {
      int rs = off_et[(size_t)k * N + n], d = deg_et[(size_t)k * N + n];
      float a0 = 0.f, a1 = 0.f, a2 = 0.f, a3 = 0.f;
      for (int i = 0; i < d; ++i) {
        const u16* hr = ah + (size_t)esrc[rs + i] * 448 + 224 + lane * 4;
        u16x4 v = *reinterpret_cast<const u16x4*>(hr);
        a0 += bf2f(v[0]); a1 += bf2f(v[1]); a2 += bf2f(v[2]); a3 += bf2f(v[3]);
      }
      u16x4 r;
      r[0] = f2bf(a0); r[1] = f2bf(a1); r[2] = f2bf(a2); r[3] = f2bf(a3);
      *reinterpret_cast<u16x4*>(srow + k * 200 + lane * 4) = r;
    } else if (k == 0 && lane == 50) {
      u16x4 r;
#pragma unroll
      for (int kk = 0; kk < 4; ++kk) r[kk] = f2bf((float)deg_et[(size_t)kk * N + n]);
      *reinterpret_cast<u16x4*>(srow + 800) = r;
    } else if (k == 1 && lane >= 51 && lane <= 57) {
      u16x4 z; z[0] = z[1] = z[2] = z[3] = 0;
      *reinterpret_cast<u16x4*>(srow + 804 + (lane - 51) * 4) = z;
    }
  }
}

// ---------------- bf16 MFMA GEMM, 128x128 tile, XCD row-band swizzle ----------------
// Cb[M,0:Nn] = A@B^T (+bias); cols [Nn,npad) zeroed. gyr = real row-block count.
__global__ __launch_bounds__(256) void gemm_mfma(
    const u16* __restrict__ A, int lda,
    const u16* __restrict__ B, int ldb,
    u16* __restrict__ Cb, int ldcb, int npad,
    int M, int Nn, int K, const float* __restrict__ bias, int gyr) {
  // swizzle: dispatch-linear id -> (xcd, slot); xcd owns a contiguous row band,
  // and iterates col-blocks fastest -> A-tile reused from this XCD's L2.
  const int gx = gridDim.x;
  int lin = blockIdx.y * gx + blockIdx.x;
  int k8 = lin & 7, j = lin >> 3;
  int band = gridDim.y >> 3;            // gy_pad / 8
  int yy = j / gx, xx = j - yy * gx;
  int by = k8 * band + yy;
  if (by >= gyr) return;
  const int m0 = by * 128, n0 = xx * 128;

  __shared__ u16 As[128 * 40];
  __shared__ u16 Bs[128 * 40];
  const int tid = threadIdx.x;
  const int lane = tid & 63;
  const int w = tid >> 6;
  const int wr = w >> 1, wc = w & 1;
  const int lrow = tid >> 1;            // 0..127
  const int lk = (tid & 1) << 4;        // 0 or 16
  const int fr = lane & 15;
  const int fk = (lane >> 4) * 8;

  f32x4 acc[4][4] = {};

  for (int k0 = 0; k0 < K; k0 += 32) {
    u16x8 va0 = 0, va1 = 0, vb0 = 0, vb1 = 0;
    int ra = m0 + lrow, rb = n0 + lrow;
    if (ra < M) {
      const u16* p = A + (size_t)ra * lda + k0 + lk;
      va0 = *reinterpret_cast<const u16x8*>(p);
      va1 = *reinterpret_cast<const u16x8*>(p + 8);
    }
    if (rb < Nn) {
      const u16* p = B + (size_t)rb * ldb + k0 + lk;
      vb0 = *reinterpret_cast<const u16x8*>(p);
      vb1 = *reinterpret_cast<const u16x8*>(p + 8);
    }
    __syncthreads();
    *reinterpret_cast<u16x8*>(&As[lrow * 40 + lk]) = va0;
    *reinterpret_cast<u16x8*>(&As[lrow * 40 + lk + 8]) = va1;
    *reinterpret_cast<u16x8*>(&Bs[lrow * 40 + lk]) = vb0;
    *reinterpret_cast<u16x8*>(&Bs[lrow * 40 + lk + 8]) = vb1;
    __syncthreads();

    bf16x8 af[4], bfv[4];
#pragma unroll
    for (int i = 0; i < 4; ++i)
      af[i] = *reinterpret_cast<const bf16x8*>(&As[(wr * 64 + i * 16 + fr) * 40 + fk]);
#pragma unroll
    for (int jj = 0; jj < 4; ++jj)
      bfv[jj] = *reinterpret_cast<const bf16x8*>(&Bs[(wc * 64 + jj * 16 + fr) * 40 + fk]);
#pragma unroll
    for (int i = 0; i < 4; ++i)
#pragma unroll
      for (int jj = 0; jj < 4; ++jj)
        acc[i][jj] = __builtin_amdgcn_mfma_f32_16x16x32_bf16(af[i], bfv[jj], acc[i][jj], 0, 0, 0);
  }

  const int er = (lane >> 4) * 4;
  const int ec = lane & 15;
#pragma unroll
  for (int i = 0; i < 4; ++i) {
#pragma unroll
    for (int jj = 0; jj < 4; ++jj) {
      int n = n0 + wc * 64 + jj * 16 + ec;
#pragma unroll
      for (int r = 0; r < 4; ++r) {
        int m = m0 + wr * 64 + i * 16 + er + r;
        if (m >= M) continue;
        if (n < Nn) {
          float v = acc[i][jj][r];
          if (bias) v += bias[n];
          Cb[(size_t)m * ldcb + n] = f2bf(v);
        } else if (n < npad) {
          Cb[(size_t)m * ldcb + n] = (u16)0;
        }
      }
    }
  }
}

// GRU finisher: gates[n][832] = [r|z|inn|hn]; h := (1-z)*tanh(inn + r*hn) + z*h
__global__ void gru_fin_k(const u16* __restrict__ g, u16* __restrict__ ah, int c0, int Nc) {
  int total = Nc * 200;
  for (int i = blockIdx.x * blockDim.x + threadIdx.x; i < total; i += blockDim.x * gridDim.x) {
    int n = i / 200, o = i - n * 200;
    const u16* gr = g + (size_t)n * 832;
    float r = sigm(bf2f(gr[o]));
    float z = sigm(bf2f(gr[200 + o]));
    float x = bf2f(gr[400 + o]) + r * bf2f(gr[600 + o]);
    float e2 = __expf(2.f * x);
    float nn = (e2 - 1.f) / (e2 + 1.f);
    size_t hi = (size_t)(c0 + n) * 448 + 224 + o;
    float hold = bf2f(ah[hi]);
    ah[hi] = f2bf((1.f - z) * nn + z * hold);
  }
}

// cmat[n][352] = [h(224 incl zero pads) | feat(100) | 0(28)]
__global__ void cmat_k(const u16* __restrict__ ah, const float* __restrict__ feat,
                       u16* __restrict__ c, int N) {
  int total = N * 352;
  for (int i = blockIdx.x * blockDim.x + threadIdx.x; i < total; i += blockDim.x * gridDim.x) {
    int n = i / 352, j = i - n * 352;
    u16 v;
    if (j < 224) v = ah[(size_t)n * 448 + 224 + j];
    else { int f = j - 224; v = (f < 100) ? f2bf(feat[(size_t)n * 100 + f]) : (u16)0; }
    c[i] = v;
  }
}

// per-channel stats: fixed channel per thread, coalesced
__global__ __launch_bounds__(1024) void bn_stats2_k(const u16* __restrict__ X, int L, int C,
                                                    float* __restrict__ stats) {
  const int Q = 1024 / C;
  const int T = Q * C;
  const int tid = threadIdx.x;
  float s = 0.f, q = 0.f;
  int c = 0;
  if (tid < T) {
    int qi = tid / C; c = tid - qi * C;
    for (size_t r = (size_t)blockIdx.x * Q + qi; r < (size_t)L; r += (size_t)gridDim.x * Q) {
      float v = bf2f(X[r * C + c]);
      s += v; q += v * v;
    }
  }
  __shared__ float sb[304], qb[304];
  for (int cc = tid; cc < C; cc += 1024) { sb[cc] = 0.f; qb[cc] = 0.f; }
  __syncthreads();
  if (tid < T) { atomicAdd(&sb[c], s); atomicAdd(&qb[c], q); }
  __syncthreads();
  for (int cc = tid; cc < C; cc += 1024) {
    atomicAdd(&stats[cc], sb[cc]);
    atomicAdd(&stats[C + cc], qb[cc]);
  }
}

__global__ void bn_fin_k(const float* __restrict__ stats, const float* __restrict__ g,
                         const float* __restrict__ b, int C, float Linv,
                         float* __restrict__ scsh) {
  int c = blockIdx.x * blockDim.x + threadIdx.x;
  if (c < C) {
    float mean = stats[c] * Linv;
    float var = stats[C + c] * Linv - mean * mean;
    float sc = g[c] * rsqrtf(var + 1e-5f);
    scsh[c] = sc;
    scsh[C + c] = b[c] - mean * sc;
  }
}

__global__ void pool_bf_k(const u16* __restrict__ X, int C, const float* __restrict__ scsh,
                          int kw, int stride, u16* __restrict__ Y, int Cpad, int Lout) {
  int total = Lout * Cpad;
  for (int i = blockIdx.x * blockDim.x + threadIdx.x; i < total; i += blockDim.x * gridDim.x) {
    int lp = i / Cpad, c = i - lp * Cpad;
    if (c >= C) { Y[i] = (u16)0; continue; }
    float sc = scsh[c], sh = scsh[C + c];
    int l0 = lp * stride;
    float m = 0.f;
    for (int wq = 0; wq < kw; ++wq)
      m = fmaxf(m, fmaf(bf2f(X[(size_t)(l0 + wq) * C + c]), sc, sh));
    Y[i] = f2bf(m);
  }
}

__global__ void pool_f32_k(const u16* __restrict__ X, int C, const float* __restrict__ scsh,
                           int kw, int stride, float* __restrict__ Y, int Lout) {
  int total = Lout * C;
  for (int i = blockIdx.x * blockDim.x + threadIdx.x; i < total; i += blockDim.x * gridDim.x) {
    int lp = i / C, c = i - lp * C;
    float sc = scsh[c], sh = scsh[C + c];
    int l0 = lp * stride;
    float m = 0.f;
    for (int wq = 0; wq < kw; ++wq)
      m = fmaxf(m, fmaf(bf2f(X[(size_t)(l0 + wq) * C + c]), sc, sh));
    Y[i] = m;
  }
}

__global__ __launch_bounds__(256) void final_dot_k(
    const float* __restrict__ Y2, const float* __restrict__ Z2,
    const float* __restrict__ wy, const float* __restrict__ by,
    const float* __restrict__ wz, const float* __restrict__ bz,
    float* __restrict__ acc, int L) {
  float s0 = 0.f, s1 = 0.f;
  for (int lp = blockIdx.x * blockDim.x + threadIdx.x; lp < L; lp += blockDim.x * gridDim.x) {
    const float* y = Y2 + (size_t)lp * 200;
    const float* z = Z2 + (size_t)lp * 300;
    float d0 = 0.f, d1 = 0.f;
    for (int k = 0; k < 200; ++k) { float v = y[k]; d0 += v * wy[k]; d1 += v * wy[200 + k]; }
    float e0 = 0.f, e1 = 0.f;
    for (int k = 0; k < 300; ++k) { float v = z[k]; e0 += v * wz[k]; e1 += v * wz[300 + k]; }
    s0 += (d0 + by[0]) * (e0 + bz[0]);
    s1 += (d1 + by[1]) * (e1 + bz[1]);
  }
  __shared__ float r0[256], r1[256];
  r0[threadIdx.x] = s0; r1[threadIdx.x] = s1;
  __syncthreads();
  for (int off = 128; off > 0; off >>= 1) {
    if (threadIdx.x < off) { r0[threadIdx.x] += r0[threadIdx.x + off]; r1[threadIdx.x] += r1[threadIdx.x + off]; }
    __syncthreads();
  }
  if (threadIdx.x == 0) { atomicAdd(&acc[0], r0[0]); atomicAdd(&acc[1], r1[0]); }
}

__global__ void final_out_k(const float* __restrict__ acc, float invL, float* __restrict__ out) {
  int j = threadIdx.x;
  if (j < 2) out[j] = 1.f / (1.f + expf(-acc[j] * invL));
}

// ---------------- host ----------------

static inline void gemmL(hipStream_t st, const u16* A, int lda, const u16* B, int ldb,
                         u16* Cb, int ldcb, int npad, int M, int Nn, int K, const float* bias) {
  int ncols = (npad > Nn) ? npad : Nn;
  int gx = (ncols + 127) / 128;
  int gy = (M + 127) / 128;
  int gyp = ((gy + 7) / 8) * 8;
  dim3 g(gx, gyp);
  gemm_mfma<<<g, 256, 0, st>>>(A, lda, B, ldb, Cb, ldcb, npad, M, Nn, K, bias, gy);
}

extern "C" void kernel_launch(void* const* d_in, const int* in_sizes, int n_in,
                              void* d_out, int out_size, void* d_ws, size_t ws_size,
                              hipStream_t stream) {
  (void)n_in; (void)out_size;
  const float* feat    = (const float*)d_in[0];
  const int*   eix     = (const int*)d_in[1];
  const int*   etyp    = (const int*)d_in[2];
  const float* ggnnW   = (const float*)d_in[3];
  const float* ggnnB   = (const float*)d_in[4];
  const float* Wih     = (const float*)d_in[5];
  const float* Whh     = (const float*)d_in[6];
  const float* bih     = (const float*)d_in[7];
  const float* bhh     = (const float*)d_in[8];
  const float* conv1w  = (const float*)d_in[9];
  const float* conv2w  = (const float*)d_in[11];
  const float* convc1w = (const float*)d_in[13];
  const float* convc2w = (const float*)d_in[15];
  const float* bnyg    = (const float*)d_in[17];
  const float* bnyb    = (const float*)d_in[18];
  const float* bncg    = (const float*)d_in[19];
  const float* bncb    = (const float*)d_in[20];
  const float* mlpyw   = (const float*)d_in[21];
  const float* mlpyb   = (const float*)d_in[22];
  const float* mlpzw   = (const float*)d_in[23];
  const float* mlpzb   = (const float*)d_in[24];

  const int N = in_sizes[0] / 100;
  const int E = in_sizes[2];
  const int* src = eix;
  const int* dst = eix + E;

  char* base = (char*)d_ws;
  const size_t AH_B = (size_t)N * 448 * 2;
  const int CH = (N + 1) / 2;
  const size_t SCR_B = (size_t)CH * 1664;   // scat / gates: CH x 832 u16

  u16* ah = (u16*)base;
  char* R1 = base + AH_B;
  char* WREG = R1 + SCR_B;

  u16* Wcat = (u16*)WREG;          // 200*832
  u16* Wall = Wcat + 166400;       // 800*448
  u16* w1c  = Wall + 358400;       // 200*1056
  u16* c2b  = w1c + 211200;        // 200*224
  u16* wc1  = c2b + 44800;         // 300*1056
  u16* wc2  = wc1 + 316800;        // 300*320
  float* ball  = (float*)(wc2 + 96000);  // 800
  float* stats = ball + 832;             // 600
  float* scsh  = stats + 600;            // 600
  float* acc2  = scsh + 600;             // 2 (+pad)
  int* deg_et = (int*)(acc2 + 8);
  int* off_et = deg_et + 4 * (size_t)N;
  int* cursor = off_et + 4 * (size_t)N;
  int* esrc   = cursor + 4 * (size_t)N;
  int* bsum   = esrc + E;
  const int L4 = 4 * N;
  const int NB = (L4 + 1023) / 1024;
  size_t need = (size_t)((char*)(bsum + NB) - base);

  if (ws_size < need) {
    fail_k<<<1, 64, 0, stream>>>((float*)d_out, -(float)(ws_size >> 20));
    return;
  }

  // ---- CSR build + packs ----
  hipMemsetAsync(deg_et, 0, sizeof(int) * 4 * (size_t)N, stream);
  init_ah_k<<<4096, 256, 0, stream>>>(feat, ah, N);
  count_deg_k<<<2048, 256, 0, stream>>>(dst, etyp, deg_et, N, E);
  bsum_k<<<NB, 1024, 0, stream>>>(deg_et, bsum, L4);
  scanb_k<<<1, 1024, 0, stream>>>(bsum, NB);
  scan_fin_k<<<NB, 1024, 0, stream>>>(deg_et, bsum, off_et, L4);
  copy_int_k<<<512, 256, 0, stream>>>(off_et, cursor, L4);
  fill_src_k<<<2048, 256, 0, stream>>>(src, dst, etyp, cursor, esrc, N, E);
  pack_wcat_k<<<651, 256, 0, stream>>>(ggnnW, ggnnB, Wcat);
  pack_wall_k<<<1400, 256, 0, stream>>>(Wih, Whh, Wall);
  ball_k<<<4, 256, 0, stream>>>(bih, bhh, ball);
  pack_w1c_k<<<825, 256, 0, stream>>>(conv1w, w1c);
  pack_lin_b<<<175, 256, 0, stream>>>(conv2w, c2b, 200, 200, 224);
  pack_wc1_b<<<1238, 256, 0, stream>>>(convc1w, wc1);
  pack_lin_b<<<375, 256, 0, stream>>>(convc2w, wc2, 300, 300, 320);

  // ---- GGNN 8 steps ----
  u16* scat = (u16*)R1;    // CH x 832 (aliases gates)

  for (int step = 0; step < 8; ++step) {
    // phase A: per chunk, a = scat @ Wcat^T (deg cols fold bias); writes a-slice + zero pads
    for (int c0 = 0; c0 < N; c0 += CH) {
      int Nc = (c0 + CH <= N) ? CH : (N - c0);
      agg_k<<<4096, 256, 0, stream>>>(off_et, deg_et, esrc, ah, scat, c0, Nc, N);
      gemmL(stream, scat, 832, Wcat, 832, ah + (size_t)c0 * 448, 448, 224,
            Nc, 200, 832, nullptr);
    }
    // phase B: per chunk, gates = [a|h] @ Wall^T (+ball), then GRU finish
    for (int c0 = 0; c0 < N; c0 += CH) {
      int Nc = (c0 + CH <= N) ? CH : (N - c0);
      const u16* ahc = ah + (size_t)c0 * 448;
      gemmL(stream, ahc, 448, Wall, 448, scat, 832, 800, Nc, 800, 448, ball);
      gru_fin_k<<<2048, 256, 0, stream>>>(scat, ah, c0, Nc);
    }
  }

  // ---- conv paths ----
  const int L1 = N - 2;
  const int L2 = (L1 - 3) / 2 + 1;
  const int L3 = (L2 - 2) / 2 + 1;

  u16* cmat = (u16*)R1;                                              // N*352
  u16* out1 = (u16*)base;                                            // L1*200
  size_t y1_off = (((size_t)L1 * 400) + 255) & ~(size_t)255;
  u16* y1 = (u16*)(base + y1_off);                                   // L2*224
  size_t o2_off = y1_off + ((((size_t)L2 * 448) + 255) & ~(size_t)255);
  u16* out2 = (u16*)(base + o2_off);                                 // L2*200
  float* Y2f = (float*)base;                                         // L3*200 f32
  size_t oc1_off = (((size_t)L3 * 800) + 255) & ~(size_t)255;
  u16* outc1 = (u16*)(base + oc1_off);                               // L1*300
  u16* z1 = (u16*)R1;                                                // L2*320
  size_t oc2_off = (((size_t)L2 * 640) + 255) & ~(size_t)255;
  u16* outc2 = (u16*)(R1 + oc2_off);                                 // L2*300
  float* Z2f = (float*)(base + oc1_off);                             // L3*300 f32

  cmat_k<<<4096, 256, 0, stream>>>(ah, feat, cmat, N);

  // Y path
  gemmL(stream, cmat, 352, w1c, 1056, out1, 200, 200, L1, 200, 1056, nullptr);
  hipMemsetAsync(stats, 0, sizeof(float) * 400, stream);
  bn_stats2_k<<<512, 1024, 0, stream>>>(out1, L1, 200, stats);
  bn_fin_k<<<2, 256, 0, stream>>>(stats, bnyg, bnyb, 200, 1.f / (float)L1, scsh);
  pool_bf_k<<<2048, 256, 0, stream>>>(out1, 200, scsh, 3, 2, y1, 224, L2);

  gemmL(stream, y1, 224, c2b, 224, out2, 200, 200, L2, 200, 224, nullptr);
  hipMemsetAsync(stats, 0, sizeof(float) * 400, stream);
  bn_stats2_k<<<512, 1024, 0, stream>>>(out2, L2, 200, stats);
  bn_fin_k<<<2, 256, 0, stream>>>(stats, bnyg, bnyb, 200, 1.f / (float)L2, scsh);
  pool_f32_k<<<2048, 256, 0, stream>>>(out2, 200, scsh, 2, 2, Y2f, L3);

  // Z path
  gemmL(stream, cmat, 352, wc1, 1056, outc1, 300, 300, L1, 300, 1056, nullptr);
  hipMemsetAsync(stats, 0, sizeof(float) * 600, stream);
  bn_stats2_k<<<512, 1024, 0, stream>>>(outc1, L1, 300, stats);
  bn_fin_k<<<2, 256, 0, stream>>>(stats, bncg, bncb, 300, 1.f / (float)L1, scsh);
  pool_bf_k<<<2048, 256, 0, stream>>>(outc1, 300, scsh, 3, 2, z1, 320, L2);

  gemmL(stream, z1, 320, wc2, 320, outc2, 300, 300, L2, 300, 320, nullptr);
  hipMemsetAsync(stats, 0, sizeof(float) * 600, stream);
  bn_stats2_k<<<512, 1024, 0, stream>>>(outc2, L2, 300, stats);
  bn_fin_k<<<2, 256, 0, stream>>>(stats, bncg, bncb, 300, 1.f / (float)L2, scsh);
  pool_f32_k<<<2048, 256, 0, stream>>>(outc2, 300, scsh, 2, 2, Z2f, L3);

  // ---- final MLP product + mean + sigmoid ----
  hipMemsetAsync(acc2, 0, sizeof(float) * 2, stream);
  final_dot_k<<<256, 256, 0, stream>>>(Y2f, Z2f, mlpyw, mlpyb, mlpzw, mlpzb, acc2, L3);
  final_out_k<<<1, 64, 0, stream>>>(acc2, 1.f / (float)L3, (float*)d_out);
}

// Round 7
// 5552.016 us; speedup vs baseline: 3.7893x; 1.0098x over previous
//
#include <hip/hip_runtime.h>
#include <cstddef>
#include <cstdint>

// ============================================================================
// DevignModel round 7: GEMM staged via global_load_lds (width 16) with a
// bank-conflict-free XOR-swizzled LDS layout (swizzle applied on the global
// source address + on the ds_read address; LDS dest linear per gload_lds HW).
// Everything else unchanged from round 6.
// ============================================================================

typedef unsigned short u16;
typedef __attribute__((ext_vector_type(8))) short bf16x8;
typedef __attribute__((ext_vector_type(4))) float f32x4;
typedef __attribute__((ext_vector_type(4))) unsigned short u16x4;

static __device__ __forceinline__ float bf2f(u16 u) {
  union { unsigned int i; float f; } v; v.i = ((unsigned int)u) << 16; return v.f;
}
static __device__ __forceinline__ u16 f2bf(float f) {
  union { float f; unsigned int i; } v; v.f = f;
  unsigned int r = v.i + 0x7FFFu + ((v.i >> 16) & 1u);
  return (u16)(r >> 16);
}
static __device__ __forceinline__ float sigm(float x) { return 1.f / (1.f + __expf(-x)); }

// async global->LDS 16B: dest = wave-uniform base + lane*16 (HW), src per-lane
static __device__ __forceinline__ void gload16(const u16* gp, u16* lp) {
  __builtin_amdgcn_global_load_lds(
      (const __attribute__((address_space(1))) void*)gp,
      (__attribute__((address_space(3))) void*)lp, 16, 0, 0);
}

__global__ void fail_k(float* out, float code) { out[0] = code; out[1] = code; }

// ah[n][448]: [a(200)+pad24 | h(200)+pad24]; h0 = [feat | 0]
__global__ void init_ah_k(const float* __restrict__ feat, u16* __restrict__ ah, int N) {
  int total = N * 448;
  for (int i = blockIdx.x * blockDim.x + threadIdx.x; i < total; i += blockDim.x * gridDim.x) {
    int n = i / 448, j = i - n * 448;
    u16 v = 0;
    if (j >= 224 && j < 324) v = f2bf(feat[(size_t)n * 100 + (j - 224)]);
    ah[i] = v;
  }
}

__global__ void count_deg_k(const int* __restrict__ dst, const int* __restrict__ et,
                            int* __restrict__ deg_et, int N, int E) {
  for (int e = blockIdx.x * blockDim.x + threadIdx.x; e < E; e += blockDim.x * gridDim.x)
    atomicAdd(&deg_et[et[e] * N + dst[e]], 1);
}

// ---- parallel exclusive scan (3 kernels) ----
__global__ __launch_bounds__(1024) void bsum_k(const int* __restrict__ cnt,
                                               int* __restrict__ bsum, int L) {
  __shared__ int buf[1024];
  int i = blockIdx.x * 1024 + threadIdx.x;
  buf[threadIdx.x] = (i < L) ? cnt[i] : 0;
  __syncthreads();
  for (int o = 512; o > 0; o >>= 1) {
    if (threadIdx.x < o) buf[threadIdx.x] += buf[threadIdx.x + o];
    __syncthreads();
  }
  if (threadIdx.x == 0) bsum[blockIdx.x] = buf[0];
}

__global__ __launch_bounds__(1024) void scanb_k(int* __restrict__ bsum, int nb) {
  __shared__ int buf[1024];
  int v = (threadIdx.x < nb) ? bsum[threadIdx.x] : 0;
  buf[threadIdx.x] = v;
  __syncthreads();
  for (int o = 1; o < 1024; o <<= 1) {
    int t = (threadIdx.x >= o) ? buf[threadIdx.x - o] : 0;
    __syncthreads();
    buf[threadIdx.x] += t;
    __syncthreads();
  }
  if (threadIdx.x < nb) bsum[threadIdx.x] = buf[threadIdx.x] - v;
}

__global__ __launch_bounds__(1024) void scan_fin_k(const int* __restrict__ cnt,
                                                   const int* __restrict__ bsum,
                                                   int* __restrict__ off, int L) {
  __shared__ int buf[1024];
  int i = blockIdx.x * 1024 + threadIdx.x;
  int v = (i < L) ? cnt[i] : 0;
  buf[threadIdx.x] = v;
  __syncthreads();
  for (int o = 1; o < 1024; o <<= 1) {
    int t = (threadIdx.x >= o) ? buf[threadIdx.x - o] : 0;
    __syncthreads();
    buf[threadIdx.x] += t;
    __syncthreads();
  }
  if (i < L) off[i] = buf[threadIdx.x] - v + bsum[blockIdx.x];
}

__global__ void copy_int_k(const int* __restrict__ a, int* __restrict__ b, int n) {
  for (int i = blockIdx.x * blockDim.x + threadIdx.x; i < n; i += blockDim.x * gridDim.x) b[i] = a[i];
}

__global__ void fill_src_k(const int* __restrict__ src, const int* __restrict__ dst,
                           const int* __restrict__ et, int* __restrict__ cursor,
                           int* __restrict__ esrc, int N, int E) {
  for (int e = blockIdx.x * blockDim.x + threadIdx.x; e < E; e += blockDim.x * gridDim.x) {
    int p = atomicAdd(&cursor[et[e] * N + dst[e]], 1);
    esrc[p] = src[e];
  }
}

// ---- weight packs ----

__global__ void pack_wcat_k(const float* __restrict__ W, const float* __restrict__ gb,
                            u16* __restrict__ dst) {
  int total = 200 * 832;
  for (int i = blockIdx.x * blockDim.x + threadIdx.x; i < total; i += blockDim.x * gridDim.x) {
    int o = i / 832, kp = i - o * 832;
    float v = 0.f;
    if (kp < 800) { int k = kp / 200, kk = kp - k * 200; v = W[((size_t)k * 200 + o) * 200 + kk]; }
    else if (kp < 804) v = gb[(kp - 800) * 200 + o];
    dst[i] = f2bf(v);
  }
}

// Wall[800][448]: rows 0-399 = [Wih_rz | 0 | Whh_rz | 0];
// rows 400-599 = [Wih_n | 0]; rows 600-799 = [0 | Whh_n]
__global__ void pack_wall_k(const float* __restrict__ Wih, const float* __restrict__ Whh,
                            u16* __restrict__ dst) {
  int total = 800 * 448;
  for (int i = blockIdx.x * blockDim.x + threadIdx.x; i < total; i += blockDim.x * gridDim.x) {
    int j = i / 448, kp = i - j * 448;
    float v = 0.f;
    if (j < 400) {
      if (kp < 200) v = Wih[(size_t)j * 200 + kp];
      else if (kp >= 224 && kp < 424) v = Whh[(size_t)j * 200 + (kp - 224)];
    } else if (j < 600) {
      if (kp < 200) v = Wih[(size_t)j * 200 + kp];
    } else {
      if (kp >= 224 && kp < 424) v = Whh[(size_t)(j - 200) * 200 + (kp - 224)];
    }
    dst[i] = f2bf(v);
  }
}

__global__ void ball_k(const float* __restrict__ bih, const float* __restrict__ bhh,
                       float* __restrict__ ball) {
  int j = blockIdx.x * blockDim.x + threadIdx.x;
  if (j < 800) ball[j] = (j < 400) ? bih[j] + bhh[j] : (j < 600 ? bih[j] : bhh[j - 200]);
}

__global__ void pack_lin_b(const float* __restrict__ src, u16* __restrict__ dst,
                           int Nn, int K, int Kp) {
  int total = Nn * Kp;
  for (int i = blockIdx.x * blockDim.x + threadIdx.x; i < total; i += blockDim.x * gridDim.x) {
    int o = i / Kp, kp = i - o * Kp;
    dst[i] = (kp < K) ? f2bf(src[(size_t)o * K + kp]) : (u16)0;
  }
}

__global__ void pack_w1c_k(const float* __restrict__ src, u16* __restrict__ dst) {
  int total = 200 * 1056;
  for (int i = blockIdx.x * blockDim.x + threadIdx.x; i < total; i += blockDim.x * gridDim.x) {
    int o = i / 1056, r = i - o * 1056;
    int t = r / 352, kp = r - t * 352;
    dst[i] = (kp < 200) ? f2bf(src[((size_t)o * 200 + kp) * 3 + t]) : (u16)0;
  }
}

__global__ void pack_wc1_b(const float* __restrict__ src, u16* __restrict__ dst) {
  int total = 300 * 1056;
  for (int i = blockIdx.x * blockDim.x + threadIdx.x; i < total; i += blockDim.x * gridDim.x) {
    int o = i / 1056, r = i - o * 1056;
    int t = r / 352, kp = r - t * 352;
    int ci = (kp < 224) ? (kp < 200 ? kp : -1) : ((kp - 224) < 100 ? 200 + (kp - 224) : -1);
    dst[i] = (ci >= 0) ? f2bf(src[((size_t)o * 300 + ci) * 3 + t]) : (u16)0;
  }
}

// aggregation: wave per (node, etype); scat[n-n0][832] = [s0|s1|s2|s3|deg0..3|0...]
__global__ void agg_k(const int* __restrict__ off_et, const int* __restrict__ deg_et,
                      const int* __restrict__ esrc, const u16* __restrict__ ah,
                      u16* __restrict__ scat, int n0, int Nc, int N) {
  int gtid = blockIdx.x * blockDim.x + threadIdx.x;
  int wid = gtid >> 6, lane = threadIdx.x & 63;
  int nw = (blockDim.x * gridDim.x) >> 6;
  int total = Nc * 4;
  for (int u = wid; u < total; u += nw) {
    int n = n0 + (u >> 2), k = u & 3;
    u16* srow = scat + (size_t)(u >> 2) * 832;
    if (lane < 50) {
      int rs = off_et[(size_t)k * N + n], d = deg_et[(size_t)k * N + n];
      float a0 = 0.f, a1 = 0.f, a2 = 0.f, a3 = 0.f;
      for (int i = 0; i < d; ++i) {
        const u16* hr = ah + (size_t)esrc[rs + i] * 448 + 224 + lane * 4;
        u16x4 v = *reinterpret_cast<const u16x4*>(hr);
        a0 += bf2f(v[0]); a1 += bf2f(v[1]); a2 += bf2f(v[2]); a3 += bf2f(v[3]);
      }
      u16x4 r;
      r[0] = f2bf(a0); r[1] = f2bf(a1); r[2] = f2bf(a2); r[3] = f2bf(a3);
      *reinterpret_cast<u16x4*>(srow + k * 200 + lane * 4) = r;
    } else if (k == 0 && lane == 50) {
      u16x4 r;
#pragma unroll
      for (int kk = 0; kk < 4; ++kk) r[kk] = f2bf((float)deg_et[(size_t)kk * N + n]);
      *reinterpret_cast<u16x4*>(srow + 800) = r;
    } else if (k == 1 && lane >= 51 && lane <= 57) {
      u16x4 z; z[0] = z[1] = z[2] = z[3] = 0;
      *reinterpret_cast<u16x4*>(srow + 804 + (lane - 51) * 4) = z;
    }
  }
}

// ---------------- bf16 MFMA GEMM, 128x128 tile, gload_lds + XOR swizzle ----------------
// LDS tile: 16B slot s = r*4 + (g ^ ((r>>1)&3)) holds A[r][k0+g*8 .. +8).
// Staged by gload16 with per-lane swizzled GLOBAL src; read with matching XOR.
__global__ __launch_bounds__(256) void gemm_mfma(
    const u16* __restrict__ A, int lda,
    const u16* __restrict__ B, int ldb,
    u16* __restrict__ Cb, int ldcb, int npad,
    int M, int Nn, int K, const float* __restrict__ bias, int gyr) {
  const int gx = gridDim.x;
  int lin = blockIdx.y * gx + blockIdx.x;
  int k8 = lin & 7, j = lin >> 3;
  int band = gridDim.y >> 3;
  int yy = j / gx, xx = j - yy * gx;
  int by = k8 * band + yy;
  if (by >= gyr) return;
  const int m0 = by * 128, n0 = xx * 128;

  __shared__ __align__(16) u16 As[128 * 32];
  __shared__ __align__(16) u16 Bs[128 * 32];
  const int tid = threadIdx.x;
  const int lane = tid & 63;
  const int w = tid >> 6;
  const int wr = w >> 1, wc = w & 1;
  const int fr = lane & 15;
  const int g = lane >> 4;

  // ---- staging (2 slots of 64 rows each; 4 gload16/thread/k-step) ----
  const int gg = (lane & 3) ^ ((lane >> 3) & 3);  // swizzled k-chunk for this lane
  const int r0 = tid >> 2;                        // rows 0..63
  const int r1 = r0 + 64;                         // rows 64..127
  int ra0 = m0 + r0; if (ra0 >= M) ra0 = M - 1;
  int ra1 = m0 + r1; if (ra1 >= M) ra1 = M - 1;
  int rb0 = n0 + r0; if (rb0 >= Nn) rb0 = Nn - 1;
  int rb1 = n0 + r1; if (rb1 >= Nn) rb1 = Nn - 1;
  const u16* pa0 = A + (size_t)ra0 * lda + gg * 8;
  const u16* pa1 = A + (size_t)ra1 * lda + gg * 8;
  const u16* pb0 = B + (size_t)rb0 * ldb + gg * 8;
  const u16* pb1 = B + (size_t)rb1 * ldb + gg * 8;
  u16* lA0 = &As[(w * 64) * 8];
  u16* lA1 = &As[(256 + w * 64) * 8];
  u16* lB0 = &Bs[(w * 64) * 8];
  u16* lB1 = &Bs[(256 + w * 64) * 8];

  // fragment read swizzle (matches store): slot = row*4 + (g ^ ((row>>1)&3))
  const int gxr = g ^ ((fr >> 1) & 3);

  f32x4 acc[4][4] = {};

  for (int k0 = 0; k0 < K; k0 += 32) {
    __syncthreads();                    // all frag reads of prev tile done
    gload16(pa0, lA0);
    gload16(pa1, lA1);
    gload16(pb0, lB0);
    gload16(pb1, lB1);
    pa0 += 32; pa1 += 32; pb0 += 32; pb1 += 32;
    __syncthreads();                    // vmcnt(0) drain + barrier

    bf16x8 af[4], bfv[4];
#pragma unroll
    for (int i = 0; i < 4; ++i) {
      int row = wr * 64 + i * 16 + fr;
      af[i] = *reinterpret_cast<const bf16x8*>(&As[(row * 4 + gxr) * 8]);
    }
#pragma unroll
    for (int jj = 0; jj < 4; ++jj) {
      int row = wc * 64 + jj * 16 + fr;
      bfv[jj] = *reinterpret_cast<const bf16x8*>(&Bs[(row * 4 + gxr) * 8]);
    }
#pragma unroll
    for (int i = 0; i < 4; ++i)
#pragma unroll
      for (int jj = 0; jj < 4; ++jj)
        acc[i][jj] = __builtin_amdgcn_mfma_f32_16x16x32_bf16(af[i], bfv[jj], acc[i][jj], 0, 0, 0);
  }

  const int er = (lane >> 4) * 4;
  const int ec = lane & 15;
#pragma unroll
  for (int i = 0; i < 4; ++i) {
#pragma unroll
    for (int jj = 0; jj < 4; ++jj) {
      int n = n0 + wc * 64 + jj * 16 + ec;
#pragma unroll
      for (int r = 0; r < 4; ++r) {
        int m = m0 + wr * 64 + i * 16 + er + r;
        if (m >= M) continue;
        if (n < Nn) {
          float v = acc[i][jj][r];
          if (bias) v += bias[n];
          Cb[(size_t)m * ldcb + n] = f2bf(v);
        } else if (n < npad) {
          Cb[(size_t)m * ldcb + n] = (u16)0;
        }
      }
    }
  }
}

// GRU finisher: gates[n][832] = [r|z|inn|hn]; h := (1-z)*tanh(inn + r*hn) + z*h
__global__ void gru_fin_k(const u16* __restrict__ g, u16* __restrict__ ah, int c0, int Nc) {
  int total = Nc * 200;
  for (int i = blockIdx.x * blockDim.x + threadIdx.x; i < total; i += blockDim.x * gridDim.x) {
    int n = i / 200, o = i - n * 200;
    const u16* gr = g + (size_t)n * 832;
    float r = sigm(bf2f(gr[o]));
    float z = sigm(bf2f(gr[200 + o]));
    float x = bf2f(gr[400 + o]) + r * bf2f(gr[600 + o]);
    float e2 = __expf(2.f * x);
    float nn = (e2 - 1.f) / (e2 + 1.f);
    size_t hi = (size_t)(c0 + n) * 448 + 224 + o;
    float hold = bf2f(ah[hi]);
    ah[hi] = f2bf((1.f - z) * nn + z * hold);
  }
}

// cmat[n][352] = [h(224 incl zero pads) | feat(100) | 0(28)]
__global__ void cmat_k(const u16* __restrict__ ah, const float* __restrict__ feat,
                       u16* __restrict__ c, int N) {
  int total = N * 352;
  for (int i = blockIdx.x * blockDim.x + threadIdx.x; i < total; i += blockDim.x * gridDim.x) {
    int n = i / 352, j = i - n * 352;
    u16 v;
    if (j < 224) v = ah[(size_t)n * 448 + 224 + j];
    else { int f = j - 224; v = (f < 100) ? f2bf(feat[(size_t)n * 100 + f]) : (u16)0; }
    c[i] = v;
  }
}

// per-channel stats: fixed channel per thread, coalesced
__global__ __launch_bounds__(1024) void bn_stats2_k(const u16* __restrict__ X, int L, int C,
                                                    float* __restrict__ stats) {
  const int Q = 1024 / C;
  const int T = Q * C;
  const int tid = threadIdx.x;
  float s = 0.f, q = 0.f;
  int c = 0;
  if (tid < T) {
    int qi = tid / C; c = tid - qi * C;
    for (size_t r = (size_t)blockIdx.x * Q + qi; r < (size_t)L; r += (size_t)gridDim.x * Q) {
      float v = bf2f(X[r * C + c]);
      s += v; q += v * v;
    }
  }
  __shared__ float sb[304], qb[304];
  for (int cc = tid; cc < C; cc += 1024) { sb[cc] = 0.f; qb[cc] = 0.f; }
  __syncthreads();
  if (tid < T) { atomicAdd(&sb[c], s); atomicAdd(&qb[c], q); }
  __syncthreads();
  for (int cc = tid; cc < C; cc += 1024) {
    atomicAdd(&stats[cc], sb[cc]);
    atomicAdd(&stats[C + cc], qb[cc]);
  }
}

__global__ void bn_fin_k(const float* __restrict__ stats, const float* __restrict__ g,
                         const float* __restrict__ b, int C, float Linv,
                         float* __restrict__ scsh) {
  int c = blockIdx.x * blockDim.x + threadIdx.x;
  if (c < C) {
    float mean = stats[c] * Linv;
    float var = stats[C + c] * Linv - mean * mean;
    float sc = g[c] * rsqrtf(var + 1e-5f);
    scsh[c] = sc;
    scsh[C + c] = b[c] - mean * sc;
  }
}

__global__ void pool_bf_k(const u16* __restrict__ X, int C, const float* __restrict__ scsh,
                          int kw, int stride, u16* __restrict__ Y, int Cpad, int Lout) {
  int total = Lout * Cpad;
  for (int i = blockIdx.x * blockDim.x + threadIdx.x; i < total; i += blockDim.x * gridDim.x) {
    int lp = i / Cpad, c = i - lp * Cpad;
    if (c >= C) { Y[i] = (u16)0; continue; }
    float sc = scsh[c], sh = scsh[C + c];
    int l0 = lp * stride;
    float m = 0.f;
    for (int wq = 0; wq < kw; ++wq)
      m = fmaxf(m, fmaf(bf2f(X[(size_t)(l0 + wq) * C + c]), sc, sh));
    Y[i] = f2bf(m);
  }
}

__global__ void pool_f32_k(const u16* __restrict__ X, int C, const float* __restrict__ scsh,
                           int kw, int stride, float* __restrict__ Y, int Lout) {
  int total = Lout * C;
  for (int i = blockIdx.x * blockDim.x + threadIdx.x; i < total; i += blockDim.x * gridDim.x) {
    int lp = i / C, c = i - lp * C;
    float sc = scsh[c], sh = scsh[C + c];
    int l0 = lp * stride;
    float m = 0.f;
    for (int wq = 0; wq < kw; ++wq)
      m = fmaxf(m, fmaf(bf2f(X[(size_t)(l0 + wq) * C + c]), sc, sh));
    Y[i] = m;
  }
}

__global__ __launch_bounds__(256) void final_dot_k(
    const float* __restrict__ Y2, const float* __restrict__ Z2,
    const float* __restrict__ wy, const float* __restrict__ by,
    const float* __restrict__ wz, const float* __restrict__ bz,
    float* __restrict__ acc, int L) {
  float s0 = 0.f, s1 = 0.f;
  for (int lp = blockIdx.x * blockDim.x + threadIdx.x; lp < L; lp += blockDim.x * gridDim.x) {
    const float* y = Y2 + (size_t)lp * 200;
    const float* z = Z2 + (size_t)lp * 300;
    float d0 = 0.f, d1 = 0.f;
    for (int k = 0; k < 200; ++k) { float v = y[k]; d0 += v * wy[k]; d1 += v * wy[200 + k]; }
    float e0 = 0.f, e1 = 0.f;
    for (int k = 0; k < 300; ++k) { float v = z[k]; e0 += v * wz[k]; e1 += v * wz[300 + k]; }
    s0 += (d0 + by[0]) * (e0 + bz[0]);
    s1 += (d1 + by[1]) * (e1 + bz[1]);
  }
  __shared__ float r0[256], r1[256];
  r0[threadIdx.x] = s0; r1[threadIdx.x] = s1;
  __syncthreads();
  for (int off = 128; off > 0; off >>= 1) {
    if (threadIdx.x < off) { r0[threadIdx.x] += r0[threadIdx.x + off]; r1[threadIdx.x] += r1[threadIdx.x + off]; }
    __syncthreads();
  }
  if (threadIdx.x == 0) { atomicAdd(&acc[0], r0[0]); atomicAdd(&acc[1], r1[0]); }
}

__global__ void final_out_k(const float* __restrict__ acc, float invL, float* __restrict__ out) {
  int j = threadIdx.x;
  if (j < 2) out[j] = 1.f / (1.f + expf(-acc[j] * invL));
}

// ---------------- host ----------------

static inline void gemmL(hipStream_t st, const u16* A, int lda, const u16* B, int ldb,
                         u16* Cb, int ldcb, int npad, int M, int Nn, int K, const float* bias) {
  int ncols = (npad > Nn) ? npad : Nn;
  int gx = (ncols + 127) / 128;
  int gy = (M + 127) / 128;
  int gyp = ((gy + 7) / 8) * 8;
  dim3 g(gx, gyp);
  gemm_mfma<<<g, 256, 0, st>>>(A, lda, B, ldb, Cb, ldcb, npad, M, Nn, K, bias, gy);
}

extern "C" void kernel_launch(void* const* d_in, const int* in_sizes, int n_in,
                              void* d_out, int out_size, void* d_ws, size_t ws_size,
                              hipStream_t stream) {
  (void)n_in; (void)out_size;
  const float* feat    = (const float*)d_in[0];
  const int*   eix     = (const int*)d_in[1];
  const int*   etyp    = (const int*)d_in[2];
  const float* ggnnW   = (const float*)d_in[3];
  const float* ggnnB   = (const float*)d_in[4];
  const float* Wih     = (const float*)d_in[5];
  const float* Whh     = (const float*)d_in[6];
  const float* bih     = (const float*)d_in[7];
  const float* bhh     = (const float*)d_in[8];
  const float* conv1w  = (const float*)d_in[9];
  const float* conv2w  = (const float*)d_in[11];
  const float* convc1w = (const float*)d_in[13];
  const float* convc2w = (const float*)d_in[15];
  const float* bnyg    = (const float*)d_in[17];
  const float* bnyb    = (const float*)d_in[18];
  const float* bncg    = (const float*)d_in[19];
  const float* bncb    = (const float*)d_in[20];
  const float* mlpyw   = (const float*)d_in[21];
  const float* mlpyb   = (const float*)d_in[22];
  const float* mlpzw   = (const float*)d_in[23];
  const float* mlpzb   = (const float*)d_in[24];

  const int N = in_sizes[0] / 100;
  const int E = in_sizes[2];
  const int* src = eix;
  const int* dst = eix + E;

  char* base = (char*)d_ws;
  const size_t AH_B = (size_t)N * 448 * 2;
  const int CH = (N + 1) / 2;
  const size_t SCR_B = (size_t)CH * 1664;   // scat / gates: CH x 832 u16

  u16* ah = (u16*)base;
  char* R1 = base + AH_B;
  char* WREG = R1 + SCR_B;

  u16* Wcat = (u16*)WREG;          // 200*832
  u16* Wall = Wcat + 166400;       // 800*448
  u16* w1c  = Wall + 358400;       // 200*1056
  u16* c2b  = w1c + 211200;        // 200*224
  u16* wc1  = c2b + 44800;         // 300*1056
  u16* wc2  = wc1 + 316800;        // 300*320
  float* ball  = (float*)(wc2 + 96000);  // 800
  float* stats = ball + 832;             // 600
  float* scsh  = stats + 600;            // 600
  float* acc2  = scsh + 600;             // 2 (+pad)
  int* deg_et = (int*)(acc2 + 8);
  int* off_et = deg_et + 4 * (size_t)N;
  int* cursor = off_et + 4 * (size_t)N;
  int* esrc   = cursor + 4 * (size_t)N;
  int* bsum   = esrc + E;
  const int L4 = 4 * N;
  const int NB = (L4 + 1023) / 1024;
  size_t need = (size_t)((char*)(bsum + NB) - base);

  if (ws_size < need) {
    fail_k<<<1, 64, 0, stream>>>((float*)d_out, -(float)(ws_size >> 20));
    return;
  }

  // ---- CSR build + packs ----
  hipMemsetAsync(deg_et, 0, sizeof(int) * 4 * (size_t)N, stream);
  init_ah_k<<<4096, 256, 0, stream>>>(feat, ah, N);
  count_deg_k<<<2048, 256, 0, stream>>>(dst, etyp, deg_et, N, E);
  bsum_k<<<NB, 1024, 0, stream>>>(deg_et, bsum, L4);
  scanb_k<<<1, 1024, 0, stream>>>(bsum, NB);
  scan_fin_k<<<NB, 1024, 0, stream>>>(deg_et, bsum, off_et, L4);
  copy_int_k<<<512, 256, 0, stream>>>(off_et, cursor, L4);
  fill_src_k<<<2048, 256, 0, stream>>>(src, dst, etyp, cursor, esrc, N, E);
  pack_wcat_k<<<651, 256, 0, stream>>>(ggnnW, ggnnB, Wcat);
  pack_wall_k<<<1400, 256, 0, stream>>>(Wih, Whh, Wall);
  ball_k<<<4, 256, 0, stream>>>(bih, bhh, ball);
  pack_w1c_k<<<825, 256, 0, stream>>>(conv1w, w1c);
  pack_lin_b<<<175, 256, 0, stream>>>(conv2w, c2b, 200, 200, 224);
  pack_wc1_b<<<1238, 256, 0, stream>>>(convc1w, wc1);
  pack_lin_b<<<375, 256, 0, stream>>>(convc2w, wc2, 300, 300, 320);

  // ---- GGNN 8 steps ----
  u16* scat = (u16*)R1;    // CH x 832 (aliases gates)

  for (int step = 0; step < 8; ++step) {
    for (int c0 = 0; c0 < N; c0 += CH) {
      int Nc = (c0 + CH <= N) ? CH : (N - c0);
      agg_k<<<4096, 256, 0, stream>>>(off_et, deg_et, esrc, ah, scat, c0, Nc, N);
      gemmL(stream, scat, 832, Wcat, 832, ah + (size_t)c0 * 448, 448, 224,
            Nc, 200, 832, nullptr);
    }
    for (int c0 = 0; c0 < N; c0 += CH) {
      int Nc = (c0 + CH <= N) ? CH : (N - c0);
      const u16* ahc = ah + (size_t)c0 * 448;
      gemmL(stream, ahc, 448, Wall, 448, scat, 832, 800, Nc, 800, 448, ball);
      gru_fin_k<<<2048, 256, 0, stream>>>(scat, ah, c0, Nc);
    }
  }

  // ---- conv paths ----
  const int L1 = N - 2;
  const int L2 = (L1 - 3) / 2 + 1;
  const int L3 = (L2 - 2) / 2 + 1;

  u16* cmat = (u16*)R1;                                              // N*352
  u16* out1 = (u16*)base;                                            // L1*200
  size_t y1_off = (((size_t)L1 * 400) + 255) & ~(size_t)255;
  u16* y1 = (u16*)(base + y1_off);                                   // L2*224
  size_t o2_off = y1_off + ((((size_t)L2 * 448) + 255) & ~(size_t)255);
  u16* out2 = (u16*)(base + o2_off);                                 // L2*200
  float* Y2f = (float*)base;                                         // L3*200 f32
  size_t oc1_off = (((size_t)L3 * 800) + 255) & ~(size_t)255;
  u16* outc1 = (u16*)(base + oc1_off);                               // L1*300
  u16* z1 = (u16*)R1;                                                // L2*320
  size_t oc2_off = (((size_t)L2 * 640) + 255) & ~(size_t)255;
  u16* outc2 = (u16*)(R1 + oc2_off);                                 // L2*300
  float* Z2f = (float*)(base + oc1_off);                             // L3*300 f32

  cmat_k<<<4096, 256, 0, stream>>>(ah, feat, cmat, N);

  // Y path
  gemmL(stream, cmat, 352, w1c, 1056, out1, 200, 200, L1, 200, 1056, nullptr);
  hipMemsetAsync(stats, 0, sizeof(float) * 400, stream);
  bn_stats2_k<<<512, 1024, 0, stream>>>(out1, L1, 200, stats);
  bn_fin_k<<<2, 256, 0, stream>>>(stats, bnyg, bnyb, 200, 1.f / (float)L1, scsh);
  pool_bf_k<<<2048, 256, 0, stream>>>(out1, 200, scsh, 3, 2, y1, 224, L2);

  gemmL(stream, y1, 224, c2b, 224, out2, 200, 200, L2, 200, 224, nullptr);
  hipMemsetAsync(stats, 0, sizeof(float) * 400, stream);
  bn_stats2_k<<<512, 1024, 0, stream>>>(out2, L2, 200, stats);
  bn_fin_k<<<2, 256, 0, stream>>>(stats, bnyg, bnyb, 200, 1.f / (float)L2, scsh);
  pool_f32_k<<<2048, 256, 0, stream>>>(out2, 200, scsh, 2, 2, Y2f, L3);

  // Z path
  gemmL(stream, cmat, 352, wc1, 1056, outc1, 300, 300, L1, 300, 1056, nullptr);
  hipMemsetAsync(stats, 0, sizeof(float) * 600, stream);
  bn_stats2_k<<<512, 1024, 0, stream>>>(outc1, L1, 300, stats);
  bn_fin_k<<<2, 256, 0, stream>>>(stats, bncg, bncb, 300, 1.f / (float)L1, scsh);
  pool_bf_k<<<2048, 256, 0, stream>>>(outc1, 300, scsh, 3, 2, z1, 320, L2);

  gemmL(stream, z1, 320, wc2, 320, outc2, 300, 300, L2, 300, 320, nullptr);
  hipMemsetAsync(stats, 0, sizeof(float) * 600, stream);
  bn_stats2_k<<<512, 1024, 0, stream>>>(outc2, L2, 300, stats);
  bn_fin_k<<<2, 256, 0, stream>>>(stats, bncg, bncb, 300, 1.f / (float)L2, scsh);
  pool_f32_k<<<2048, 256, 0, stream>>>(outc2, 300, scsh, 2, 2, Z2f, L3);

  // ---- final MLP product + mean + sigmoid ----
  hipMemsetAsync(acc2, 0, sizeof(float) * 2, stream);
  final_dot_k<<<256, 256, 0, stream>>>(Y2f, Z2f, mlpyw, mlpyb, mlpzw, mlpzb, acc2, L3);
  final_out_k<<<1, 64, 0, stream>>>(acc2, 1.f / (float)L3, (float*)d_out);
}

// Round 8
// 5395.066 us; speedup vs baseline: 3.8995x; 1.0291x over previous
//
#include <hip/hip_runtime.h>
#include <cstddef>
#include <cstdint>

// ============================================================================
// DevignModel round 8: double-buffered gload_lds GEMM pipeline (T3 2-phase):
// issue next K-tile's loads BEFORE current tile's MFMA; one barrier per step.
// Round 7's swizzle (conflict-free) kept. Everything else unchanged.
// ============================================================================

typedef unsigned short u16;
typedef __attribute__((ext_vector_type(8))) short bf16x8;
typedef __attribute__((ext_vector_type(4))) float f32x4;
typedef __attribute__((ext_vector_type(4))) unsigned short u16x4;

static __device__ __forceinline__ float bf2f(u16 u) {
  union { unsigned int i; float f; } v; v.i = ((unsigned int)u) << 16; return v.f;
}
static __device__ __forceinline__ u16 f2bf(float f) {
  union { float f; unsigned int i; } v; v.f = f;
  unsigned int r = v.i + 0x7FFFu + ((v.i >> 16) & 1u);
  return (u16)(r >> 16);
}
static __device__ __forceinline__ float sigm(float x) { return 1.f / (1.f + __expf(-x)); }

// async global->LDS 16B: dest = wave-uniform base + lane*16 (HW), src per-lane
static __device__ __forceinline__ void gload16(const u16* gp, u16* lp) {
  __builtin_amdgcn_global_load_lds(
      (const __attribute__((address_space(1))) void*)gp,
      (__attribute__((address_space(3))) void*)lp, 16, 0, 0);
}

__global__ void fail_k(float* out, float code) { out[0] = code; out[1] = code; }

// ah[n][448]: [a(200)+pad24 | h(200)+pad24]; h0 = [feat | 0]
__global__ void init_ah_k(const float* __restrict__ feat, u16* __restrict__ ah, int N) {
  int total = N * 448;
  for (int i = blockIdx.x * blockDim.x + threadIdx.x; i < total; i += blockDim.x * gridDim.x) {
    int n = i / 448, j = i - n * 448;
    u16 v = 0;
    if (j >= 224 && j < 324) v = f2bf(feat[(size_t)n * 100 + (j - 224)]);
    ah[i] = v;
  }
}

__global__ void count_deg_k(const int* __restrict__ dst, const int* __restrict__ et,
                            int* __restrict__ deg_et, int N, int E) {
  for (int e = blockIdx.x * blockDim.x + threadIdx.x; e < E; e += blockDim.x * gridDim.x)
    atomicAdd(&deg_et[et[e] * N + dst[e]], 1);
}

// ---- parallel exclusive scan (3 kernels) ----
__global__ __launch_bounds__(1024) void bsum_k(const int* __restrict__ cnt,
                                               int* __restrict__ bsum, int L) {
  __shared__ int buf[1024];
  int i = blockIdx.x * 1024 + threadIdx.x;
  buf[threadIdx.x] = (i < L) ? cnt[i] : 0;
  __syncthreads();
  for (int o = 512; o > 0; o >>= 1) {
    if (threadIdx.x < o) buf[threadIdx.x] += buf[threadIdx.x + o];
    __syncthreads();
  }
  if (threadIdx.x == 0) bsum[blockIdx.x] = buf[0];
}

__global__ __launch_bounds__(1024) void scanb_k(int* __restrict__ bsum, int nb) {
  __shared__ int buf[1024];
  int v = (threadIdx.x < nb) ? bsum[threadIdx.x] : 0;
  buf[threadIdx.x] = v;
  __syncthreads();
  for (int o = 1; o < 1024; o <<= 1) {
    int t = (threadIdx.x >= o) ? buf[threadIdx.x - o] : 0;
    __syncthreads();
    buf[threadIdx.x] += t;
    __syncthreads();
  }
  if (threadIdx.x < nb) bsum[threadIdx.x] = buf[threadIdx.x] - v;
}

__global__ __launch_bounds__(1024) void scan_fin_k(const int* __restrict__ cnt,
                                                   const int* __restrict__ bsum,
                                                   int* __restrict__ off, int L) {
  __shared__ int buf[1024];
  int i = blockIdx.x * 1024 + threadIdx.x;
  int v = (i < L) ? cnt[i] : 0;
  buf[threadIdx.x] = v;
  __syncthreads();
  for (int o = 1; o < 1024; o <<= 1) {
    int t = (threadIdx.x >= o) ? buf[threadIdx.x - o] : 0;
    __syncthreads();
    buf[threadIdx.x] += t;
    __syncthreads();
  }
  if (i < L) off[i] = buf[threadIdx.x] - v + bsum[blockIdx.x];
}

__global__ void copy_int_k(const int* __restrict__ a, int* __restrict__ b, int n) {
  for (int i = blockIdx.x * blockDim.x + threadIdx.x; i < n; i += blockDim.x * gridDim.x) b[i] = a[i];
}

__global__ void fill_src_k(const int* __restrict__ src, const int* __restrict__ dst,
                           const int* __restrict__ et, int* __restrict__ cursor,
                           int* __restrict__ esrc, int N, int E) {
  for (int e = blockIdx.x * blockDim.x + threadIdx.x; e < E; e += blockDim.x * gridDim.x) {
    int p = atomicAdd(&cursor[et[e] * N + dst[e]], 1);
    esrc[p] = src[e];
  }
}

// ---- weight packs ----

__global__ void pack_wcat_k(const float* __restrict__ W, const float* __restrict__ gb,
                            u16* __restrict__ dst) {
  int total = 200 * 832;
  for (int i = blockIdx.x * blockDim.x + threadIdx.x; i < total; i += blockDim.x * gridDim.x) {
    int o = i / 832, kp = i - o * 832;
    float v = 0.f;
    if (kp < 800) { int k = kp / 200, kk = kp - k * 200; v = W[((size_t)k * 200 + o) * 200 + kk]; }
    else if (kp < 804) v = gb[(kp - 800) * 200 + o];
    dst[i] = f2bf(v);
  }
}

// Wall[800][448]: rows 0-399 = [Wih_rz | 0 | Whh_rz | 0];
// rows 400-599 = [Wih_n | 0]; rows 600-799 = [0 | Whh_n]
__global__ void pack_wall_k(const float* __restrict__ Wih, const float* __restrict__ Whh,
                            u16* __restrict__ dst) {
  int total = 800 * 448;
  for (int i = blockIdx.x * blockDim.x + threadIdx.x; i < total; i += blockDim.x * gridDim.x) {
    int j = i / 448, kp = i - j * 448;
    float v = 0.f;
    if (j < 400) {
      if (kp < 200) v = Wih[(size_t)j * 200 + kp];
      else if (kp >= 224 && kp < 424) v = Whh[(size_t)j * 200 + (kp - 224)];
    } else if (j < 600) {
      if (kp < 200) v = Wih[(size_t)j * 200 + kp];
    } else {
      if (kp >= 224 && kp < 424) v = Whh[(size_t)(j - 200) * 200 + (kp - 224)];
    }
    dst[i] = f2bf(v);
  }
}

__global__ void ball_k(const float* __restrict__ bih, const float* __restrict__ bhh,
                       float* __restrict__ ball) {
  int j = blockIdx.x * blockDim.x + threadIdx.x;
  if (j < 800) ball[j] = (j < 400) ? bih[j] + bhh[j] : (j < 600 ? bih[j] : bhh[j - 200]);
}

__global__ void pack_lin_b(const float* __restrict__ src, u16* __restrict__ dst,
                           int Nn, int K, int Kp) {
  int total = Nn * Kp;
  for (int i = blockIdx.x * blockDim.x + threadIdx.x; i < total; i += blockDim.x * gridDim.x) {
    int o = i / Kp, kp = i - o * Kp;
    dst[i] = (kp < K) ? f2bf(src[(size_t)o * K + kp]) : (u16)0;
  }
}

__global__ void pack_w1c_k(const float* __restrict__ src, u16* __restrict__ dst) {
  int total = 200 * 1056;
  for (int i = blockIdx.x * blockDim.x + threadIdx.x; i < total; i += blockDim.x * gridDim.x) {
    int o = i / 1056, r = i - o * 1056;
    int t = r / 352, kp = r - t * 352;
    dst[i] = (kp < 200) ? f2bf(src[((size_t)o * 200 + kp) * 3 + t]) : (u16)0;
  }
}

__global__ void pack_wc1_b(const float* __restrict__ src, u16* __restrict__ dst) {
  int total = 300 * 1056;
  for (int i = blockIdx.x * blockDim.x + threadIdx.x; i < total; i += blockDim.x * gridDim.x) {
    int o = i / 1056, r = i - o * 1056;
    int t = r / 352, kp = r - t * 352;
    int ci = (kp < 224) ? (kp < 200 ? kp : -1) : ((kp - 224) < 100 ? 200 + (kp - 224) : -1);
    dst[i] = (ci >= 0) ? f2bf(src[((size_t)o * 300 + ci) * 3 + t]) : (u16)0;
  }
}

// aggregation: wave per (node, etype); scat[n-n0][832] = [s0|s1|s2|s3|deg0..3|0...]
__global__ void agg_k(const int* __restrict__ off_et, const int* __restrict__ deg_et,
                      const int* __restrict__ esrc, const u16* __restrict__ ah,
                      u16* __restrict__ scat, int n0, int Nc, int N) {
  int gtid = blockIdx.x * blockDim.x + threadIdx.x;
  int wid = gtid >> 6, lane = threadIdx.x & 63;
  int nw = (blockDim.x * gridDim.x) >> 6;
  int total = Nc * 4;
  for (int u = wid; u < total; u += nw) {
    int n = n0 + (u >> 2), k = u & 3;
    u16* srow = scat + (size_t)(u >> 2) * 832;
    if (lane < 50) {
      int rs = off_et[(size_t)k * N + n], d = deg_et[(size_t)k * N + n];
      float a0 = 0.f, a1 = 0.f, a2 = 0.f, a3 = 0.f;
      for (int i = 0; i < d; ++i) {
        const u16* hr = ah + (size_t)esrc[rs + i] * 448 + 224 + lane * 4;
        u16x4 v = *reinterpret_cast<const u16x4*>(hr);
        a0 += bf2f(v[0]); a1 += bf2f(v[1]); a2 += bf2f(v[2]); a3 += bf2f(v[3]);
      }
      u16x4 r;
      r[0] = f2bf(a0); r[1] = f2bf(a1); r[2] = f2bf(a2); r[3] = f2bf(a3);
      *reinterpret_cast<u16x4*>(srow + k * 200 + lane * 4) = r;
    } else if (k == 0 && lane == 50) {
      u16x4 r;
#pragma unroll
      for (int kk = 0; kk < 4; ++kk) r[kk] = f2bf((float)deg_et[(size_t)kk * N + n]);
      *reinterpret_cast<u16x4*>(srow + 800) = r;
    } else if (k == 1 && lane >= 51 && lane <= 57) {
      u16x4 z; z[0] = z[1] = z[2] = z[3] = 0;
      *reinterpret_cast<u16x4*>(srow + 804 + (lane - 51) * 4) = z;
    }
  }
}

// ---------------- bf16 MFMA GEMM, 128x128 tile, dbuf gload_lds + XOR swizzle --------
// LDS tile (per buffer): 16B slot s = r*4 + (g ^ ((r>>1)&3)) holds row r, k-chunk g.
// Double-buffered: stage t+1 issued BEFORE tile-t MFMA; one barrier per K-step.
__global__ __launch_bounds__(256) void gemm_mfma(
    const u16* __restrict__ A, int lda,
    const u16* __restrict__ B, int ldb,
    u16* __restrict__ Cb, int ldcb, int npad,
    int M, int Nn, int K, const float* __restrict__ bias, int gyr) {
  const int gx = gridDim.x;
  int lin = blockIdx.y * gx + blockIdx.x;
  int k8 = lin & 7, j = lin >> 3;
  int band = gridDim.y >> 3;
  int yy = j / gx, xx = j - yy * gx;
  int by = k8 * band + yy;
  if (by >= gyr) return;
  const int m0 = by * 128, n0 = xx * 128;

  __shared__ __align__(16) u16 As[2 * 128 * 32];
  __shared__ __align__(16) u16 Bs[2 * 128 * 32];
  const int tid = threadIdx.x;
  const int lane = tid & 63;
  const int w = tid >> 6;
  const int wr = w >> 1, wc = w & 1;
  const int fr = lane & 15;
  const int g = lane >> 4;

  // staging geometry (per buffer): wave w writes slots [w*64, w*64+64) and +256
  const int gg = (lane & 3) ^ ((lane >> 3) & 3);  // swizzled k-chunk for this lane
  const int r0 = tid >> 2;
  const int r1 = r0 + 64;
  int ra0 = m0 + r0; if (ra0 >= M) ra0 = M - 1;
  int ra1 = m0 + r1; if (ra1 >= M) ra1 = M - 1;
  int rb0 = n0 + r0; if (rb0 >= Nn) rb0 = Nn - 1;
  int rb1 = n0 + r1; if (rb1 >= Nn) rb1 = Nn - 1;
  const u16* pa0 = A + (size_t)ra0 * lda + gg * 8;
  const u16* pa1 = A + (size_t)ra1 * lda + gg * 8;
  const u16* pb0 = B + (size_t)rb0 * ldb + gg * 8;
  const u16* pb1 = B + (size_t)rb1 * ldb + gg * 8;
  const int sl0 = (w * 64) * 8;          // u16 offset of this wave's lane-0 slot
  const int sl1 = (256 + w * 64) * 8;

  // fragment read swizzle (matches store): slot = row*4 + (g ^ ((row>>1)&3))
  const int gxr = g ^ ((fr >> 1) & 3);

  f32x4 acc[4][4] = {};
  const int nt = K >> 5;

  // prologue: stage tile 0 into buffer 0
  gload16(pa0, &As[sl0]); gload16(pa1, &As[sl1]);
  gload16(pb0, &Bs[sl0]); gload16(pb1, &Bs[sl1]);
  pa0 += 32; pa1 += 32; pb0 += 32; pb1 += 32;
  __syncthreads();

  int cur = 0;
  for (int t = 0; t < nt; ++t) {
    int nxt = cur ^ 4096;   // 128*32 u16 per buffer
    if (t + 1 < nt) {
      gload16(pa0, &As[nxt + sl0]); gload16(pa1, &As[nxt + sl1]);
      gload16(pb0, &Bs[nxt + sl0]); gload16(pb1, &Bs[nxt + sl1]);
      pa0 += 32; pa1 += 32; pb0 += 32; pb1 += 32;
    }
    bf16x8 af[4], bfv[4];
#pragma unroll
    for (int i = 0; i < 4; ++i) {
      int row = wr * 64 + i * 16 + fr;
      af[i] = *reinterpret_cast<const bf16x8*>(&As[cur + (row * 4 + gxr) * 8]);
    }
#pragma unroll
    for (int jj = 0; jj < 4; ++jj) {
      int row = wc * 64 + jj * 16 + fr;
      bfv[jj] = *reinterpret_cast<const bf16x8*>(&Bs[cur + (row * 4 + gxr) * 8]);
    }
#pragma unroll
    for (int i = 0; i < 4; ++i)
#pragma unroll
      for (int jj = 0; jj < 4; ++jj)
        acc[i][jj] = __builtin_amdgcn_mfma_f32_16x16x32_bf16(af[i], bfv[jj], acc[i][jj], 0, 0, 0);
    __syncthreads();   // drains next-tile loads; guards buffer reuse
    cur = nxt;
  }

  const int er = (lane >> 4) * 4;
  const int ec = lane & 15;
#pragma unroll
  for (int i = 0; i < 4; ++i) {
#pragma unroll
    for (int jj = 0; jj < 4; ++jj) {
      int n = n0 + wc * 64 + jj * 16 + ec;
#pragma unroll
      for (int r = 0; r < 4; ++r) {
        int m = m0 + wr * 64 + i * 16 + er + r;
        if (m >= M) continue;
        if (n < Nn) {
          float v = acc[i][jj][r];
          if (bias) v += bias[n];
          Cb[(size_t)m * ldcb + n] = f2bf(v);
        } else if (n < npad) {
          Cb[(size_t)m * ldcb + n] = (u16)0;
        }
      }
    }
  }
}

// GRU finisher: gates[n][832] = [r|z|inn|hn]; h := (1-z)*tanh(inn + r*hn) + z*h
__global__ void gru_fin_k(const u16* __restrict__ g, u16* __restrict__ ah, int c0, int Nc) {
  int total = Nc * 200;
  for (int i = blockIdx.x * blockDim.x + threadIdx.x; i < total; i += blockDim.x * gridDim.x) {
    int n = i / 200, o = i - n * 200;
    const u16* gr = g + (size_t)n * 832;
    float r = sigm(bf2f(gr[o]));
    float z = sigm(bf2f(gr[200 + o]));
    float x = bf2f(gr[400 + o]) + r * bf2f(gr[600 + o]);
    float e2 = __expf(2.f * x);
    float nn = (e2 - 1.f) / (e2 + 1.f);
    size_t hi = (size_t)(c0 + n) * 448 + 224 + o;
    float hold = bf2f(ah[hi]);
    ah[hi] = f2bf((1.f - z) * nn + z * hold);
  }
}

// cmat[n][352] = [h(224 incl zero pads) | feat(100) | 0(28)]
__global__ void cmat_k(const u16* __restrict__ ah, const float* __restrict__ feat,
                       u16* __restrict__ c, int N) {
  int total = N * 352;
  for (int i = blockIdx.x * blockDim.x + threadIdx.x; i < total; i += blockDim.x * gridDim.x) {
    int n = i / 352, j = i - n * 352;
    u16 v;
    if (j < 224) v = ah[(size_t)n * 448 + 224 + j];
    else { int f = j - 224; v = (f < 100) ? f2bf(feat[(size_t)n * 100 + f]) : (u16)0; }
    c[i] = v;
  }
}

// per-channel stats: fixed channel per thread, coalesced
__global__ __launch_bounds__(1024) void bn_stats2_k(const u16* __restrict__ X, int L, int C,
                                                    float* __restrict__ stats) {
  const int Q = 1024 / C;
  const int T = Q * C;
  const int tid = threadIdx.x;
  float s = 0.f, q = 0.f;
  int c = 0;
  if (tid < T) {
    int qi = tid / C; c = tid - qi * C;
    for (size_t r = (size_t)blockIdx.x * Q + qi; r < (size_t)L; r += (size_t)gridDim.x * Q) {
      float v = bf2f(X[r * C + c]);
      s += v; q += v * v;
    }
  }
  __shared__ float sb[304], qb[304];
  for (int cc = tid; cc < C; cc += 1024) { sb[cc] = 0.f; qb[cc] = 0.f; }
  __syncthreads();
  if (tid < T) { atomicAdd(&sb[c], s); atomicAdd(&qb[c], q); }
  __syncthreads();
  for (int cc = tid; cc < C; cc += 1024) {
    atomicAdd(&stats[cc], sb[cc]);
    atomicAdd(&stats[C + cc], qb[cc]);
  }
}

__global__ void bn_fin_k(const float* __restrict__ stats, const float* __restrict__ g,
                         const float* __restrict__ b, int C, float Linv,
                         float* __restrict__ scsh) {
  int c = blockIdx.x * blockDim.x + threadIdx.x;
  if (c < C) {
    float mean = stats[c] * Linv;
    float var = stats[C + c] * Linv - mean * mean;
    float sc = g[c] * rsqrtf(var + 1e-5f);
    scsh[c] = sc;
    scsh[C + c] = b[c] - mean * sc;
  }
}

__global__ void pool_bf_k(const u16* __restrict__ X, int C, const float* __restrict__ scsh,
                          int kw, int stride, u16* __restrict__ Y, int Cpad, int Lout) {
  int total = Lout * Cpad;
  for (int i = blockIdx.x * blockDim.x + threadIdx.x; i < total; i += blockDim.x * gridDim.x) {
    int lp = i / Cpad, c = i - lp * Cpad;
    if (c >= C) { Y[i] = (u16)0; continue; }
    float sc = scsh[c], sh = scsh[C + c];
    int l0 = lp * stride;
    float m = 0.f;
    for (int wq = 0; wq < kw; ++wq)
      m = fmaxf(m, fmaf(bf2f(X[(size_t)(l0 + wq) * C + c]), sc, sh));
    Y[i] = f2bf(m);
  }
}

__global__ void pool_f32_k(const u16* __restrict__ X, int C, const float* __restrict__ scsh,
                           int kw, int stride, float* __restrict__ Y, int Lout) {
  int total = Lout * C;
  for (int i = blockIdx.x * blockDim.x + threadIdx.x; i < total; i += blockDim.x * gridDim.x) {
    int lp = i / C, c = i - lp * C;
    float sc = scsh[c], sh = scsh[C + c];
    int l0 = lp * stride;
    float m = 0.f;
    for (int wq = 0; wq < kw; ++wq)
      m = fmaxf(m, fmaf(bf2f(X[(size_t)(l0 + wq) * C + c]), sc, sh));
    Y[i] = m;
  }
}

__global__ __launch_bounds__(256) void final_dot_k(
    const float* __restrict__ Y2, const float* __restrict__ Z2,
    const float* __restrict__ wy, const float* __restrict__ by,
    const float* __restrict__ wz, const float* __restrict__ bz,
    float* __restrict__ acc, int L) {
  float s0 = 0.f, s1 = 0.f;
  for (int lp = blockIdx.x * blockDim.x + threadIdx.x; lp < L; lp += blockDim.x * gridDim.x) {
    const float* y = Y2 + (size_t)lp * 200;
    const float* z = Z2 + (size_t)lp * 300;
    float d0 = 0.f, d1 = 0.f;
    for (int k = 0; k < 200; ++k) { float v = y[k]; d0 += v * wy[k]; d1 += v * wy[200 + k]; }
    float e0 = 0.f, e1 = 0.f;
    for (int k = 0; k < 300; ++k) { float v = z[k]; e0 += v * wz[k]; e1 += v * wz[300 + k]; }
    s0 += (d0 + by[0]) * (e0 + bz[0]);
    s1 += (d1 + by[1]) * (e1 + bz[1]);
  }
  __shared__ float r0[256], r1[256];
  r0[threadIdx.x] = s0; r1[threadIdx.x] = s1;
  __syncthreads();
  for (int off = 128; off > 0; off >>= 1) {
    if (threadIdx.x < off) { r0[threadIdx.x] += r0[threadIdx.x + off]; r1[threadIdx.x] += r1[threadIdx.x + off]; }
    __syncthreads();
  }
  if (threadIdx.x == 0) { atomicAdd(&acc[0], r0[0]); atomicAdd(&acc[1], r1[0]); }
}

__global__ void final_out_k(const float* __restrict__ acc, float invL, float* __restrict__ out) {
  int j = threadIdx.x;
  if (j < 2) out[j] = 1.f / (1.f + expf(-acc[j] * invL));
}

// ---------------- host ----------------

static inline void gemmL(hipStream_t st, const u16* A, int lda, const u16* B, int ldb,
                         u16* Cb, int ldcb, int npad, int M, int Nn, int K, const float* bias) {
  int ncols = (npad > Nn) ? npad : Nn;
  int gx = (ncols + 127) / 128;
  int gy = (M + 127) / 128;
  int gyp = ((gy + 7) / 8) * 8;
  dim3 g(gx, gyp);
  gemm_mfma<<<g, 256, 0, st>>>(A, lda, B, ldb, Cb, ldcb, npad, M, Nn, K, bias, gy);
}

extern "C" void kernel_launch(void* const* d_in, const int* in_sizes, int n_in,
                              void* d_out, int out_size, void* d_ws, size_t ws_size,
                              hipStream_t stream) {
  (void)n_in; (void)out_size;
  const float* feat    = (const float*)d_in[0];
  const int*   eix     = (const int*)d_in[1];
  const int*   etyp    = (const int*)d_in[2];
  const float* ggnnW   = (const float*)d_in[3];
  const float* ggnnB   = (const float*)d_in[4];
  const float* Wih     = (const float*)d_in[5];
  const float* Whh     = (const float*)d_in[6];
  const float* bih     = (const float*)d_in[7];
  const float* bhh     = (const float*)d_in[8];
  const float* conv1w  = (const float*)d_in[9];
  const float* conv2w  = (const float*)d_in[11];
  const float* convc1w = (const float*)d_in[13];
  const float* convc2w = (const float*)d_in[15];
  const float* bnyg    = (const float*)d_in[17];
  const float* bnyb    = (const float*)d_in[18];
  const float* bncg    = (const float*)d_in[19];
  const float* bncb    = (const float*)d_in[20];
  const float* mlpyw   = (const float*)d_in[21];
  const float* mlpyb   = (const float*)d_in[22];
  const float* mlpzw   = (const float*)d_in[23];
  const float* mlpzb   = (const float*)d_in[24];

  const int N = in_sizes[0] / 100;
  const int E = in_sizes[2];
  const int* src = eix;
  const int* dst = eix + E;

  char* base = (char*)d_ws;
  const size_t AH_B = (size_t)N * 448 * 2;
  const int CH = (N + 1) / 2;
  const size_t SCR_B = (size_t)CH * 1664;   // scat / gates: CH x 832 u16

  u16* ah = (u16*)base;
  char* R1 = base + AH_B;
  char* WREG = R1 + SCR_B;

  u16* Wcat = (u16*)WREG;          // 200*832
  u16* Wall = Wcat + 166400;       // 800*448
  u16* w1c  = Wall + 358400;       // 200*1056
  u16* c2b  = w1c + 211200;        // 200*224
  u16* wc1  = c2b + 44800;         // 300*1056
  u16* wc2  = wc1 + 316800;        // 300*320
  float* ball  = (float*)(wc2 + 96000);  // 800
  float* stats = ball + 832;             // 600
  float* scsh  = stats + 600;            // 600
  float* acc2  = scsh + 600;             // 2 (+pad)
  int* deg_et = (int*)(acc2 + 8);
  int* off_et = deg_et + 4 * (size_t)N;
  int* cursor = off_et + 4 * (size_t)N;
  int* esrc   = cursor + 4 * (size_t)N;
  int* bsum   = esrc + E;
  const int L4 = 4 * N;
  const int NB = (L4 + 1023) / 1024;
  size_t need = (size_t)((char*)(bsum + NB) - base);

  if (ws_size < need) {
    fail_k<<<1, 64, 0, stream>>>((float*)d_out, -(float)(ws_size >> 20));
    return;
  }

  // ---- CSR build + packs ----
  hipMemsetAsync(deg_et, 0, sizeof(int) * 4 * (size_t)N, stream);
  init_ah_k<<<4096, 256, 0, stream>>>(feat, ah, N);
  count_deg_k<<<2048, 256, 0, stream>>>(dst, etyp, deg_et, N, E);
  bsum_k<<<NB, 1024, 0, stream>>>(deg_et, bsum, L4);
  scanb_k<<<1, 1024, 0, stream>>>(bsum, NB);
  scan_fin_k<<<NB, 1024, 0, stream>>>(deg_et, bsum, off_et, L4);
  copy_int_k<<<512, 256, 0, stream>>>(off_et, cursor, L4);
  fill_src_k<<<2048, 256, 0, stream>>>(src, dst, etyp, cursor, esrc, N, E);
  pack_wcat_k<<<651, 256, 0, stream>>>(ggnnW, ggnnB, Wcat);
  pack_wall_k<<<1400, 256, 0, stream>>>(Wih, Whh, Wall);
  ball_k<<<4, 256, 0, stream>>>(bih, bhh, ball);
  pack_w1c_k<<<825, 256, 0, stream>>>(conv1w, w1c);
  pack_lin_b<<<175, 256, 0, stream>>>(conv2w, c2b, 200, 200, 224);
  pack_wc1_b<<<1238, 256, 0, stream>>>(convc1w, wc1);
  pack_lin_b<<<375, 256, 0, stream>>>(convc2w, wc2, 300, 300, 320);

  // ---- GGNN 8 steps ----
  u16* scat = (u16*)R1;    // CH x 832 (aliases gates)

  for (int step = 0; step < 8; ++step) {
    for (int c0 = 0; c0 < N; c0 += CH) {
      int Nc = (c0 + CH <= N) ? CH : (N - c0);
      agg_k<<<4096, 256, 0, stream>>>(off_et, deg_et, esrc, ah, scat, c0, Nc, N);
      gemmL(stream, scat, 832, Wcat, 832, ah + (size_t)c0 * 448, 448, 224,
            Nc, 200, 832, nullptr);
    }
    for (int c0 = 0; c0 < N; c0 += CH) {
      int Nc = (c0 + CH <= N) ? CH : (N - c0);
      const u16* ahc = ah + (size_t)c0 * 448;
      gemmL(stream, ahc, 448, Wall, 448, scat, 832, 800, Nc, 800, 448, ball);
      gru_fin_k<<<2048, 256, 0, stream>>>(scat, ah, c0, Nc);
    }
  }

  // ---- conv paths ----
  const int L1 = N - 2;
  const int L2 = (L1 - 3) / 2 + 1;
  const int L3 = (L2 - 2) / 2 + 1;

  u16* cmat = (u16*)R1;                                              // N*352
  u16* out1 = (u16*)base;                                            // L1*200
  size_t y1_off = (((size_t)L1 * 400) + 255) & ~(size_t)255;
  u16* y1 = (u16*)(base + y1_off);                                   // L2*224
  size_t o2_off = y1_off + ((((size_t)L2 * 448) + 255) & ~(size_t)255);
  u16* out2 = (u16*)(base + o2_off);                                 // L2*200
  float* Y2f = (float*)base;                                         // L3*200 f32
  size_t oc1_off = (((size_t)L3 * 800) + 255) & ~(size_t)255;
  u16* outc1 = (u16*)(base + oc1_off);                               // L1*300
  u16* z1 = (u16*)R1;                                                // L2*320
  size_t oc2_off = (((size_t)L2 * 640) + 255) & ~(size_t)255;
  u16* outc2 = (u16*)(R1 + oc2_off);                                 // L2*300
  float* Z2f = (float*)(base + oc1_off);                             // L3*300 f32

  cmat_k<<<4096, 256, 0, stream>>>(ah, feat, cmat, N);

  // Y path
  gemmL(stream, cmat, 352, w1c, 1056, out1, 200, 200, L1, 200, 1056, nullptr);
  hipMemsetAsync(stats, 0, sizeof(float) * 400, stream);
  bn_stats2_k<<<512, 1024, 0, stream>>>(out1, L1, 200, stats);
  bn_fin_k<<<2, 256, 0, stream>>>(stats, bnyg, bnyb, 200, 1.f / (float)L1, scsh);
  pool_bf_k<<<2048, 256, 0, stream>>>(out1, 200, scsh, 3, 2, y1, 224, L2);

  gemmL(stream, y1, 224, c2b, 224, out2, 200, 200, L2, 200, 224, nullptr);
  hipMemsetAsync(stats, 0, sizeof(float) * 400, stream);
  bn_stats2_k<<<512, 1024, 0, stream>>>(out2, L2, 200, stats);
  bn_fin_k<<<2, 256, 0, stream>>>(stats, bnyg, bnyb, 200, 1.f / (float)L2, scsh);
  pool_f32_k<<<2048, 256, 0, stream>>>(out2, 200, scsh, 2, 2, Y2f, L3);

  // Z path
  gemmL(stream, cmat, 352, wc1, 1056, outc1, 300, 300, L1, 300, 1056, nullptr);
  hipMemsetAsync(stats, 0, sizeof(float) * 600, stream);
  bn_stats2_k<<<512, 1024, 0, stream>>>(outc1, L1, 300, stats);
  bn_fin_k<<<2, 256, 0, stream>>>(stats, bncg, bncb, 300, 1.f / (float)L1, scsh);
  pool_bf_k<<<2048, 256, 0, stream>>>(outc1, 300, scsh, 3, 2, z1, 320, L2);

  gemmL(stream, z1, 320, wc2, 320, outc2, 300, 300, L2, 300, 320, nullptr);
  hipMemsetAsync(stats, 0, sizeof(float) * 600, stream);
  bn_stats2_k<<<512, 1024, 0, stream>>>(outc2, L2, 300, stats);
  bn_fin_k<<<2, 256, 0, stream>>>(stats, bncg, bncb, 300, 1.f / (float)L2, scsh);
  pool_f32_k<<<2048, 256, 0, stream>>>(outc2, 300, scsh, 2, 2, Z2f, L3);

  // ---- final MLP product + mean + sigmoid ----
  hipMemsetAsync(acc2, 0, sizeof(float) * 2, stream);
  final_dot_k<<<256, 256, 0, stream>>>(Y2f, Z2f, mlpyw, mlpyb, mlpzw, mlpzb, acc2, L3);
  final_out_k<<<1, 64, 0, stream>>>(acc2, 1.f / (float)L3, (float*)d_out);
}